// Round 2
// baseline (2344.953 us; speedup 1.0000x reference)
//
#include <hip/hip_runtime.h>
#include <math.h>

#define B_ 16
#define S_ 256
#define D_ 1024
#define HP_ 16
#define DK_ 64
#define HC_ 8
#define SK_ 32
#define EPS_ 1e-6f

// ---------------- K1: LayerNorm over channels (per row of D=1024) ----------------
__global__ __launch_bounds__(256) void k1_ln_p(
    const float* __restrict__ x, const float* __restrict__ a_p,
    const float* __restrict__ b_p, float* __restrict__ out)
{
    const int row = blockIdx.x;                  // b*S + s
    const float4* xr = (const float4*)(x + (size_t)row * D_);
    float4* orow = (float4*)(out + (size_t)row * D_);
    const int tid = threadIdx.x;
    float4 v = xr[tid];
    float s  = v.x + v.y + v.z + v.w;
    float sq = v.x*v.x + v.y*v.y + v.z*v.z + v.w*v.w;
    #pragma unroll
    for (int off = 32; off > 0; off >>= 1) {
        s  += __shfl_down(s, off);
        sq += __shfl_down(sq, off);
    }
    __shared__ float red[8];
    const int wid = tid >> 6, lane = tid & 63;
    if (lane == 0) { red[wid] = s; red[4 + wid] = sq; }
    __syncthreads();
    if (tid == 0) {
        float S0 = red[0] + red[1] + red[2] + red[3];
        float Q0 = red[4] + red[5] + red[6] + red[7];
        float mean = S0 / (float)D_;
        float var  = fmaxf((Q0 - (float)D_ * mean * mean) / (float)(D_ - 1), 0.0f);
        red[0] = mean;
        red[1] = 1.0f / (sqrtf(var) + EPS_);     // torch std(): unbiased; eps on std
    }
    __syncthreads();
    const float mean = red[0], inv = red[1];
    float4 a = ((const float4*)a_p)[tid];
    float4 b = ((const float4*)b_p)[tid];
    float4 o;
    o.x = a.x * (v.x - mean) * inv + b.x;
    o.y = a.y * (v.y - mean) * inv + b.y;
    o.z = a.z * (v.z - mean) * inv + b.z;
    o.w = a.w * (v.w - mean) * inv + b.w;
    orow[tid] = o;
}

// ---------------- Generic f32 matmul C[m,n] = sum_k A[m,k]*B[k,n] + bias[n] ------
__global__ __launch_bounds__(256) void mm_bias(
    const float* __restrict__ A, const float* __restrict__ Bm,
    const float* __restrict__ bias, float* __restrict__ C,
    int M, int N, int K, long sB, long sBias, long sC)
{
    const int n = blockIdx.z;
    Bm   += (size_t)n * sB;
    bias += (size_t)n * sBias;
    C    += (size_t)n * sC;
    const int m0 = blockIdx.y * 128, n0 = blockIdx.x * 128;
    __shared__ float As[16][132];   // transposed: As[k][m]
    __shared__ float Bs[16][132];
    const int tid = threadIdx.x;
    const int tx = tid & 15, ty = tid >> 4;
    const int arow = tid >> 2, acol = (tid & 3) * 4;
    const int brow = tid >> 5, bcol = (tid & 31) * 4;
    float acc[8][8];
    {
        float4 bi0 = *(const float4*)&bias[n0 + tx*8];
        float4 bi1 = *(const float4*)&bias[n0 + tx*8 + 4];
        #pragma unroll
        for (int i = 0; i < 8; i++) {
            acc[i][0]=bi0.x; acc[i][1]=bi0.y; acc[i][2]=bi0.z; acc[i][3]=bi0.w;
            acc[i][4]=bi1.x; acc[i][5]=bi1.y; acc[i][6]=bi1.z; acc[i][7]=bi1.w;
        }
    }
    for (int k0 = 0; k0 < K; k0 += 16) {
        float4 a0 = *(const float4*)&A[(size_t)(m0 + arow     ) * K + k0 + acol];
        float4 a1 = *(const float4*)&A[(size_t)(m0 + arow + 64) * K + k0 + acol];
        float4 b0 = *(const float4*)&Bm[(size_t)(k0 + brow    ) * N + n0 + bcol];
        float4 b1 = *(const float4*)&Bm[(size_t)(k0 + brow + 8) * N + n0 + bcol];
        __syncthreads();
        As[acol+0][arow] = a0.x; As[acol+1][arow] = a0.y;
        As[acol+2][arow] = a0.z; As[acol+3][arow] = a0.w;
        As[acol+0][arow+64] = a1.x; As[acol+1][arow+64] = a1.y;
        As[acol+2][arow+64] = a1.z; As[acol+3][arow+64] = a1.w;
        *(float4*)&Bs[brow][bcol]   = b0;
        *(float4*)&Bs[brow+8][bcol] = b1;
        __syncthreads();
        #pragma unroll
        for (int kk = 0; kk < 16; kk++) {
            float4 af0 = *(const float4*)&As[kk][ty*8];
            float4 af1 = *(const float4*)&As[kk][ty*8+4];
            float4 bf0 = *(const float4*)&Bs[kk][tx*8];
            float4 bf1 = *(const float4*)&Bs[kk][tx*8+4];
            float ar[8] = {af0.x,af0.y,af0.z,af0.w,af1.x,af1.y,af1.z,af1.w};
            float br[8] = {bf0.x,bf0.y,bf0.z,bf0.w,bf1.x,bf1.y,bf1.z,bf1.w};
            #pragma unroll
            for (int i = 0; i < 8; i++)
                #pragma unroll
                for (int j = 0; j < 8; j++)
                    acc[i][j] = fmaf(ar[i], br[j], acc[i][j]);
        }
    }
    #pragma unroll
    for (int i = 0; i < 8; i++) {
        float4 o0 = {acc[i][0],acc[i][1],acc[i][2],acc[i][3]};
        float4 o1 = {acc[i][4],acc[i][5],acc[i][6],acc[i][7]};
        float* cr = &C[(size_t)(m0 + ty*8 + i) * N + n0 + tx*8];
        *(float4*)cr     = o0;
        *(float4*)(cr+4) = o1;
    }
}

// ---------------- K3: positional attention, GEMM-flash -------------------------
// tokens=256 (seq), heads=16, dk=64. Mtile=128, Ntile=64, Ps chunked by 16 n.
// LDS: Qs[64][132] + KV-union[64][68] + PsL[128*20] = 60 KB -> 2 blocks/CU.
__global__ __launch_bounds__(256) void k3_flash(
    const float* __restrict__ q, const float* __restrict__ k,
    const float* __restrict__ v, float* __restrict__ out)
{
    const int m0 = blockIdx.x * 128;
    const int h = blockIdx.y, b = blockIdx.z;
    __shared__ float Qs[64][132];     // Qs[kdim][m]
    __shared__ float KV[64][68];      // Ks[kdim][n] then Vt[d][n]
    __shared__ float PsL[128*20];     // P chunk [128][16+pad4]; later l-reduce [8][128]
    const int tid = threadIdx.x;
    const int hoff = h * DK_;
    const size_t rowb = (size_t)b * S_;

    { // stage Q transposed (once)
        const int m = tid >> 1, c0 = (tid & 1) * 32;
        const float* qr = q + (rowb + m0 + m) * D_ + hoff + c0;
        #pragma unroll
        for (int cc = 0; cc < 32; cc += 4) {
            float4 t = *(const float4*)(qr + cc);
            Qs[c0+cc+0][m] = t.x; Qs[c0+cc+1][m] = t.y;
            Qs[c0+cc+2][m] = t.z; Qs[c0+cc+3][m] = t.w;
        }
    }
    const int tx = tid & 7, ty = tid >> 3;    // score: n-frag 8 (4tx / 32+4tx), m-frag 4 (ty*4)
    const int mg = tid >> 3, dg = tid & 7;    // PV: m = mg+32i, d = dg+8j (strided, bank-free)
    float o[4][8] = {};
    float lpart[4] = {};
    for (int kt = 0; kt < 4; kt++) {
        const int n00 = kt * 64;
        __syncthreads();
        { // stage K -> KV[kdim][n]
            const int n = tid >> 2, c0 = (tid & 3) * 16;
            const float* kr = k + (rowb + n00 + n) * D_ + hoff + c0;
            #pragma unroll
            for (int cc = 0; cc < 16; cc += 4) {
                float4 t = *(const float4*)(kr + cc);
                KV[c0+cc+0][n] = t.x; KV[c0+cc+1][n] = t.y;
                KV[c0+cc+2][n] = t.z; KV[c0+cc+3][n] = t.w;
            }
        }
        __syncthreads();
        float s[4][8] = {};
        for (int kk = 0; kk < 64; kk++) {
            float4 a0 = *(const float4*)&Qs[kk][ty*4];
            float4 b0 = *(const float4*)&KV[kk][tx*4];
            float4 b1 = *(const float4*)&KV[kk][32 + tx*4];
            float ar[4] = {a0.x,a0.y,a0.z,a0.w};
            float br[8] = {b0.x,b0.y,b0.z,b0.w,b1.x,b1.y,b1.z,b1.w};
            #pragma unroll
            for (int i=0;i<4;i++)
                #pragma unroll
                for (int j=0;j<8;j++)
                    s[i][j] = fmaf(ar[i], br[j], s[i][j]);
        }
        #pragma unroll
        for (int i=0;i<4;i++)
            #pragma unroll
            for (int j=0;j<8;j++) {
                s[i][j] = __expf(s[i][j] * 0.125f);   // 1/sqrt(64); scores bounded
                lpart[i] += s[i][j];
            }
        __syncthreads();   // score done reading K
        { // stage V -> KV[d][n]
            const int n = tid >> 2, c0 = (tid & 3) * 16;
            const float* vr = v + (rowb + n00 + n) * D_ + hoff + c0;
            #pragma unroll
            for (int cc = 0; cc < 16; cc += 4) {
                float4 t = *(const float4*)(vr + cc);
                KV[c0+cc+0][n] = t.x; KV[c0+cc+1][n] = t.y;
                KV[c0+cc+2][n] = t.z; KV[c0+cc+3][n] = t.w;
            }
        }
        #pragma unroll
        for (int c = 0; c < 4; c++) {          // 16-wide P chunks
            const int part = c >> 1;
            if ((tx >> 2) == (c & 1)) {
                const int col = 4 * (tx & 3);
                #pragma unroll
                for (int i=0;i<4;i++) {
                    float4 t = { s[i][part*4+0], s[i][part*4+1],
                                 s[i][part*4+2], s[i][part*4+3] };
                    *(float4*)&PsL[(ty*4+i)*20 + col] = t;
                }
            }
            __syncthreads();                   // covers V stage (c==0) + P chunk
            #pragma unroll
            for (int nn = 0; nn < 16; nn += 4) {
                float4 pf[4], vf[8];
                #pragma unroll
                for (int i=0;i<4;i++) pf[i] = *(const float4*)&PsL[(mg+32*i)*20 + nn];
                #pragma unroll
                for (int j=0;j<8;j++) vf[j] = *(const float4*)&KV[dg+8*j][c*16 + nn];
                #pragma unroll
                for (int i=0;i<4;i++)
                    #pragma unroll
                    for (int j=0;j<8;j++) {
                        o[i][j] = fmaf(pf[i].x, vf[j].x, o[i][j]);
                        o[i][j] = fmaf(pf[i].y, vf[j].y, o[i][j]);
                        o[i][j] = fmaf(pf[i].z, vf[j].z, o[i][j]);
                        o[i][j] = fmaf(pf[i].w, vf[j].w, o[i][j]);
                    }
            }
            __syncthreads();                   // PV done before P reuse / K restage
        }
    }
    // l reduction (alias PsL) + normalize + store
    #pragma unroll
    for (int i=0;i<4;i++) PsL[tx*128 + ty*4 + i] = lpart[i];
    __syncthreads();
    #pragma unroll
    for (int i=0;i<4;i++) {
        const int m = mg + 32*i;
        float l = 0.f;
        #pragma unroll
        for (int t=0;t<8;t++) l += PsL[t*128 + m];
        const float inv = 1.0f / l;
        float* orow = out + (rowb + m0 + m) * D_ + hoff;
        #pragma unroll
        for (int j=0;j<8;j++) orow[dg + 8*j] = o[i][j] * inv;
    }
}

// ---------------- K6: channel attention, GEMM-flash ----------------------------
// tokens=1024 (channels), heads=8, dk=32. Mtile=128, Ntile=128, Ps chunked by 32.
// LDS: Qs[32][132] + KV-union[32][132] + PsL[128*36] = 51 KB -> 3 blocks/CU.
__global__ __launch_bounds__(256) void k6_flash(
    const float* __restrict__ qc, const float* __restrict__ kc,
    const float* __restrict__ vc, float* __restrict__ out)
{
    const int m0 = blockIdx.x * 128;
    const int h = blockIdx.y, b = blockIdx.z;
    __shared__ float Qs[32][132];
    __shared__ float KV[32][132];
    __shared__ float PsL[128*36];
    const int tid = threadIdx.x;
    const size_t rowb = (size_t)b * D_;
    const int hoff = h * SK_;

    { // stage Q transposed (once)
        const int m = tid >> 1, c0 = (tid & 1) * 16;
        const float* qr = qc + (rowb + m0 + m) * S_ + hoff + c0;
        #pragma unroll
        for (int cc = 0; cc < 16; cc += 4) {
            float4 t = *(const float4*)(qr + cc);
            Qs[c0+cc+0][m] = t.x; Qs[c0+cc+1][m] = t.y;
            Qs[c0+cc+2][m] = t.z; Qs[c0+cc+3][m] = t.w;
        }
    }
    const int tx = tid & 15, ty = tid >> 4;   // score: n-frag 8 (4tx / 64+4tx), m-frag 8
    const int mg = tid >> 3, dg = tid & 7;    // PV: m = mg+32i, d = dg+8j
    float o[4][4] = {};
    float lpart[8] = {};
    for (int kt = 0; kt < 8; kt++) {
        const int n00 = kt * 128;
        __syncthreads();
        { // stage K -> KV[kdim][n]
            const int n = tid >> 1, c0 = (tid & 1) * 16;
            const float* kr = kc + (rowb + n00 + n) * S_ + hoff + c0;
            #pragma unroll
            for (int cc = 0; cc < 16; cc += 4) {
                float4 t = *(const float4*)(kr + cc);
                KV[c0+cc+0][n] = t.x; KV[c0+cc+1][n] = t.y;
                KV[c0+cc+2][n] = t.z; KV[c0+cc+3][n] = t.w;
            }
        }
        __syncthreads();
        float s[8][8] = {};
        for (int kk = 0; kk < 32; kk++) {
            float4 a0 = *(const float4*)&Qs[kk][ty*8];
            float4 a1 = *(const float4*)&Qs[kk][ty*8+4];
            float4 b0 = *(const float4*)&KV[kk][tx*4];
            float4 b1 = *(const float4*)&KV[kk][64 + tx*4];
            float ar[8] = {a0.x,a0.y,a0.z,a0.w,a1.x,a1.y,a1.z,a1.w};
            float br[8] = {b0.x,b0.y,b0.z,b0.w,b1.x,b1.y,b1.z,b1.w};
            #pragma unroll
            for (int i=0;i<8;i++)
                #pragma unroll
                for (int j=0;j<8;j++)
                    s[i][j] = fmaf(ar[i], br[j], s[i][j]);
        }
        #pragma unroll
        for (int i=0;i<8;i++)
            #pragma unroll
            for (int j=0;j<8;j++) {
                s[i][j] = __expf(s[i][j] * 0.17677669529663687f);  // 1/sqrt(32)
                lpart[i] += s[i][j];
            }
        __syncthreads();   // score done reading K
        { // stage V -> KV[d][n]
            const int n = tid >> 1, c0 = (tid & 1) * 16;
            const float* vr = vc + (rowb + n00 + n) * S_ + hoff + c0;
            #pragma unroll
            for (int cc = 0; cc < 16; cc += 4) {
                float4 t = *(const float4*)(vr + cc);
                KV[c0+cc+0][n] = t.x; KV[c0+cc+1][n] = t.y;
                KV[c0+cc+2][n] = t.z; KV[c0+cc+3][n] = t.w;
            }
        }
        #pragma unroll
        for (int c = 0; c < 4; c++) {          // 32-wide P chunks
            const int part = c >> 1;
            if ((tx >> 3) == (c & 1)) {
                const int col = 4 * (tx & 7);
                #pragma unroll
                for (int i=0;i<8;i++) {
                    float4 t = { s[i][part*4+0], s[i][part*4+1],
                                 s[i][part*4+2], s[i][part*4+3] };
                    *(float4*)&PsL[(ty*8+i)*36 + col] = t;
                }
            }
            __syncthreads();
            #pragma unroll
            for (int nn = 0; nn < 32; nn += 4) {
                float4 pf[4], vf[4];
                #pragma unroll
                for (int i=0;i<4;i++) pf[i] = *(const float4*)&PsL[(mg+32*i)*36 + nn];
                #pragma unroll
                for (int j=0;j<4;j++) vf[j] = *(const float4*)&KV[dg+8*j][c*32 + nn];
                #pragma unroll
                for (int i=0;i<4;i++)
                    #pragma unroll
                    for (int j=0;j<4;j++) {
                        o[i][j] = fmaf(pf[i].x, vf[j].x, o[i][j]);
                        o[i][j] = fmaf(pf[i].y, vf[j].y, o[i][j]);
                        o[i][j] = fmaf(pf[i].z, vf[j].z, o[i][j]);
                        o[i][j] = fmaf(pf[i].w, vf[j].w, o[i][j]);
                    }
            }
            __syncthreads();
        }
    }
    // l reduction (alias PsL) + normalize + store
    #pragma unroll
    for (int i=0;i<8;i++) PsL[tx*128 + ty*8 + i] = lpart[i];
    __syncthreads();
    #pragma unroll
    for (int i=0;i<4;i++) {
        const int m = mg + 32*i;
        float l = 0.f;
        #pragma unroll
        for (int t=0;t<16;t++) l += PsL[t*128 + m];
        const float inv = 1.0f / l;
        float* orow = out + (rowb + m0 + m) * S_ + hoff;
        #pragma unroll
        for (int j=0;j<4;j++) orow[dg + 8*j] = o[i][j] * inv;
    }
}

// ---------------- K4a: per-(b,d) stats over sequence dim ----------------
__global__ __launch_bounds__(256) void k4a_stats(
    const float* __restrict__ x, float* __restrict__ meanc, float* __restrict__ invc)
{
    const int d = blockIdx.x * 256 + threadIdx.x;
    const int b = blockIdx.y;
    const float* p = x + (size_t)b * S_ * D_ + d;
    float s = 0.f, q = 0.f;
    for (int t = 0; t < S_; t++) { float vv = p[(size_t)t * D_]; s += vv; q += vv*vv; }
    const float mean = s / (float)S_;
    const float var  = fmaxf((q - (float)S_ * mean * mean) / (float)(S_ - 1), 0.0f);
    meanc[b*D_ + d] = mean;
    invc[b*D_ + d]  = 1.0f / (sqrtf(var) + EPS_);
}

// ---------------- K4b: normalize (LN over seq) + transpose to [B,D,S] ----------
__global__ __launch_bounds__(256) void k4b_ntrans(
    const float* __restrict__ x, const float* __restrict__ meanc,
    const float* __restrict__ invc, const float* __restrict__ a_c,
    const float* __restrict__ b_c, float* __restrict__ xt)
{
    const int s0 = blockIdx.x * 64, d0 = blockIdx.y * 64, b = blockIdx.z;
    __shared__ float tile[64][65];
    const int ix = threadIdx.x & 63, iy = threadIdx.x >> 6;
    const int d = d0 + ix;
    const float mean = meanc[b*D_ + d], inv = invc[b*D_ + d];
    #pragma unroll
    for (int u = 0; u < 16; u++) {
        const int srow = iy*16 + u;
        const float vv = x[((size_t)(b*S_ + s0 + srow)) * D_ + d];
        tile[srow][ix] = a_c[s0+srow] * (vv - mean) * inv + b_c[s0+srow];
    }
    __syncthreads();
    #pragma unroll
    for (int u = 0; u < 16; u++) {
        const int drow = iy*16 + u;
        xt[((size_t)(b*D_ + d0 + drow)) * S_ + s0 + ix] = tile[ix][drow];
    }
}

// ---------------- K8: final transpose [B,D,S] -> [B,S,D] ----------------
__global__ __launch_bounds__(256) void k8_trans(
    const float* __restrict__ y, float* __restrict__ out)
{
    const int e0 = blockIdx.x * 64, d0 = blockIdx.y * 64, b = blockIdx.z;
    __shared__ float tile[64][65];
    const int ix = threadIdx.x & 63, iy = threadIdx.x >> 6;
    #pragma unroll
    for (int u = 0; u < 16; u++) {
        const int drow = iy*16 + u;
        tile[drow][ix] = y[((size_t)(b*D_ + d0 + drow)) * S_ + e0 + ix];
    }
    __syncthreads();
    #pragma unroll
    for (int u = 0; u < 16; u++) {
        const int erow = iy*16 + u;
        out[((size_t)(b*S_ + e0 + erow)) * D_ + d0 + ix] = tile[ix][erow];
    }
}

extern "C" void kernel_launch(void* const* d_in, const int* in_sizes, int n_in,
                              void* d_out, int out_size, void* d_ws, size_t ws_size,
                              hipStream_t stream)
{
    const float* x   = (const float*)d_in[0];
    const float* Wp  = (const float*)d_in[1];
    const float* bp  = (const float*)d_in[2];
    const float* Wc  = (const float*)d_in[3];
    const float* bc  = (const float*)d_in[4];
    const float* a_p = (const float*)d_in[5];
    const float* b_p = (const float*)d_in[6];
    const float* a_c = (const float*)d_in[7];
    const float* b_c = (const float*)d_in[8];
    float* out = (float*)d_out;
    float* ws  = (float*)d_ws;
    const size_t NE = (size_t)B_ * S_ * D_;

    float* R0 = ws;
    float* R1 = ws + NE;
    float* R2 = ws + 2*NE;
    float* R3 = ws + 3*NE;
    float* meanc = ws + 4*NE;
    float* invc  = meanc + (size_t)B_*D_;

    // 1) LayerNorm over channels: x -> R0
    k1_ln_p<<<dim3(B_*S_), 256, 0, stream>>>(x, a_p, b_p, R0);
    // 2) QKV projection: R0 @ Wp[n] + bp[n] -> R1,R2,R3
    mm_bias<<<dim3(D_/128, (B_*S_)/128, 3), 256, 0, stream>>>(
        R0, Wp, bp, R1, B_*S_, D_, D_, (long)D_*D_, (long)D_, (long)NE);
    // 3) positional attention (GEMM-flash) -> R0
    k3_flash<<<dim3(S_/128, HP_, B_), 256, 0, stream>>>(R1, R2, R3, R0);
    // 4) LN over sequence: stats then normalize+transpose -> R1 (xt [B,D,S])
    k4a_stats<<<dim3(D_/256, B_), 256, 0, stream>>>(R0, meanc, invc);
    k4b_ntrans<<<dim3(S_/64, D_/64, B_), 256, 0, stream>>>(R0, meanc, invc, a_c, b_c, R1);
    // 5) channel QKV: R1 @ Wc[n] + bc[n] -> qc:R2, kc:R3, vc:R0
    float* qkvc[3] = {R2, R3, R0};
    for (int nn = 0; nn < 3; nn++) {
        mm_bias<<<dim3(S_/128, (B_*D_)/128, 1), 256, 0, stream>>>(
            R1, Wc + (size_t)nn*S_*S_, bc + (size_t)nn*S_, qkvc[nn],
            B_*D_, S_, S_, 0, 0, 0);
    }
    // 6) channel attention (GEMM-flash) -> R1 (xcatt [B,D,S])
    k6_flash<<<dim3(D_/128, HC_, B_), 256, 0, stream>>>(R2, R3, R0, R1);
    // 7) final projection: R1 @ Wc[3] + bc[3] -> R0 (y [B,D,S])
    mm_bias<<<dim3(S_/128, (B_*D_)/128, 1), 256, 0, stream>>>(
        R1, Wc + (size_t)3*S_*S_, bc + (size_t)3*S_, R0,
        B_*D_, S_, S_, 0, 0, 0);
    // 8) transpose y -> out [B,S,D]
    k8_trans<<<dim3(S_/64, D_/64, B_), 256, 0, stream>>>(R0, out);
}

// Round 3
// 889.716 us; speedup vs baseline: 2.6356x; 2.6356x over previous
//
#include <hip/hip_runtime.h>
#include <math.h>

#define B_ 16
#define S_ 256
#define D_ 1024
#define HP_ 16
#define DK_ 64
#define HC_ 8
#define SK_ 32
#define EPS_ 1e-6f

// ---------------- K1: LayerNorm over channels (per row of D=1024) ----------------
__global__ __launch_bounds__(256) void k1_ln_p(
    const float* __restrict__ x, const float* __restrict__ a_p,
    const float* __restrict__ b_p, float* __restrict__ out)
{
    const int row = blockIdx.x;                  // b*S + s
    const float4* xr = (const float4*)(x + (size_t)row * D_);
    float4* orow = (float4*)(out + (size_t)row * D_);
    const int tid = threadIdx.x;
    float4 v = xr[tid];
    float s  = v.x + v.y + v.z + v.w;
    float sq = v.x*v.x + v.y*v.y + v.z*v.z + v.w*v.w;
    #pragma unroll
    for (int off = 32; off > 0; off >>= 1) {
        s  += __shfl_down(s, off);
        sq += __shfl_down(sq, off);
    }
    __shared__ float red[8];
    const int wid = tid >> 6, lane = tid & 63;
    if (lane == 0) { red[wid] = s; red[4 + wid] = sq; }
    __syncthreads();
    if (tid == 0) {
        float S0 = red[0] + red[1] + red[2] + red[3];
        float Q0 = red[4] + red[5] + red[6] + red[7];
        float mean = S0 / (float)D_;
        float var  = fmaxf((Q0 - (float)D_ * mean * mean) / (float)(D_ - 1), 0.0f);
        red[0] = mean;
        red[1] = 1.0f / (sqrtf(var) + EPS_);     // torch std(): unbiased; eps on std
    }
    __syncthreads();
    const float mean = red[0], inv = red[1];
    float4 a = ((const float4*)a_p)[tid];
    float4 b = ((const float4*)b_p)[tid];
    float4 o;
    o.x = a.x * (v.x - mean) * inv + b.x;
    o.y = a.y * (v.y - mean) * inv + b.y;
    o.z = a.z * (v.z - mean) * inv + b.z;
    o.w = a.w * (v.w - mean) * inv + b.w;
    orow[tid] = o;
}

// ---------------- Generic f32 matmul C[m,n] = sum_k A[m,k]*B[k,n] + bias[n] ------
__global__ __launch_bounds__(256) void mm_bias(
    const float* __restrict__ A, const float* __restrict__ Bm,
    const float* __restrict__ bias, float* __restrict__ C,
    int M, int N, int K, long sB, long sBias, long sC)
{
    const int n = blockIdx.z;
    Bm   += (size_t)n * sB;
    bias += (size_t)n * sBias;
    C    += (size_t)n * sC;
    const int m0 = blockIdx.y * 128, n0 = blockIdx.x * 128;
    __shared__ float As[16][132];   // transposed: As[k][m]
    __shared__ float Bs[16][132];
    const int tid = threadIdx.x;
    const int tx = tid & 15, ty = tid >> 4;
    const int arow = tid >> 2, acol = (tid & 3) * 4;
    const int brow = tid >> 5, bcol = (tid & 31) * 4;
    float acc[8][8];
    {
        float4 bi0 = *(const float4*)&bias[n0 + tx*8];
        float4 bi1 = *(const float4*)&bias[n0 + tx*8 + 4];
        #pragma unroll
        for (int i = 0; i < 8; i++) {
            acc[i][0]=bi0.x; acc[i][1]=bi0.y; acc[i][2]=bi0.z; acc[i][3]=bi0.w;
            acc[i][4]=bi1.x; acc[i][5]=bi1.y; acc[i][6]=bi1.z; acc[i][7]=bi1.w;
        }
    }
    for (int k0 = 0; k0 < K; k0 += 16) {
        float4 a0 = *(const float4*)&A[(size_t)(m0 + arow     ) * K + k0 + acol];
        float4 a1 = *(const float4*)&A[(size_t)(m0 + arow + 64) * K + k0 + acol];
        float4 b0 = *(const float4*)&Bm[(size_t)(k0 + brow    ) * N + n0 + bcol];
        float4 b1 = *(const float4*)&Bm[(size_t)(k0 + brow + 8) * N + n0 + bcol];
        __syncthreads();
        As[acol+0][arow] = a0.x; As[acol+1][arow] = a0.y;
        As[acol+2][arow] = a0.z; As[acol+3][arow] = a0.w;
        As[acol+0][arow+64] = a1.x; As[acol+1][arow+64] = a1.y;
        As[acol+2][arow+64] = a1.z; As[acol+3][arow+64] = a1.w;
        *(float4*)&Bs[brow][bcol]   = b0;
        *(float4*)&Bs[brow+8][bcol] = b1;
        __syncthreads();
        #pragma unroll
        for (int kk = 0; kk < 16; kk++) {
            float4 af0 = *(const float4*)&As[kk][ty*8];
            float4 af1 = *(const float4*)&As[kk][ty*8+4];
            float4 bf0 = *(const float4*)&Bs[kk][tx*8];
            float4 bf1 = *(const float4*)&Bs[kk][tx*8+4];
            float ar[8] = {af0.x,af0.y,af0.z,af0.w,af1.x,af1.y,af1.z,af1.w};
            float br[8] = {bf0.x,bf0.y,bf0.z,bf0.w,bf1.x,bf1.y,bf1.z,bf1.w};
            #pragma unroll
            for (int i = 0; i < 8; i++)
                #pragma unroll
                for (int j = 0; j < 8; j++)
                    acc[i][j] = fmaf(ar[i], br[j], acc[i][j]);
        }
    }
    #pragma unroll
    for (int i = 0; i < 8; i++) {
        float4 o0 = {acc[i][0],acc[i][1],acc[i][2],acc[i][3]};
        float4 o1 = {acc[i][4],acc[i][5],acc[i][6],acc[i][7]};
        float* cr = &C[(size_t)(m0 + ty*8 + i) * N + n0 + tx*8];
        *(float4*)cr     = o0;
        *(float4*)(cr+4) = o1;
    }
}

// ---------------- K3: positional attention, flash. Mtile=64, Ntile=64, dk=64 -----
// Per-thread score frag 4x4 (dies before PV: full P -> LDS). 68 KB LDS, 2 blk/CU.
__global__ __launch_bounds__(256) void k3_flash(
    const float* __restrict__ q, const float* __restrict__ k,
    const float* __restrict__ v, float* __restrict__ out)
{
    const int m0 = blockIdx.x * 64;
    const int h = blockIdx.y, b = blockIdx.z;
    __shared__ float Qs[64][68];      // [kdim][m]
    __shared__ float Ks[64][68];      // [kdim][n]
    __shared__ float Vs[64][68];      // [d][n]
    __shared__ float Ps[64][68];      // [m][n]; epilogue alias lred[16][65]
    const int tid = threadIdx.x;
    const int hoff = h * DK_;
    const size_t rowb = (size_t)b * S_;
    { // stage Q transposed (once)
        const int m = tid >> 2, c0 = (tid & 3) * 16;
        const float* qr = q + (rowb + m0 + m) * D_ + hoff + c0;
        #pragma unroll
        for (int cc = 0; cc < 16; cc += 4) {
            float4 t = *(const float4*)(qr + cc);
            Qs[c0+cc+0][m] = t.x; Qs[c0+cc+1][m] = t.y;
            Qs[c0+cc+2][m] = t.z; Qs[c0+cc+3][m] = t.w;
        }
    }
    const int tx = tid & 15, ty = tid >> 4;       // score: n = tx*4+j, m = ty*4+i
    const int mg = tid >> 4, dg = tid & 15;       // PV: m = mg+16i, d = dg+16j
    float o[4][4] = {};
    float lpart[4] = {};
    const int sn = tid >> 2, sc0 = (tid & 3) * 16;
    for (int kt = 0; kt < 4; kt++) {
        const int n00 = kt * 64;
        float4 kr[4], vr[4];
        { // prefetch K,V tile into regs (hides HBM latency under barrier)
            const float* kp = k + (rowb + n00 + sn) * D_ + hoff + sc0;
            const float* vp = v + (rowb + n00 + sn) * D_ + hoff + sc0;
            #pragma unroll
            for (int cc = 0; cc < 4; cc++) {
                kr[cc] = *(const float4*)(kp + cc*4);
                vr[cc] = *(const float4*)(vp + cc*4);
            }
        }
        __syncthreads();   // prev PV done reading Vs/Ps
        #pragma unroll
        for (int cc = 0; cc < 4; cc++) {
            Ks[sc0+cc*4+0][sn]=kr[cc].x; Ks[sc0+cc*4+1][sn]=kr[cc].y;
            Ks[sc0+cc*4+2][sn]=kr[cc].z; Ks[sc0+cc*4+3][sn]=kr[cc].w;
            Vs[sc0+cc*4+0][sn]=vr[cc].x; Vs[sc0+cc*4+1][sn]=vr[cc].y;
            Vs[sc0+cc*4+2][sn]=vr[cc].z; Vs[sc0+cc*4+3][sn]=vr[cc].w;
        }
        __syncthreads();
        float s[4][4] = {};
        #pragma unroll 8
        for (int kk = 0; kk < 64; kk++) {
            float4 a  = *(const float4*)&Qs[kk][ty*4];
            float4 bv = *(const float4*)&Ks[kk][tx*4];
            float ar[4] = {a.x,a.y,a.z,a.w};
            float br[4] = {bv.x,bv.y,bv.z,bv.w};
            #pragma unroll
            for (int i=0;i<4;i++)
                #pragma unroll
                for (int j=0;j<4;j++)
                    s[i][j] = fmaf(ar[i], br[j], s[i][j]);
        }
        #pragma unroll
        for (int i=0;i<4;i++) {
            #pragma unroll
            for (int j=0;j<4;j++) {
                s[i][j] = __expf(s[i][j] * 0.125f);   // 1/sqrt(64); scores bounded
                lpart[i] += s[i][j];
            }
            float4 t = {s[i][0], s[i][1], s[i][2], s[i][3]};
            *(float4*)&Ps[ty*4+i][tx*4] = t;          // s dead after this
        }
        __syncthreads();
        #pragma unroll 4
        for (int nn = 0; nn < 64; nn += 4) {
            float4 pf[4], vf[4];
            #pragma unroll
            for (int i=0;i<4;i++) pf[i] = *(const float4*)&Ps[mg+16*i][nn];
            #pragma unroll
            for (int j=0;j<4;j++) vf[j] = *(const float4*)&Vs[dg+16*j][nn];
            #pragma unroll
            for (int i=0;i<4;i++)
                #pragma unroll
                for (int j=0;j<4;j++) {
                    o[i][j] = fmaf(pf[i].x, vf[j].x, o[i][j]);
                    o[i][j] = fmaf(pf[i].y, vf[j].y, o[i][j]);
                    o[i][j] = fmaf(pf[i].z, vf[j].z, o[i][j]);
                    o[i][j] = fmaf(pf[i].w, vf[j].w, o[i][j]);
                }
        }
    }
    // l reduction via Ps alias [16][65] + normalize + store
    __syncthreads();
    float* lred = &Ps[0][0];
    #pragma unroll
    for (int i=0;i<4;i++) lred[tx*65 + ty*4 + i] = lpart[i];
    __syncthreads();
    #pragma unroll
    for (int i=0;i<4;i++) {
        const int m = mg + 16*i;
        float l = 0.f;
        #pragma unroll
        for (int t=0;t<16;t++) l += lred[t*65 + m];
        const float inv = 1.0f / l;
        float* orow = out + (rowb + m0 + m) * D_ + hoff;
        #pragma unroll
        for (int j=0;j<4;j++) orow[dg + 16*j] = o[i][j] * inv;
    }
}

// ---------------- K6: channel attention, flash. Mtile=128, Ntile=64, dk=32 -------
// Per-thread score frag 8x4 (dies before PV). 69 KB LDS, 2 blk/CU.
__global__ __launch_bounds__(256) void k6_flash(
    const float* __restrict__ qc, const float* __restrict__ kc,
    const float* __restrict__ vc, float* __restrict__ out)
{
    const int m0 = blockIdx.x * 128;
    const int h = blockIdx.y, b = blockIdx.z;
    __shared__ float Qs[32][132];     // [kdim][m]
    __shared__ float Ks[32][68];      // [kdim][n]
    __shared__ float Vs[32][68];      // [d][n]
    __shared__ float Ps[128][68];     // [m][n]; epilogue alias lred[16][129]
    const int tid = threadIdx.x;
    const int hoff = h * SK_;
    const size_t rowb = (size_t)b * D_;
    { // stage Q transposed (once)
        const int m = tid >> 1, c0 = (tid & 1) * 16;
        const float* qr = qc + (rowb + m0 + m) * S_ + hoff + c0;
        #pragma unroll
        for (int cc = 0; cc < 16; cc += 4) {
            float4 t = *(const float4*)(qr + cc);
            Qs[c0+cc+0][m] = t.x; Qs[c0+cc+1][m] = t.y;
            Qs[c0+cc+2][m] = t.z; Qs[c0+cc+3][m] = t.w;
        }
    }
    const int tx = tid & 15, ty = tid >> 4;       // score: n = tx*4+j, m = ty*8+i
    const int mg = tid >> 3, dg = tid & 7;        // PV: m = mg+32i, d = dg+8j
    float o[4][4] = {};
    float lpart[8] = {};
    const int sn = tid >> 2, sc0 = (tid & 3) * 8;
    for (int kt = 0; kt < 16; kt++) {
        const int n00 = kt * 64;
        float4 kr[2], vr[2];
        {
            const float* kp = kc + (rowb + n00 + sn) * S_ + hoff + sc0;
            const float* vp = vc + (rowb + n00 + sn) * S_ + hoff + sc0;
            kr[0] = *(const float4*)kp;     kr[1] = *(const float4*)(kp + 4);
            vr[0] = *(const float4*)vp;     vr[1] = *(const float4*)(vp + 4);
        }
        __syncthreads();   // prev PV done reading Vs/Ps
        #pragma unroll
        for (int cc = 0; cc < 2; cc++) {
            Ks[sc0+cc*4+0][sn]=kr[cc].x; Ks[sc0+cc*4+1][sn]=kr[cc].y;
            Ks[sc0+cc*4+2][sn]=kr[cc].z; Ks[sc0+cc*4+3][sn]=kr[cc].w;
            Vs[sc0+cc*4+0][sn]=vr[cc].x; Vs[sc0+cc*4+1][sn]=vr[cc].y;
            Vs[sc0+cc*4+2][sn]=vr[cc].z; Vs[sc0+cc*4+3][sn]=vr[cc].w;
        }
        __syncthreads();
        float s[8][4] = {};
        #pragma unroll 4
        for (int kk = 0; kk < 32; kk++) {
            float4 a0 = *(const float4*)&Qs[kk][ty*8];
            float4 a1 = *(const float4*)&Qs[kk][ty*8+4];
            float4 bv = *(const float4*)&Ks[kk][tx*4];
            float ar[8] = {a0.x,a0.y,a0.z,a0.w,a1.x,a1.y,a1.z,a1.w};
            float br[4] = {bv.x,bv.y,bv.z,bv.w};
            #pragma unroll
            for (int i=0;i<8;i++)
                #pragma unroll
                for (int j=0;j<4;j++)
                    s[i][j] = fmaf(ar[i], br[j], s[i][j]);
        }
        #pragma unroll
        for (int i=0;i<8;i++) {
            #pragma unroll
            for (int j=0;j<4;j++) {
                s[i][j] = __expf(s[i][j] * 0.17677669529663687f);  // 1/sqrt(32)
                lpart[i] += s[i][j];
            }
            float4 t = {s[i][0], s[i][1], s[i][2], s[i][3]};
            *(float4*)&Ps[ty*8+i][tx*4] = t;          // s dead after this
        }
        __syncthreads();
        #pragma unroll 4
        for (int nn = 0; nn < 64; nn += 4) {
            float4 pf[4], vf[4];
            #pragma unroll
            for (int i=0;i<4;i++) pf[i] = *(const float4*)&Ps[mg+32*i][nn];
            #pragma unroll
            for (int j=0;j<4;j++) vf[j] = *(const float4*)&Vs[dg+8*j][nn];
            #pragma unroll
            for (int i=0;i<4;i++)
                #pragma unroll
                for (int j=0;j<4;j++) {
                    o[i][j] = fmaf(pf[i].x, vf[j].x, o[i][j]);
                    o[i][j] = fmaf(pf[i].y, vf[j].y, o[i][j]);
                    o[i][j] = fmaf(pf[i].z, vf[j].z, o[i][j]);
                    o[i][j] = fmaf(pf[i].w, vf[j].w, o[i][j]);
                }
        }
    }
    // l reduction via Ps alias [16][129] + normalize + store
    __syncthreads();
    float* lred = &Ps[0][0];
    #pragma unroll
    for (int i=0;i<8;i++) lred[tx*129 + ty*8 + i] = lpart[i];
    __syncthreads();
    #pragma unroll
    for (int i=0;i<4;i++) {
        const int m = mg + 32*i;
        float l = 0.f;
        #pragma unroll
        for (int t=0;t<16;t++) l += lred[t*129 + m];
        const float inv = 1.0f / l;
        float* orow = out + (rowb + m0 + m) * S_ + hoff;
        #pragma unroll
        for (int j=0;j<4;j++) orow[dg + 8*j] = o[i][j] * inv;
    }
}

// ---------------- K4a: per-(b,d) stats over sequence dim ----------------
__global__ __launch_bounds__(256) void k4a_stats(
    const float* __restrict__ x, float* __restrict__ meanc, float* __restrict__ invc)
{
    const int d = blockIdx.x * 256 + threadIdx.x;
    const int b = blockIdx.y;
    const float* p = x + (size_t)b * S_ * D_ + d;
    float s = 0.f, q = 0.f;
    for (int t = 0; t < S_; t++) { float vv = p[(size_t)t * D_]; s += vv; q += vv*vv; }
    const float mean = s / (float)S_;
    const float var  = fmaxf((q - (float)S_ * mean * mean) / (float)(S_ - 1), 0.0f);
    meanc[b*D_ + d] = mean;
    invc[b*D_ + d]  = 1.0f / (sqrtf(var) + EPS_);
}

// ---------------- K4b: normalize (LN over seq) + transpose to [B,D,S] ----------
__global__ __launch_bounds__(256) void k4b_ntrans(
    const float* __restrict__ x, const float* __restrict__ meanc,
    const float* __restrict__ invc, const float* __restrict__ a_c,
    const float* __restrict__ b_c, float* __restrict__ xt)
{
    const int s0 = blockIdx.x * 64, d0 = blockIdx.y * 64, b = blockIdx.z;
    __shared__ float tile[64][65];
    const int ix = threadIdx.x & 63, iy = threadIdx.x >> 6;
    const int d = d0 + ix;
    const float mean = meanc[b*D_ + d], inv = invc[b*D_ + d];
    #pragma unroll
    for (int u = 0; u < 16; u++) {
        const int srow = iy*16 + u;
        const float vv = x[((size_t)(b*S_ + s0 + srow)) * D_ + d];
        tile[srow][ix] = a_c[s0+srow] * (vv - mean) * inv + b_c[s0+srow];
    }
    __syncthreads();
    #pragma unroll
    for (int u = 0; u < 16; u++) {
        const int drow = iy*16 + u;
        xt[((size_t)(b*D_ + d0 + drow)) * S_ + s0 + ix] = tile[ix][drow];
    }
}

// ---------------- K8: final transpose [B,D,S] -> [B,S,D] ----------------
__global__ __launch_bounds__(256) void k8_trans(
    const float* __restrict__ y, float* __restrict__ out)
{
    const int e0 = blockIdx.x * 64, d0 = blockIdx.y * 64, b = blockIdx.z;
    __shared__ float tile[64][65];
    const int ix = threadIdx.x & 63, iy = threadIdx.x >> 6;
    #pragma unroll
    for (int u = 0; u < 16; u++) {
        const int drow = iy*16 + u;
        tile[drow][ix] = y[((size_t)(b*D_ + d0 + drow)) * S_ + e0 + ix];
    }
    __syncthreads();
    #pragma unroll
    for (int u = 0; u < 16; u++) {
        const int erow = iy*16 + u;
        out[((size_t)(b*S_ + e0 + erow)) * D_ + d0 + ix] = tile[ix][erow];
    }
}

extern "C" void kernel_launch(void* const* d_in, const int* in_sizes, int n_in,
                              void* d_out, int out_size, void* d_ws, size_t ws_size,
                              hipStream_t stream)
{
    const float* x   = (const float*)d_in[0];
    const float* Wp  = (const float*)d_in[1];
    const float* bp  = (const float*)d_in[2];
    const float* Wc  = (const float*)d_in[3];
    const float* bc  = (const float*)d_in[4];
    const float* a_p = (const float*)d_in[5];
    const float* b_p = (const float*)d_in[6];
    const float* a_c = (const float*)d_in[7];
    const float* b_c = (const float*)d_in[8];
    float* out = (float*)d_out;
    float* ws  = (float*)d_ws;
    const size_t NE = (size_t)B_ * S_ * D_;

    float* R0 = ws;
    float* R1 = ws + NE;
    float* R2 = ws + 2*NE;
    float* R3 = ws + 3*NE;
    float* meanc = ws + 4*NE;
    float* invc  = meanc + (size_t)B_*D_;

    // 1) LayerNorm over channels: x -> R0
    k1_ln_p<<<dim3(B_*S_), 256, 0, stream>>>(x, a_p, b_p, R0);
    // 2) QKV projection: R0 @ Wp[n] + bp[n] -> R1,R2,R3
    mm_bias<<<dim3(D_/128, (B_*S_)/128, 3), 256, 0, stream>>>(
        R0, Wp, bp, R1, B_*S_, D_, D_, (long)D_*D_, (long)D_, (long)NE);
    // 3) positional attention (flash) -> R0
    k3_flash<<<dim3(S_/64, HP_, B_), 256, 0, stream>>>(R1, R2, R3, R0);
    // 4) LN over sequence: stats then normalize+transpose -> R1 (xt [B,D,S])
    k4a_stats<<<dim3(D_/256, B_), 256, 0, stream>>>(R0, meanc, invc);
    k4b_ntrans<<<dim3(S_/64, D_/64, B_), 256, 0, stream>>>(R0, meanc, invc, a_c, b_c, R1);
    // 5) channel QKV: R1 @ Wc[n] + bc[n] -> qc:R2, kc:R3, vc:R0
    float* qkvc[3] = {R2, R3, R0};
    for (int nn = 0; nn < 3; nn++) {
        mm_bias<<<dim3(S_/128, (B_*D_)/128, 1), 256, 0, stream>>>(
            R1, Wc + (size_t)nn*S_*S_, bc + (size_t)nn*S_, qkvc[nn],
            B_*D_, S_, S_, 0, 0, 0);
    }
    // 6) channel attention (flash) -> R1 (xcatt [B,D,S])
    k6_flash<<<dim3(D_/128, HC_, B_), 256, 0, stream>>>(R2, R3, R0, R1);
    // 7) final projection: R1 @ Wc[3] + bc[3] -> R0 (y [B,D,S])
    mm_bias<<<dim3(S_/128, (B_*D_)/128, 1), 256, 0, stream>>>(
        R1, Wc + (size_t)3*S_*S_, bc + (size_t)3*S_, R0,
        B_*D_, S_, S_, 0, 0, 0);
    // 8) transpose y -> out [B,S,D]
    k8_trans<<<dim3(S_/64, D_/64, B_), 256, 0, stream>>>(R0, out);
}

// Round 4
// 619.664 us; speedup vs baseline: 3.7842x; 1.4358x over previous
//
#include <hip/hip_runtime.h>
#include <math.h>

#define B_ 16
#define S_ 256
#define D_ 1024
#define HP_ 16
#define DK_ 64
#define HC_ 8
#define SK_ 32
#define EPS_ 1e-6f

typedef __attribute__((ext_vector_type(8))) short short8v;
typedef __attribute__((ext_vector_type(4))) float f32x4;

__device__ __forceinline__ unsigned short f2bf(float f) {
    unsigned u = __float_as_uint(f);
    u += 0x7fffu + ((u >> 16) & 1u);          // round-to-nearest-even
    return (unsigned short)(u >> 16);
}
__device__ __forceinline__ float bf2f(unsigned short h) {
    return __uint_as_float((unsigned)h << 16);
}

// ---------------- K1: LayerNorm over channels -> bf16 hi/lo split ---------------
__global__ __launch_bounds__(256) void k1_ln_p(
    const float* __restrict__ x, const float* __restrict__ a_p,
    const float* __restrict__ b_p, unsigned short* __restrict__ xh,
    unsigned short* __restrict__ xl)
{
    const int row = blockIdx.x;                  // b*S + s
    const float4* xr = (const float4*)(x + (size_t)row * D_);
    const int tid = threadIdx.x;
    float4 v = xr[tid];
    float s  = v.x + v.y + v.z + v.w;
    float sq = v.x*v.x + v.y*v.y + v.z*v.z + v.w*v.w;
    #pragma unroll
    for (int off = 32; off > 0; off >>= 1) {
        s  += __shfl_down(s, off);
        sq += __shfl_down(sq, off);
    }
    __shared__ float red[8];
    const int wid = tid >> 6, lane = tid & 63;
    if (lane == 0) { red[wid] = s; red[4 + wid] = sq; }
    __syncthreads();
    if (tid == 0) {
        float S0 = red[0] + red[1] + red[2] + red[3];
        float Q0 = red[4] + red[5] + red[6] + red[7];
        float mean = S0 / (float)D_;
        float var  = fmaxf((Q0 - (float)D_ * mean * mean) / (float)(D_ - 1), 0.0f);
        red[0] = mean;
        red[1] = 1.0f / (sqrtf(var) + EPS_);     // torch std(): unbiased; eps on std
    }
    __syncthreads();
    const float mean = red[0], inv = red[1];
    float4 a = ((const float4*)a_p)[tid];
    float4 b = ((const float4*)b_p)[tid];
    float o0 = a.x * (v.x - mean) * inv + b.x;
    float o1 = a.y * (v.y - mean) * inv + b.y;
    float o2 = a.z * (v.z - mean) * inv + b.z;
    float o3 = a.w * (v.w - mean) * inv + b.w;
    ushort4 hv, lv;
    hv.x = f2bf(o0); lv.x = f2bf(o0 - bf2f(hv.x));
    hv.y = f2bf(o1); lv.y = f2bf(o1 - bf2f(hv.y));
    hv.z = f2bf(o2); lv.z = f2bf(o2 - bf2f(hv.z));
    hv.w = f2bf(o3); lv.w = f2bf(o3 - bf2f(hv.w));
    *(ushort4*)&xh[(size_t)row * D_ + tid*4] = hv;
    *(ushort4*)&xl[(size_t)row * D_ + tid*4] = lv;
}

// ------------- Transpose + bf16-split weights: W[k][n] -> T[n][k] hi/lo ---------
__global__ __launch_bounds__(256) void tsplit(
    const float* __restrict__ W, unsigned short* __restrict__ Th,
    unsigned short* __restrict__ Tl, int K, int N)
{
    const int z = blockIdx.z;
    W  += (size_t)z * K * N;
    Th += (size_t)z * K * N;
    Tl += (size_t)z * K * N;
    const int k0 = blockIdx.x * 64, n0 = blockIdx.y * 64;
    __shared__ float tile[64][65];
    const int ix = threadIdx.x & 63, iy = threadIdx.x >> 6;
    #pragma unroll
    for (int u = 0; u < 16; u++) {
        const int kk = iy*16 + u;
        tile[kk][ix] = W[(size_t)(k0+kk)*N + n0 + ix];
    }
    __syncthreads();
    #pragma unroll
    for (int u = 0; u < 16; u++) {
        const int nn = iy*16 + u;
        const float v = tile[ix][nn];
        const unsigned short h = f2bf(v);
        Th[(size_t)(n0+nn)*K + k0 + ix] = h;
        Tl[(size_t)(n0+nn)*K + k0 + ix] = f2bf(v - bf2f(h));
    }
}

// ------------- Split-bf16 MFMA GEMM: C = A*B^T + bias, A hi/lo, B^T hi/lo -------
// A: [M][K] bf16 hi/lo. B: [N][K] bf16 hi/lo (pre-transposed). C: f32 [M][N].
// 128x128 tile, 4 waves of 64x64, K-step 32, mfma_f32_16x16x32_bf16 x3 (split).
__global__ __launch_bounds__(256) void mm_mfma(
    const unsigned short* __restrict__ Ah, const unsigned short* __restrict__ Al,
    const unsigned short* __restrict__ Bh, const unsigned short* __restrict__ Bl,
    const float* __restrict__ bias, float* __restrict__ C,
    int M, int N, int K, long sB, long sBias, long sC)
{
    const int z = blockIdx.z;
    Bh   += (size_t)z * sB;
    Bl   += (size_t)z * sB;
    bias += (size_t)z * sBias;
    C    += (size_t)z * sC;
    const int n0 = blockIdx.x * 128, m0 = blockIdx.y * 128;
    __shared__ unsigned short Ash[128][40];   // pitch 40 bf16: even bank spread
    __shared__ unsigned short Als[128][40];
    __shared__ unsigned short Bsh[128][40];
    __shared__ unsigned short Bls[128][40];
    const int tid = threadIdx.x;
    const int wave = tid >> 6, lane = tid & 63;
    const int wm = wave & 1, wn = wave >> 1;
    const int lrow = lane & 15, quad = lane >> 4;
    const int sr = tid >> 1, sko = (tid & 1) * 16;   // staging: row, k-offset
    f32x4 acc[4][4];
    #pragma unroll
    for (int j = 0; j < 4; j++) {
        const float bv = bias[n0 + wn*64 + j*16 + lrow];
        #pragma unroll
        for (int i = 0; i < 4; i++) {
            acc[i][j][0] = bv; acc[i][j][1] = bv; acc[i][j][2] = bv; acc[i][j][3] = bv;
        }
    }
    for (int k0 = 0; k0 < K; k0 += 32) {
        const size_t ga = (size_t)(m0 + sr) * K + k0 + sko;
        const size_t gb = (size_t)(n0 + sr) * K + k0 + sko;
        uint4 ah0 = *(const uint4*)&Ah[ga];
        uint4 ah1 = *(const uint4*)&Ah[ga + 8];
        uint4 al0 = *(const uint4*)&Al[ga];
        uint4 al1 = *(const uint4*)&Al[ga + 8];
        uint4 bh0 = *(const uint4*)&Bh[gb];
        uint4 bh1 = *(const uint4*)&Bh[gb + 8];
        uint4 bl0 = *(const uint4*)&Bl[gb];
        uint4 bl1 = *(const uint4*)&Bl[gb + 8];
        __syncthreads();             // prev iter fragment reads done
        *(uint4*)&Ash[sr][sko]     = ah0;
        *(uint4*)&Ash[sr][sko + 8] = ah1;
        *(uint4*)&Als[sr][sko]     = al0;
        *(uint4*)&Als[sr][sko + 8] = al1;
        *(uint4*)&Bsh[sr][sko]     = bh0;
        *(uint4*)&Bsh[sr][sko + 8] = bh1;
        *(uint4*)&Bls[sr][sko]     = bl0;
        *(uint4*)&Bls[sr][sko + 8] = bl1;
        __syncthreads();
        short8v bhf[4], blf[4];
        #pragma unroll
        for (int j = 0; j < 4; j++) {
            bhf[j] = *(const short8v*)&Bsh[wn*64 + j*16 + lrow][quad*8];
            blf[j] = *(const short8v*)&Bls[wn*64 + j*16 + lrow][quad*8];
        }
        #pragma unroll
        for (int i = 0; i < 4; i++) {
            short8v ahf = *(const short8v*)&Ash[wm*64 + i*16 + lrow][quad*8];
            short8v alf = *(const short8v*)&Als[wm*64 + i*16 + lrow][quad*8];
            #pragma unroll
            for (int j = 0; j < 4; j++) {
                acc[i][j] = __builtin_amdgcn_mfma_f32_16x16x32_bf16(ahf, bhf[j], acc[i][j], 0, 0, 0);
                acc[i][j] = __builtin_amdgcn_mfma_f32_16x16x32_bf16(ahf, blf[j], acc[i][j], 0, 0, 0);
                acc[i][j] = __builtin_amdgcn_mfma_f32_16x16x32_bf16(alf, bhf[j], acc[i][j], 0, 0, 0);
            }
        }
    }
    // C/D layout: col = lane&15, row = quad*4 + reg  [m89/m91-verified]
    #pragma unroll
    for (int i = 0; i < 4; i++) {
        const int mrow = m0 + wm*64 + i*16 + quad*4;
        #pragma unroll
        for (int j = 0; j < 4; j++) {
            const int ncol = n0 + wn*64 + j*16 + lrow;
            #pragma unroll
            for (int r = 0; r < 4; r++)
                C[(size_t)(mrow + r) * N + ncol] = acc[i][j][r];
        }
    }
}

// ---------------- K3: positional attention, flash. Mtile=64, Ntile=64, dk=64 -----
__global__ __launch_bounds__(256) void k3_flash(
    const float* __restrict__ q, const float* __restrict__ k,
    const float* __restrict__ v, float* __restrict__ out)
{
    const int m0 = blockIdx.x * 64;
    const int h = blockIdx.y, b = blockIdx.z;
    __shared__ float Qs[64][68];      // [kdim][m]
    __shared__ float Ks[64][68];      // [kdim][n]
    __shared__ float Vs[64][68];      // [d][n]
    __shared__ float Ps[64][68];      // [m][n]; epilogue alias lred[16][65]
    const int tid = threadIdx.x;
    const int hoff = h * DK_;
    const size_t rowb = (size_t)b * S_;
    { // stage Q transposed (once)
        const int m = tid >> 2, c0 = (tid & 3) * 16;
        const float* qr = q + (rowb + m0 + m) * D_ + hoff + c0;
        #pragma unroll
        for (int cc = 0; cc < 16; cc += 4) {
            float4 t = *(const float4*)(qr + cc);
            Qs[c0+cc+0][m] = t.x; Qs[c0+cc+1][m] = t.y;
            Qs[c0+cc+2][m] = t.z; Qs[c0+cc+3][m] = t.w;
        }
    }
    const int tx = tid & 15, ty = tid >> 4;       // score: n = tx*4+j, m = ty*4+i
    const int mg = tid >> 4, dg = tid & 15;       // PV: m = mg+16i, d = dg+16j
    float o[4][4] = {};
    float lpart[4] = {};
    const int sn = tid >> 2, sc0 = (tid & 3) * 16;
    for (int kt = 0; kt < 4; kt++) {
        const int n00 = kt * 64;
        float4 kr[4], vr[4];
        {
            const float* kp = k + (rowb + n00 + sn) * D_ + hoff + sc0;
            const float* vp = v + (rowb + n00 + sn) * D_ + hoff + sc0;
            #pragma unroll
            for (int cc = 0; cc < 4; cc++) {
                kr[cc] = *(const float4*)(kp + cc*4);
                vr[cc] = *(const float4*)(vp + cc*4);
            }
        }
        __syncthreads();
        #pragma unroll
        for (int cc = 0; cc < 4; cc++) {
            Ks[sc0+cc*4+0][sn]=kr[cc].x; Ks[sc0+cc*4+1][sn]=kr[cc].y;
            Ks[sc0+cc*4+2][sn]=kr[cc].z; Ks[sc0+cc*4+3][sn]=kr[cc].w;
            Vs[sc0+cc*4+0][sn]=vr[cc].x; Vs[sc0+cc*4+1][sn]=vr[cc].y;
            Vs[sc0+cc*4+2][sn]=vr[cc].z; Vs[sc0+cc*4+3][sn]=vr[cc].w;
        }
        __syncthreads();
        float s[4][4] = {};
        #pragma unroll 8
        for (int kk = 0; kk < 64; kk++) {
            float4 a  = *(const float4*)&Qs[kk][ty*4];
            float4 bv = *(const float4*)&Ks[kk][tx*4];
            float ar[4] = {a.x,a.y,a.z,a.w};
            float br[4] = {bv.x,bv.y,bv.z,bv.w};
            #pragma unroll
            for (int i=0;i<4;i++)
                #pragma unroll
                for (int j=0;j<4;j++)
                    s[i][j] = fmaf(ar[i], br[j], s[i][j]);
        }
        #pragma unroll
        for (int i=0;i<4;i++) {
            #pragma unroll
            for (int j=0;j<4;j++) {
                s[i][j] = __expf(s[i][j] * 0.125f);   // 1/sqrt(64); scores bounded
                lpart[i] += s[i][j];
            }
            float4 t = {s[i][0], s[i][1], s[i][2], s[i][3]};
            *(float4*)&Ps[ty*4+i][tx*4] = t;          // s dead after this
        }
        __syncthreads();
        #pragma unroll 4
        for (int nn = 0; nn < 64; nn += 4) {
            float4 pf[4], vf[4];
            #pragma unroll
            for (int i=0;i<4;i++) pf[i] = *(const float4*)&Ps[mg+16*i][nn];
            #pragma unroll
            for (int j=0;j<4;j++) vf[j] = *(const float4*)&Vs[dg+16*j][nn];
            #pragma unroll
            for (int i=0;i<4;i++)
                #pragma unroll
                for (int j=0;j<4;j++) {
                    o[i][j] = fmaf(pf[i].x, vf[j].x, o[i][j]);
                    o[i][j] = fmaf(pf[i].y, vf[j].y, o[i][j]);
                    o[i][j] = fmaf(pf[i].z, vf[j].z, o[i][j]);
                    o[i][j] = fmaf(pf[i].w, vf[j].w, o[i][j]);
                }
        }
    }
    __syncthreads();
    float* lred = &Ps[0][0];
    #pragma unroll
    for (int i=0;i<4;i++) lred[tx*65 + ty*4 + i] = lpart[i];
    __syncthreads();
    #pragma unroll
    for (int i=0;i<4;i++) {
        const int m = mg + 16*i;
        float l = 0.f;
        #pragma unroll
        for (int t=0;t<16;t++) l += lred[t*65 + m];
        const float inv = 1.0f / l;
        float* orow = out + (rowb + m0 + m) * D_ + hoff;
        #pragma unroll
        for (int j=0;j<4;j++) orow[dg + 16*j] = o[i][j] * inv;
    }
}

// ---------------- K6: channel attention, flash -> bf16 hi/lo out -----------------
__global__ __launch_bounds__(256) void k6_flash(
    const float* __restrict__ qc, const float* __restrict__ kc,
    const float* __restrict__ vc, unsigned short* __restrict__ oh,
    unsigned short* __restrict__ ol)
{
    const int m0 = blockIdx.x * 128;
    const int h = blockIdx.y, b = blockIdx.z;
    __shared__ float Qs[32][132];     // [kdim][m]
    __shared__ float Ks[32][68];      // [kdim][n]
    __shared__ float Vs[32][68];      // [d][n]
    __shared__ float Ps[128][68];     // [m][n]; epilogue alias lred[16][129]
    const int tid = threadIdx.x;
    const int hoff = h * SK_;
    const size_t rowb = (size_t)b * D_;
    { // stage Q transposed (once)
        const int m = tid >> 1, c0 = (tid & 1) * 16;
        const float* qr = qc + (rowb + m0 + m) * S_ + hoff + c0;
        #pragma unroll
        for (int cc = 0; cc < 16; cc += 4) {
            float4 t = *(const float4*)(qr + cc);
            Qs[c0+cc+0][m] = t.x; Qs[c0+cc+1][m] = t.y;
            Qs[c0+cc+2][m] = t.z; Qs[c0+cc+3][m] = t.w;
        }
    }
    const int tx = tid & 15, ty = tid >> 4;       // score: n = tx*4+j, m = ty*8+i
    const int mg = tid >> 3, dg = tid & 7;        // PV: m = mg+32i, d = dg+8j
    float o[4][4] = {};
    float lpart[8] = {};
    const int sn = tid >> 2, sc0 = (tid & 3) * 8;
    for (int kt = 0; kt < 16; kt++) {
        const int n00 = kt * 64;
        float4 kr[2], vr[2];
        {
            const float* kp = kc + (rowb + n00 + sn) * S_ + hoff + sc0;
            const float* vp = vc + (rowb + n00 + sn) * S_ + hoff + sc0;
            kr[0] = *(const float4*)kp;     kr[1] = *(const float4*)(kp + 4);
            vr[0] = *(const float4*)vp;     vr[1] = *(const float4*)(vp + 4);
        }
        __syncthreads();
        #pragma unroll
        for (int cc = 0; cc < 2; cc++) {
            Ks[sc0+cc*4+0][sn]=kr[cc].x; Ks[sc0+cc*4+1][sn]=kr[cc].y;
            Ks[sc0+cc*4+2][sn]=kr[cc].z; Ks[sc0+cc*4+3][sn]=kr[cc].w;
            Vs[sc0+cc*4+0][sn]=vr[cc].x; Vs[sc0+cc*4+1][sn]=vr[cc].y;
            Vs[sc0+cc*4+2][sn]=vr[cc].z; Vs[sc0+cc*4+3][sn]=vr[cc].w;
        }
        __syncthreads();
        float s[8][4] = {};
        #pragma unroll 4
        for (int kk = 0; kk < 32; kk++) {
            float4 a0 = *(const float4*)&Qs[kk][ty*8];
            float4 a1 = *(const float4*)&Qs[kk][ty*8+4];
            float4 bv = *(const float4*)&Ks[kk][tx*4];
            float ar[8] = {a0.x,a0.y,a0.z,a0.w,a1.x,a1.y,a1.z,a1.w};
            float br[4] = {bv.x,bv.y,bv.z,bv.w};
            #pragma unroll
            for (int i=0;i<8;i++)
                #pragma unroll
                for (int j=0;j<4;j++)
                    s[i][j] = fmaf(ar[i], br[j], s[i][j]);
        }
        #pragma unroll
        for (int i=0;i<8;i++) {
            #pragma unroll
            for (int j=0;j<4;j++) {
                s[i][j] = __expf(s[i][j] * 0.17677669529663687f);  // 1/sqrt(32)
                lpart[i] += s[i][j];
            }
            float4 t = {s[i][0], s[i][1], s[i][2], s[i][3]};
            *(float4*)&Ps[ty*8+i][tx*4] = t;          // s dead after this
        }
        __syncthreads();
        #pragma unroll 4
        for (int nn = 0; nn < 64; nn += 4) {
            float4 pf[4], vf[4];
            #pragma unroll
            for (int i=0;i<4;i++) pf[i] = *(const float4*)&Ps[mg+32*i][nn];
            #pragma unroll
            for (int j=0;j<4;j++) vf[j] = *(const float4*)&Vs[dg+8*j][nn];
            #pragma unroll
            for (int i=0;i<4;i++)
                #pragma unroll
                for (int j=0;j<4;j++) {
                    o[i][j] = fmaf(pf[i].x, vf[j].x, o[i][j]);
                    o[i][j] = fmaf(pf[i].y, vf[j].y, o[i][j]);
                    o[i][j] = fmaf(pf[i].z, vf[j].z, o[i][j]);
                    o[i][j] = fmaf(pf[i].w, vf[j].w, o[i][j]);
                }
        }
    }
    __syncthreads();
    float* lred = &Ps[0][0];
    #pragma unroll
    for (int i=0;i<8;i++) lred[tx*129 + ty*8 + i] = lpart[i];
    __syncthreads();
    #pragma unroll
    for (int i=0;i<4;i++) {
        const int m = mg + 32*i;
        float l = 0.f;
        #pragma unroll
        for (int t=0;t<16;t++) l += lred[t*129 + m];
        const float inv = 1.0f / l;
        const size_t obase = (rowb + m0 + m) * S_ + hoff;
        #pragma unroll
        for (int j=0;j<4;j++) {
            const float val = o[i][j] * inv;
            const unsigned short hh = f2bf(val);
            oh[obase + dg + 8*j] = hh;
            ol[obase + dg + 8*j] = f2bf(val - bf2f(hh));
        }
    }
}

// ---------------- K4a: per-(b,d) stats over sequence dim ----------------
__global__ __launch_bounds__(256) void k4a_stats(
    const float* __restrict__ x, float* __restrict__ meanc, float* __restrict__ invc)
{
    const int d = blockIdx.x * 256 + threadIdx.x;
    const int b = blockIdx.y;
    const float* p = x + (size_t)b * S_ * D_ + d;
    float s = 0.f, q = 0.f;
    for (int t = 0; t < S_; t++) { float vv = p[(size_t)t * D_]; s += vv; q += vv*vv; }
    const float mean = s / (float)S_;
    const float var  = fmaxf((q - (float)S_ * mean * mean) / (float)(S_ - 1), 0.0f);
    meanc[b*D_ + d] = mean;
    invc[b*D_ + d]  = 1.0f / (sqrtf(var) + EPS_);
}

// ------- K4b: LN over seq + transpose to [B,D,S], output bf16 hi/lo split --------
__global__ __launch_bounds__(256) void k4b_ntrans(
    const float* __restrict__ x, const float* __restrict__ meanc,
    const float* __restrict__ invc, const float* __restrict__ a_c,
    const float* __restrict__ b_c, unsigned short* __restrict__ xth,
    unsigned short* __restrict__ xtl)
{
    const int s0 = blockIdx.x * 64, d0 = blockIdx.y * 64, b = blockIdx.z;
    __shared__ float tile[64][65];
    const int ix = threadIdx.x & 63, iy = threadIdx.x >> 6;
    const int d = d0 + ix;
    const float mean = meanc[b*D_ + d], inv = invc[b*D_ + d];
    #pragma unroll
    for (int u = 0; u < 16; u++) {
        const int srow = iy*16 + u;
        const float vv = x[((size_t)(b*S_ + s0 + srow)) * D_ + d];
        tile[srow][ix] = a_c[s0+srow] * (vv - mean) * inv + b_c[s0+srow];
    }
    __syncthreads();
    #pragma unroll
    for (int u = 0; u < 16; u++) {
        const int drow = iy*16 + u;
        const float vv = tile[ix][drow];
        const unsigned short h = f2bf(vv);
        const size_t idx = ((size_t)(b*D_ + d0 + drow)) * S_ + s0 + ix;
        xth[idx] = h;
        xtl[idx] = f2bf(vv - bf2f(h));
    }
}

// ---------------- K8: final transpose [B,D,S] -> [B,S,D] ----------------
__global__ __launch_bounds__(256) void k8_trans(
    const float* __restrict__ y, float* __restrict__ out)
{
    const int e0 = blockIdx.x * 64, d0 = blockIdx.y * 64, b = blockIdx.z;
    __shared__ float tile[64][65];
    const int ix = threadIdx.x & 63, iy = threadIdx.x >> 6;
    #pragma unroll
    for (int u = 0; u < 16; u++) {
        const int drow = iy*16 + u;
        tile[drow][ix] = y[((size_t)(b*D_ + d0 + drow)) * S_ + e0 + ix];
    }
    __syncthreads();
    #pragma unroll
    for (int u = 0; u < 16; u++) {
        const int erow = iy*16 + u;
        out[((size_t)(b*S_ + e0 + erow)) * D_ + d0 + ix] = tile[ix][erow];
    }
}

extern "C" void kernel_launch(void* const* d_in, const int* in_sizes, int n_in,
                              void* d_out, int out_size, void* d_ws, size_t ws_size,
                              hipStream_t stream)
{
    const float* x   = (const float*)d_in[0];
    const float* Wp  = (const float*)d_in[1];
    const float* bp  = (const float*)d_in[2];
    const float* Wc  = (const float*)d_in[3];
    const float* bc  = (const float*)d_in[4];
    const float* a_p = (const float*)d_in[5];
    const float* b_p = (const float*)d_in[6];
    const float* a_c = (const float*)d_in[7];
    const float* b_c = (const float*)d_in[8];
    float* out = (float*)d_out;
    float* ws  = (float*)d_ws;
    const size_t NE = (size_t)B_ * S_ * D_;     // 4,194,304

    float* S0 = ws;             // xp-bf16 -> attn f32 -> vc f32 -> y f32
    float* S1 = ws + NE;        // q -> xt-bf16 -> xcatt-bf16
    float* S2 = ws + 2*NE;      // k -> qc
    float* S3 = ws + 3*NE;      // v -> kc
    float* meanc = ws + 4*NE;
    float* invc  = meanc + (size_t)B_*D_;
    unsigned short* SW = (unsigned short*)(invc + (size_t)B_*D_);

    const size_t baseBytes  = (4*NE + 2*(size_t)B_*D_) * sizeof(float);
    const size_t bigWBytes  = (size_t)3 * D_ * D_ * 2 * sizeof(unsigned short) * 2 / 2; // hi+lo
    const bool big = ws_size >= baseBytes + (size_t)2 * 3 * D_ * D_ * sizeof(unsigned short) * 2;

    unsigned short* xh = (unsigned short*)S0;
    unsigned short* xl = xh + NE;

    // 1) LayerNorm over channels -> bf16 hi/lo
    k1_ln_p<<<dim3(B_*S_), 256, 0, stream>>>(x, a_p, b_p, xh, xl);

    // 2) QKV projection via split-bf16 MFMA -> q:S1, k:S2, v:S3 (f32)
    if (big) {
        unsigned short* WTh = SW;
        unsigned short* WTl = WTh + (size_t)3 * D_ * D_;
        tsplit<<<dim3(D_/64, D_/64, 3), 256, 0, stream>>>(Wp, WTh, WTl, D_, D_);
        mm_mfma<<<dim3(D_/128, (B_*S_)/128, 3), 256, 0, stream>>>(
            xh, xl, WTh, WTl, bp, S1,
            B_*S_, D_, D_, (long)D_*D_, (long)D_, (long)NE);
    } else {
        unsigned short* WTh = SW;
        unsigned short* WTl = WTh + (size_t)D_ * D_;
        for (int z = 0; z < 3; z++) {
            tsplit<<<dim3(D_/64, D_/64, 1), 256, 0, stream>>>(
                Wp + (size_t)z*D_*D_, WTh, WTl, D_, D_);
            mm_mfma<<<dim3(D_/128, (B_*S_)/128, 1), 256, 0, stream>>>(
                xh, xl, WTh, WTl, bp + (size_t)z*D_, S1 + (size_t)z*NE,
                B_*S_, D_, D_, 0, 0, 0);
        }
    }

    // 3) positional attention (flash, f32) -> S0
    k3_flash<<<dim3(S_/64, HP_, B_), 256, 0, stream>>>(S1, S2, S3, S0);

    // 4) LN over sequence -> xt bf16 hi/lo in S1 ([B*D][S])
    k4a_stats<<<dim3(D_/256, B_), 256, 0, stream>>>(S0, meanc, invc);
    unsigned short* xth = (unsigned short*)S1;
    unsigned short* xtl = xth + NE;
    k4b_ntrans<<<dim3(S_/64, D_/64, B_), 256, 0, stream>>>(
        S0, meanc, invc, a_c, b_c, xth, xtl);

    // 5) channel weights transpose+split (WpT dead now) + channel QKV mms
    unsigned short* WcTh = SW;
    unsigned short* WcTl = WcTh + (size_t)4 * S_ * S_;
    tsplit<<<dim3(S_/64, S_/64, 4), 256, 0, stream>>>(Wc, WcTh, WcTl, S_, S_);
    float* qkvc[3] = {S2, S3, S0};
    for (int nn = 0; nn < 3; nn++) {
        mm_mfma<<<dim3(S_/128, (B_*D_)/128, 1), 256, 0, stream>>>(
            xth, xtl, WcTh + (size_t)nn*S_*S_, WcTl + (size_t)nn*S_*S_,
            bc + (size_t)nn*S_, qkvc[nn], B_*D_, S_, S_, 0, 0, 0);
    }

    // 6) channel attention (flash) -> xcatt bf16 hi/lo in S1
    unsigned short* xch = (unsigned short*)S1;
    unsigned short* xcl = xch + NE;
    k6_flash<<<dim3(D_/128, HC_, B_), 256, 0, stream>>>(S2, S3, S0, xch, xcl);

    // 7) final projection -> y f32 in S0
    mm_mfma<<<dim3(S_/128, (B_*D_)/128, 1), 256, 0, stream>>>(
        xch, xcl, WcTh + (size_t)3*S_*S_, WcTl + (size_t)3*S_*S_,
        bc + (size_t)3*S_, S0, B_*D_, S_, S_, 0, 0, 0);

    // 8) transpose y -> out [B,S,D]
    k8_trans<<<dim3(S_/64, D_/64, B_), 256, 0, stream>>>(S0, out);
}

// Round 5
// 414.005 us; speedup vs baseline: 5.6641x; 1.4968x over previous
//
#include <hip/hip_runtime.h>
#include <math.h>

#define B_ 16
#define S_ 256
#define D_ 1024
#define HP_ 16
#define DK_ 64
#define HC_ 8
#define SK_ 32
#define EPS_ 1e-6f

typedef __attribute__((ext_vector_type(8))) short short8v;
typedef __attribute__((ext_vector_type(4))) float f32x4;

__device__ __forceinline__ unsigned short f2bf(float f) {
    unsigned u = __float_as_uint(f);
    u += 0x7fffu + ((u >> 16) & 1u);          // round-to-nearest-even
    return (unsigned short)(u >> 16);
}
__device__ __forceinline__ float bf2f(unsigned short h) {
    return __uint_as_float((unsigned)h << 16);
}

// ---------------- K1: LayerNorm over channels -> bf16 hi/lo split ---------------
__global__ __launch_bounds__(256) void k1_ln_p(
    const float* __restrict__ x, const float* __restrict__ a_p,
    const float* __restrict__ b_p, unsigned short* __restrict__ xh,
    unsigned short* __restrict__ xl)
{
    const int row = blockIdx.x;                  // b*S + s
    const float4* xr = (const float4*)(x + (size_t)row * D_);
    const int tid = threadIdx.x;
    float4 v = xr[tid];
    float s  = v.x + v.y + v.z + v.w;
    float sq = v.x*v.x + v.y*v.y + v.z*v.z + v.w*v.w;
    #pragma unroll
    for (int off = 32; off > 0; off >>= 1) {
        s  += __shfl_down(s, off);
        sq += __shfl_down(sq, off);
    }
    __shared__ float red[8];
    const int wid = tid >> 6, lane = tid & 63;
    if (lane == 0) { red[wid] = s; red[4 + wid] = sq; }
    __syncthreads();
    if (tid == 0) {
        float S0 = red[0] + red[1] + red[2] + red[3];
        float Q0 = red[4] + red[5] + red[6] + red[7];
        float mean = S0 / (float)D_;
        float var  = fmaxf((Q0 - (float)D_ * mean * mean) / (float)(D_ - 1), 0.0f);
        red[0] = mean;
        red[1] = 1.0f / (sqrtf(var) + EPS_);     // torch std(): unbiased; eps on std
    }
    __syncthreads();
    const float mean = red[0], inv = red[1];
    float4 a = ((const float4*)a_p)[tid];
    float4 b = ((const float4*)b_p)[tid];
    float o0 = a.x * (v.x - mean) * inv + b.x;
    float o1 = a.y * (v.y - mean) * inv + b.y;
    float o2 = a.z * (v.z - mean) * inv + b.z;
    float o3 = a.w * (v.w - mean) * inv + b.w;
    ushort4 hv, lv;
    hv.x = f2bf(o0); lv.x = f2bf(o0 - bf2f(hv.x));
    hv.y = f2bf(o1); lv.y = f2bf(o1 - bf2f(hv.y));
    hv.z = f2bf(o2); lv.z = f2bf(o2 - bf2f(hv.z));
    hv.w = f2bf(o3); lv.w = f2bf(o3 - bf2f(hv.w));
    *(ushort4*)&xh[(size_t)row * D_ + tid*4] = hv;
    *(ushort4*)&xl[(size_t)row * D_ + tid*4] = lv;
}

// ------------- Transpose + bf16-split weights: W[k][n] -> T[n][k] hi/lo ---------
__global__ __launch_bounds__(256) void tsplit(
    const float* __restrict__ W, unsigned short* __restrict__ Th,
    unsigned short* __restrict__ Tl, int K, int N)
{
    const int z = blockIdx.z;
    W  += (size_t)z * K * N;
    Th += (size_t)z * K * N;
    Tl += (size_t)z * K * N;
    const int k0 = blockIdx.x * 64, n0 = blockIdx.y * 64;
    __shared__ float tile[64][65];
    const int ix = threadIdx.x & 63, iy = threadIdx.x >> 6;
    #pragma unroll
    for (int u = 0; u < 16; u++) {
        const int kk = iy*16 + u;
        tile[kk][ix] = W[(size_t)(k0+kk)*N + n0 + ix];
    }
    __syncthreads();
    #pragma unroll
    for (int u = 0; u < 16; u++) {
        const int nn = iy*16 + u;
        const float v = tile[ix][nn];
        const unsigned short h = f2bf(v);
        Th[(size_t)(n0+nn)*K + k0 + ix] = h;
        Tl[(size_t)(n0+nn)*K + k0 + ix] = f2bf(v - bf2f(h));
    }
}

// ------------- Split-bf16 MFMA GEMM: C = A*B^T + bias ---------------------------
// OUTMODE 0: f32 row-major. 1: bf16 hi/lo row-major. 2: bf16 hi/lo transposed
// per batch of TB rows: out[b][n][t], b=m/TB, t=m%TB.
template<int OUTMODE>
__global__ __launch_bounds__(256) void mm_mfma(
    const unsigned short* __restrict__ Ah, const unsigned short* __restrict__ Al,
    const unsigned short* __restrict__ Bh, const unsigned short* __restrict__ Bl,
    const float* __restrict__ bias, void* __restrict__ Cout,
    int M, int N, int K, long sB, long sBias, long sC, long loff, int TB)
{
    const int z = blockIdx.z;
    Bh   += (size_t)z * sB;
    Bl   += (size_t)z * sB;
    bias += (size_t)z * sBias;
    const int n0 = blockIdx.x * 128, m0 = blockIdx.y * 128;
    __shared__ __align__(16) unsigned short Ash[128][40];
    __shared__ __align__(16) unsigned short Als[128][40];
    __shared__ __align__(16) unsigned short Bsh[128][40];
    __shared__ __align__(16) unsigned short Bls[128][40];
    const int tid = threadIdx.x;
    const int wave = tid >> 6, lane = tid & 63;
    const int wm = wave & 1, wn = wave >> 1;
    const int lrow = lane & 15, quad = lane >> 4;
    const int sr = tid >> 1, sko = (tid & 1) * 16;
    f32x4 acc[4][4];
    #pragma unroll
    for (int j = 0; j < 4; j++) {
        const float bv = bias[n0 + wn*64 + j*16 + lrow];
        #pragma unroll
        for (int i = 0; i < 4; i++) {
            acc[i][j][0] = bv; acc[i][j][1] = bv; acc[i][j][2] = bv; acc[i][j][3] = bv;
        }
    }
    for (int k0 = 0; k0 < K; k0 += 32) {
        const size_t ga = (size_t)(m0 + sr) * K + k0 + sko;
        const size_t gb = (size_t)(n0 + sr) * K + k0 + sko;
        uint4 ah0 = *(const uint4*)&Ah[ga];
        uint4 ah1 = *(const uint4*)&Ah[ga + 8];
        uint4 al0 = *(const uint4*)&Al[ga];
        uint4 al1 = *(const uint4*)&Al[ga + 8];
        uint4 bh0 = *(const uint4*)&Bh[gb];
        uint4 bh1 = *(const uint4*)&Bh[gb + 8];
        uint4 bl0 = *(const uint4*)&Bl[gb];
        uint4 bl1 = *(const uint4*)&Bl[gb + 8];
        __syncthreads();
        *(uint4*)&Ash[sr][sko]     = ah0;
        *(uint4*)&Ash[sr][sko + 8] = ah1;
        *(uint4*)&Als[sr][sko]     = al0;
        *(uint4*)&Als[sr][sko + 8] = al1;
        *(uint4*)&Bsh[sr][sko]     = bh0;
        *(uint4*)&Bsh[sr][sko + 8] = bh1;
        *(uint4*)&Bls[sr][sko]     = bl0;
        *(uint4*)&Bls[sr][sko + 8] = bl1;
        __syncthreads();
        short8v bhf[4], blf[4];
        #pragma unroll
        for (int j = 0; j < 4; j++) {
            bhf[j] = *(const short8v*)&Bsh[wn*64 + j*16 + lrow][quad*8];
            blf[j] = *(const short8v*)&Bls[wn*64 + j*16 + lrow][quad*8];
        }
        #pragma unroll
        for (int i = 0; i < 4; i++) {
            short8v ahf = *(const short8v*)&Ash[wm*64 + i*16 + lrow][quad*8];
            short8v alf = *(const short8v*)&Als[wm*64 + i*16 + lrow][quad*8];
            #pragma unroll
            for (int j = 0; j < 4; j++) {
                acc[i][j] = __builtin_amdgcn_mfma_f32_16x16x32_bf16(ahf, bhf[j], acc[i][j], 0, 0, 0);
                acc[i][j] = __builtin_amdgcn_mfma_f32_16x16x32_bf16(ahf, blf[j], acc[i][j], 0, 0, 0);
                acc[i][j] = __builtin_amdgcn_mfma_f32_16x16x32_bf16(alf, bhf[j], acc[i][j], 0, 0, 0);
            }
        }
    }
    // C/D layout: col = lane&15, row = quad*4 + reg  [m89/m91-verified]
    #pragma unroll
    for (int i = 0; i < 4; i++) {
        const int mrow = m0 + wm*64 + i*16 + quad*4;
        #pragma unroll
        for (int j = 0; j < 4; j++) {
            const int ncol = n0 + wn*64 + j*16 + lrow;
            if (OUTMODE == 0) {
                float* C = (float*)Cout + (size_t)z * sC;
                #pragma unroll
                for (int r = 0; r < 4; r++)
                    C[(size_t)(mrow + r) * N + ncol] = acc[i][j][r];
            } else if (OUTMODE == 1) {
                unsigned short* Ch = (unsigned short*)Cout + (size_t)z * sC;
                unsigned short* Cl = Ch + loff;
                #pragma unroll
                for (int r = 0; r < 4; r++) {
                    const float val = acc[i][j][r];
                    const unsigned short hh = f2bf(val);
                    Ch[(size_t)(mrow + r) * N + ncol] = hh;
                    Cl[(size_t)(mrow + r) * N + ncol] = f2bf(val - bf2f(hh));
                }
            } else {
                unsigned short* Ch = (unsigned short*)Cout;
                unsigned short* Cl = Ch + loff;
                const int bidx = mrow / TB, t0 = mrow % TB;
                const size_t ad = (size_t)bidx * N * TB + (size_t)ncol * TB + t0;
                ushort4 hv, lv;
                float v0 = acc[i][j][0], v1 = acc[i][j][1], v2 = acc[i][j][2], v3 = acc[i][j][3];
                hv.x = f2bf(v0); lv.x = f2bf(v0 - bf2f(hv.x));
                hv.y = f2bf(v1); lv.y = f2bf(v1 - bf2f(hv.y));
                hv.z = f2bf(v2); lv.z = f2bf(v2 - bf2f(hv.z));
                hv.w = f2bf(v3); lv.w = f2bf(v3 - bf2f(hv.w));
                *(ushort4*)&Ch[ad] = hv;
                *(ushort4*)&Cl[ad] = lv;
            }
        }
    }
}

// ------- K3: positional attention, split-bf16 MFMA flash. Mtile=64, Ntile=64 ----
// dk=64 (2 k-steps). Wave owns 16 rows. P round-trips LDS as bf16 hi/lo.
__global__ __launch_bounds__(256) void k3_mfma(
    const unsigned short* __restrict__ qh, const unsigned short* __restrict__ ql,
    const unsigned short* __restrict__ kh, const unsigned short* __restrict__ kl,
    const unsigned short* __restrict__ vth, const unsigned short* __restrict__ vtl,
    float* __restrict__ out)
{
    const int m0 = blockIdx.x * 64;
    const int h = blockIdx.y, b = blockIdx.z;
    const int hoff = h * DK_;
    const size_t rowb = (size_t)b * S_;
    __shared__ __align__(16) unsigned short Ksh[64][72], Ksl[64][72];
    __shared__ __align__(16) unsigned short VTh[64][72], VTl[64][72];
    __shared__ __align__(16) unsigned short Psh[64][40], Psl[64][40];
    const int tid = threadIdx.x;
    const int w = tid >> 6, lane = tid & 63;
    const int lrow = lane & 15, quad = lane >> 4;
    short8v aqh[2], aql[2];
    {
        const size_t qb = (rowb + m0 + w*16 + lrow) * D_ + hoff + quad*8;
        aqh[0] = *(const short8v*)&qh[qb];
        aqh[1] = *(const short8v*)&qh[qb + 32];
        aql[0] = *(const short8v*)&ql[qb];
        aql[1] = *(const short8v*)&ql[qb + 32];
    }
    const int srow = tid & 63, scol = (tid >> 6) * 16;
    f32x4 o[4] = {};
    float lacc[4] = {0.f, 0.f, 0.f, 0.f};
    for (int kt = 0; kt < 4; kt++) {
        const int n00 = kt * 64;
        const size_t kb = (rowb + n00 + srow) * D_ + hoff + scol;
        const size_t vb = ((size_t)b * D_ + hoff + srow) * S_ + n00 + scol;
        uint4 kH0 = *(const uint4*)&kh[kb];
        uint4 kH1 = *(const uint4*)&kh[kb + 8];
        uint4 kL0 = *(const uint4*)&kl[kb];
        uint4 kL1 = *(const uint4*)&kl[kb + 8];
        uint4 vH0 = *(const uint4*)&vth[vb];
        uint4 vH1 = *(const uint4*)&vth[vb + 8];
        uint4 vL0 = *(const uint4*)&vtl[vb];
        uint4 vL1 = *(const uint4*)&vtl[vb + 8];
        *(uint4*)&Ksh[srow][scol]     = kH0;
        *(uint4*)&Ksh[srow][scol + 8] = kH1;
        *(uint4*)&Ksl[srow][scol]     = kL0;
        *(uint4*)&Ksl[srow][scol + 8] = kL1;
        *(uint4*)&VTh[srow][scol]     = vH0;
        *(uint4*)&VTh[srow][scol + 8] = vH1;
        *(uint4*)&VTl[srow][scol]     = vL0;
        *(uint4*)&VTl[srow][scol + 8] = vL1;
        __syncthreads();
        f32x4 sa[4] = {};
        #pragma unroll
        for (int ks = 0; ks < 2; ks++) {
            #pragma unroll
            for (int j = 0; j < 4; j++) {
                short8v bh = *(const short8v*)&Ksh[j*16 + lrow][ks*32 + quad*8];
                short8v bl = *(const short8v*)&Ksl[j*16 + lrow][ks*32 + quad*8];
                sa[j] = __builtin_amdgcn_mfma_f32_16x16x32_bf16(aqh[ks], bh, sa[j], 0, 0, 0);
                sa[j] = __builtin_amdgcn_mfma_f32_16x16x32_bf16(aql[ks], bh, sa[j], 0, 0, 0);
                sa[j] = __builtin_amdgcn_mfma_f32_16x16x32_bf16(aqh[ks], bl, sa[j], 0, 0, 0);
            }
        }
        float p[4][4];
        #pragma unroll
        for (int j = 0; j < 4; j++)
            #pragma unroll
            for (int r = 0; r < 4; r++) {
                p[j][r] = __expf(sa[j][r] * 0.125f);   // 1/sqrt(64); scores bounded
                lacc[r] += p[j][r];
            }
        #pragma unroll
        for (int c = 0; c < 2; c++) {
            #pragma unroll
            for (int jj = 0; jj < 2; jj++) {
                const int j = c*2 + jj;
                #pragma unroll
                for (int r = 0; r < 4; r++) {
                    const float val = p[j][r];
                    const unsigned short hh = f2bf(val);
                    Psh[w*16 + quad*4 + r][jj*16 + lrow] = hh;
                    Psl[w*16 + quad*4 + r][jj*16 + lrow] = f2bf(val - bf2f(hh));
                }
            }
            __syncthreads();
            short8v ah = *(const short8v*)&Psh[w*16 + lrow][quad*8];
            short8v al = *(const short8v*)&Psl[w*16 + lrow][quad*8];
            #pragma unroll
            for (int nf = 0; nf < 4; nf++) {
                short8v bh = *(const short8v*)&VTh[nf*16 + lrow][c*32 + quad*8];
                short8v bl = *(const short8v*)&VTl[nf*16 + lrow][c*32 + quad*8];
                o[nf] = __builtin_amdgcn_mfma_f32_16x16x32_bf16(ah, bh, o[nf], 0, 0, 0);
                o[nf] = __builtin_amdgcn_mfma_f32_16x16x32_bf16(al, bh, o[nf], 0, 0, 0);
                o[nf] = __builtin_amdgcn_mfma_f32_16x16x32_bf16(ah, bl, o[nf], 0, 0, 0);
            }
            __syncthreads();
        }
    }
    #pragma unroll
    for (int m = 1; m < 16; m <<= 1)
        #pragma unroll
        for (int r = 0; r < 4; r++) lacc[r] += __shfl_xor(lacc[r], m);
    #pragma unroll
    for (int r = 0; r < 4; r++) lacc[r] = 1.0f / lacc[r];
    #pragma unroll
    for (int nf = 0; nf < 4; nf++)
        #pragma unroll
        for (int r = 0; r < 4; r++)
            out[(rowb + m0 + w*16 + quad*4 + r) * D_ + hoff + nf*16 + lrow] =
                o[nf][r] * lacc[r];
}

// ------- K6: channel attention, split-bf16 MFMA flash. Mtile=128, Ntile=64 ------
// dk=32 (1 k-step). Wave owns 32 rows (2 m-frags). Out bf16 hi/lo.
__global__ __launch_bounds__(256) void k6_mfma(
    const unsigned short* __restrict__ qch, const unsigned short* __restrict__ qcl,
    const unsigned short* __restrict__ kch, const unsigned short* __restrict__ kcl,
    const unsigned short* __restrict__ vth, const unsigned short* __restrict__ vtl,
    unsigned short* __restrict__ oh, unsigned short* __restrict__ ol)
{
    const int m0 = blockIdx.x * 128;
    const int h = blockIdx.y, b = blockIdx.z;
    const int hoff = h * SK_;
    const size_t rowb = (size_t)b * D_;
    __shared__ __align__(16) unsigned short Ksh[64][40], Ksl[64][40];
    __shared__ __align__(16) unsigned short VTh[32][72], VTl[32][72];
    __shared__ __align__(16) unsigned short Psh[128][40], Psl[128][40];
    const int tid = threadIdx.x;
    const int w = tid >> 6, lane = tid & 63;
    const int lrow = lane & 15, quad = lane >> 4;
    short8v aqh[2], aql[2];
    #pragma unroll
    for (int i = 0; i < 2; i++) {
        const size_t qb = (rowb + m0 + w*32 + i*16 + lrow) * S_ + hoff + quad*8;
        aqh[i] = *(const short8v*)&qch[qb];
        aql[i] = *(const short8v*)&qcl[qb];
    }
    const int krow = tid >> 2, kcol = (tid & 3) * 8;
    const int vrow = tid >> 3, vcol = (tid & 7) * 8;
    f32x4 o[2][2] = {};
    float lacc[2][4] = {};
    for (int kt = 0; kt < 16; kt++) {
        const int n00 = kt * 64;
        const size_t kb = (rowb + n00 + krow) * S_ + hoff + kcol;
        const size_t vb = ((size_t)b * S_ + hoff + vrow) * D_ + n00 + vcol;
        uint4 kH = *(const uint4*)&kch[kb];
        uint4 kL = *(const uint4*)&kcl[kb];
        uint4 vH = *(const uint4*)&vth[vb];
        uint4 vL = *(const uint4*)&vtl[vb];
        *(uint4*)&Ksh[krow][kcol] = kH;
        *(uint4*)&Ksl[krow][kcol] = kL;
        *(uint4*)&VTh[vrow][vcol] = vH;
        *(uint4*)&VTl[vrow][vcol] = vL;
        __syncthreads();
        f32x4 sa[2][4] = {};
        #pragma unroll
        for (int j = 0; j < 4; j++) {
            short8v bh = *(const short8v*)&Ksh[j*16 + lrow][quad*8];
            short8v bl = *(const short8v*)&Ksl[j*16 + lrow][quad*8];
            #pragma unroll
            for (int i = 0; i < 2; i++) {
                sa[i][j] = __builtin_amdgcn_mfma_f32_16x16x32_bf16(aqh[i], bh, sa[i][j], 0, 0, 0);
                sa[i][j] = __builtin_amdgcn_mfma_f32_16x16x32_bf16(aql[i], bh, sa[i][j], 0, 0, 0);
                sa[i][j] = __builtin_amdgcn_mfma_f32_16x16x32_bf16(aqh[i], bl, sa[i][j], 0, 0, 0);
            }
        }
        float p[2][4][4];
        #pragma unroll
        for (int i = 0; i < 2; i++)
            #pragma unroll
            for (int j = 0; j < 4; j++)
                #pragma unroll
                for (int r = 0; r < 4; r++) {
                    p[i][j][r] = __expf(sa[i][j][r] * 0.17677669529663687f);  // 1/sqrt(32)
                    lacc[i][r] += p[i][j][r];
                }
        #pragma unroll
        for (int c = 0; c < 2; c++) {
            #pragma unroll
            for (int i = 0; i < 2; i++)
                #pragma unroll
                for (int jj = 0; jj < 2; jj++) {
                    const int j = c*2 + jj;
                    #pragma unroll
                    for (int r = 0; r < 4; r++) {
                        const float val = p[i][j][r];
                        const unsigned short hh = f2bf(val);
                        Psh[w*32 + i*16 + quad*4 + r][jj*16 + lrow] = hh;
                        Psl[w*32 + i*16 + quad*4 + r][jj*16 + lrow] = f2bf(val - bf2f(hh));
                    }
                }
            __syncthreads();
            short8v ah[2], al[2];
            #pragma unroll
            for (int i = 0; i < 2; i++) {
                ah[i] = *(const short8v*)&Psh[w*32 + i*16 + lrow][quad*8];
                al[i] = *(const short8v*)&Psl[w*32 + i*16 + lrow][quad*8];
            }
            #pragma unroll
            for (int nf = 0; nf < 2; nf++) {
                short8v bh = *(const short8v*)&VTh[nf*16 + lrow][c*32 + quad*8];
                short8v bl = *(const short8v*)&VTl[nf*16 + lrow][c*32 + quad*8];
                #pragma unroll
                for (int i = 0; i < 2; i++) {
                    o[i][nf] = __builtin_amdgcn_mfma_f32_16x16x32_bf16(ah[i], bh, o[i][nf], 0, 0, 0);
                    o[i][nf] = __builtin_amdgcn_mfma_f32_16x16x32_bf16(al[i], bh, o[i][nf], 0, 0, 0);
                    o[i][nf] = __builtin_amdgcn_mfma_f32_16x16x32_bf16(ah[i], bl, o[i][nf], 0, 0, 0);
                }
            }
            __syncthreads();
        }
    }
    #pragma unroll
    for (int i = 0; i < 2; i++) {
        #pragma unroll
        for (int m = 1; m < 16; m <<= 1)
            #pragma unroll
            for (int r = 0; r < 4; r++) lacc[i][r] += __shfl_xor(lacc[i][r], m);
        #pragma unroll
        for (int r = 0; r < 4; r++) lacc[i][r] = 1.0f / lacc[i][r];
    }
    #pragma unroll
    for (int i = 0; i < 2; i++)
        #pragma unroll
        for (int nf = 0; nf < 2; nf++)
            #pragma unroll
            for (int r = 0; r < 4; r++) {
                const float val = o[i][nf][r] * lacc[i][r];
                const unsigned short hh = f2bf(val);
                const size_t idx =
                    (rowb + m0 + w*32 + i*16 + quad*4 + r) * S_ + hoff + nf*16 + lrow;
                oh[idx] = hh;
                ol[idx] = f2bf(val - bf2f(hh));
            }
}

// ---------------- K4a: per-(b,d) stats over sequence dim ----------------
__global__ __launch_bounds__(256) void k4a_stats(
    const float* __restrict__ x, float* __restrict__ meanc, float* __restrict__ invc)
{
    const int d = blockIdx.x * 256 + threadIdx.x;
    const int b = blockIdx.y;
    const float* p = x + (size_t)b * S_ * D_ + d;
    float s = 0.f, q = 0.f;
    for (int t = 0; t < S_; t++) { float vv = p[(size_t)t * D_]; s += vv; q += vv*vv; }
    const float mean = s / (float)S_;
    const float var  = fmaxf((q - (float)S_ * mean * mean) / (float)(S_ - 1), 0.0f);
    meanc[b*D_ + d] = mean;
    invc[b*D_ + d]  = 1.0f / (sqrtf(var) + EPS_);
}

// ------- K4b: LN over seq + transpose to [B,D,S], output bf16 hi/lo split --------
__global__ __launch_bounds__(256) void k4b_ntrans(
    const float* __restrict__ x, const float* __restrict__ meanc,
    const float* __restrict__ invc, const float* __restrict__ a_c,
    const float* __restrict__ b_c, unsigned short* __restrict__ xth,
    unsigned short* __restrict__ xtl)
{
    const int s0 = blockIdx.x * 64, d0 = blockIdx.y * 64, b = blockIdx.z;
    __shared__ float tile[64][65];
    const int ix = threadIdx.x & 63, iy = threadIdx.x >> 6;
    const int d = d0 + ix;
    const float mean = meanc[b*D_ + d], inv = invc[b*D_ + d];
    #pragma unroll
    for (int u = 0; u < 16; u++) {
        const int srow = iy*16 + u;
        const float vv = x[((size_t)(b*S_ + s0 + srow)) * D_ + d];
        tile[srow][ix] = a_c[s0+srow] * (vv - mean) * inv + b_c[s0+srow];
    }
    __syncthreads();
    #pragma unroll
    for (int u = 0; u < 16; u++) {
        const int drow = iy*16 + u;
        const float vv = tile[ix][drow];
        const unsigned short h = f2bf(vv);
        const size_t idx = ((size_t)(b*D_ + d0 + drow)) * S_ + s0 + ix;
        xth[idx] = h;
        xtl[idx] = f2bf(vv - bf2f(h));
    }
}

// ---------------- K8: final transpose [B,D,S] -> [B,S,D] ----------------
__global__ __launch_bounds__(256) void k8_trans(
    const float* __restrict__ y, float* __restrict__ out)
{
    const int e0 = blockIdx.x * 64, d0 = blockIdx.y * 64, b = blockIdx.z;
    __shared__ float tile[64][65];
    const int ix = threadIdx.x & 63, iy = threadIdx.x >> 6;
    #pragma unroll
    for (int u = 0; u < 16; u++) {
        const int drow = iy*16 + u;
        tile[drow][ix] = y[((size_t)(b*D_ + d0 + drow)) * S_ + e0 + ix];
    }
    __syncthreads();
    #pragma unroll
    for (int u = 0; u < 16; u++) {
        const int erow = iy*16 + u;
        out[((size_t)(b*S_ + e0 + erow)) * D_ + d0 + ix] = tile[ix][erow];
    }
}

extern "C" void kernel_launch(void* const* d_in, const int* in_sizes, int n_in,
                              void* d_out, int out_size, void* d_ws, size_t ws_size,
                              hipStream_t stream)
{
    const float* x   = (const float*)d_in[0];
    const float* Wp  = (const float*)d_in[1];
    const float* bp  = (const float*)d_in[2];
    const float* Wc  = (const float*)d_in[3];
    const float* bc  = (const float*)d_in[4];
    const float* a_p = (const float*)d_in[5];
    const float* b_p = (const float*)d_in[6];
    const float* a_c = (const float*)d_in[7];
    const float* b_c = (const float*)d_in[8];
    float* out = (float*)d_out;
    float* ws  = (float*)d_ws;
    const size_t NE = (size_t)B_ * S_ * D_;     // 4,194,304

    float* S0 = ws;             // xp h/l -> attn f32 -> vcT h/l
    float* S1 = ws + NE;        // q h/l -> xt h/l -> xcatt h/l
    float* S2 = ws + 2*NE;      // k h/l -> qc h/l -> y f32
    float* S3 = ws + 3*NE;      // vT h/l -> kc h/l
    float* meanc = ws + 4*NE;
    float* invc  = meanc + (size_t)B_*D_;
    unsigned short* SW = (unsigned short*)(invc + (size_t)B_*D_);

    const size_t baseBytes = (4*NE + 2*(size_t)B_*D_) * sizeof(float);
    const bool big = ws_size >= baseBytes + (size_t)2 * 3 * D_ * D_ * sizeof(unsigned short) * 2;

    unsigned short* xh = (unsigned short*)S0;
    unsigned short* xl = xh + NE;
    unsigned short* q_h  = (unsigned short*)S1;
    unsigned short* k_h  = (unsigned short*)S2;
    unsigned short* vt_h = (unsigned short*)S3;

    // 1) LayerNorm over channels -> bf16 hi/lo
    k1_ln_p<<<dim3(B_*S_), 256, 0, stream>>>(x, a_p, b_p, xh, xl);

    // 2) QKV projection: q,k row-major bf16 h/l; v transposed bf16 h/l
    if (big) {
        unsigned short* WTh = SW;
        unsigned short* WTl = WTh + (size_t)3 * D_ * D_;
        tsplit<<<dim3(D_/64, D_/64, 3), 256, 0, stream>>>(Wp, WTh, WTl, D_, D_);
        mm_mfma<1><<<dim3(D_/128, (B_*S_)/128, 2), 256, 0, stream>>>(
            xh, xl, WTh, WTl, bp, (void*)q_h,
            B_*S_, D_, D_, (long)D_*D_, (long)D_, (long)(2*NE), (long)NE, 1);
        mm_mfma<2><<<dim3(D_/128, (B_*S_)/128, 1), 256, 0, stream>>>(
            xh, xl, WTh + (size_t)2*D_*D_, WTl + (size_t)2*D_*D_, bp + 2*D_,
            (void*)vt_h, B_*S_, D_, D_, 0, 0, 0, (long)NE, S_);
    } else {
        unsigned short* WTh = SW;
        unsigned short* WTl = WTh + (size_t)D_ * D_;
        for (int z = 0; z < 3; z++) {
            tsplit<<<dim3(D_/64, D_/64, 1), 256, 0, stream>>>(
                Wp + (size_t)z*D_*D_, WTh, WTl, D_, D_);
            if (z < 2)
                mm_mfma<1><<<dim3(D_/128, (B_*S_)/128, 1), 256, 0, stream>>>(
                    xh, xl, WTh, WTl, bp + (size_t)z*D_,
                    (void*)(q_h + (size_t)z*2*NE),
                    B_*S_, D_, D_, 0, 0, 0, (long)NE, 1);
            else
                mm_mfma<2><<<dim3(D_/128, (B_*S_)/128, 1), 256, 0, stream>>>(
                    xh, xl, WTh, WTl, bp + (size_t)z*D_, (void*)vt_h,
                    B_*S_, D_, D_, 0, 0, 0, (long)NE, S_);
        }
    }

    // 3) positional attention (MFMA flash) -> attn f32 in S0 (xp dead)
    k3_mfma<<<dim3(S_/64, HP_, B_), 256, 0, stream>>>(
        q_h, q_h + NE, k_h, k_h + NE, vt_h, vt_h + NE, S0);

    // 4) LN over sequence -> xt bf16 h/l in S1 (q dead)
    k4a_stats<<<dim3(D_/256, B_), 256, 0, stream>>>(S0, meanc, invc);
    unsigned short* xth = (unsigned short*)S1;
    k4b_ntrans<<<dim3(S_/64, D_/64, B_), 256, 0, stream>>>(
        S0, meanc, invc, a_c, b_c, xth, xth + NE);

    // 5) channel weights + channel QKV: qc,kc row-major; vc transposed
    unsigned short* WcTh = SW;
    unsigned short* WcTl = WcTh + (size_t)4 * S_ * S_;
    tsplit<<<dim3(S_/64, S_/64, 4), 256, 0, stream>>>(Wc, WcTh, WcTl, S_, S_);
    unsigned short* qc_h  = (unsigned short*)S2;   // k dead
    unsigned short* vct_h = (unsigned short*)S0;   // attn f32 dead after k4b
    mm_mfma<1><<<dim3(S_/128, (B_*D_)/128, 2), 256, 0, stream>>>(
        xth, xth + NE, WcTh, WcTl, bc, (void*)qc_h,
        B_*D_, S_, S_, (long)S_*S_, (long)S_, (long)(2*NE), (long)NE, 1);
    mm_mfma<2><<<dim3(S_/128, (B_*D_)/128, 1), 256, 0, stream>>>(
        xth, xth + NE, WcTh + (size_t)2*S_*S_, WcTl + (size_t)2*S_*S_, bc + 2*S_,
        (void*)vct_h, B_*D_, S_, S_, 0, 0, 0, (long)NE, D_);

    // 6) channel attention (MFMA flash) -> xcatt bf16 h/l in S1 (xt dead)
    unsigned short* kc_h = (unsigned short*)S3;
    unsigned short* xch  = (unsigned short*)S1;
    k6_mfma<<<dim3(D_/128, HC_, B_), 256, 0, stream>>>(
        qc_h, qc_h + NE, kc_h, kc_h + NE, vct_h, vct_h + NE, xch, xch + NE);

    // 7) final projection -> y f32 in S2 (qc dead)
    mm_mfma<0><<<dim3(S_/128, (B_*D_)/128, 1), 256, 0, stream>>>(
        xch, xch + NE, WcTh + (size_t)3*S_*S_, WcTl + (size_t)3*S_*S_, bc + 3*S_,
        (void*)S2, B_*D_, S_, S_, 0, 0, 0, 0, 1);

    // 8) transpose y -> out [B,S,D]
    k8_trans<<<dim3(S_/64, D_/64, B_), 256, 0, stream>>>(S2, out);
}

// Round 6
// 377.127 us; speedup vs baseline: 6.2179x; 1.0978x over previous
//
#include <hip/hip_runtime.h>
#include <math.h>

#define B_ 16
#define S_ 256
#define D_ 1024
#define HP_ 16
#define DK_ 64
#define HC_ 8
#define SK_ 32
#define EPS_ 1e-6f

typedef __attribute__((ext_vector_type(8))) short short8v;
typedef __attribute__((ext_vector_type(4))) float f32x4;

__device__ __forceinline__ unsigned short f2bf(float f) {
    unsigned u = __float_as_uint(f);
    u += 0x7fffu + ((u >> 16) & 1u);          // round-to-nearest-even
    return (unsigned short)(u >> 16);
}
__device__ __forceinline__ float bf2f(unsigned short h) {
    return __uint_as_float((unsigned)h << 16);
}

// ---------------- K1: LayerNorm over channels -> bf16 hi/lo split ---------------
__global__ __launch_bounds__(256) void k1_ln_p(
    const float* __restrict__ x, const float* __restrict__ a_p,
    const float* __restrict__ b_p, unsigned short* __restrict__ xh,
    unsigned short* __restrict__ xl)
{
    const int row = blockIdx.x;                  // b*S + s
    const float4* xr = (const float4*)(x + (size_t)row * D_);
    const int tid = threadIdx.x;
    float4 v = xr[tid];
    float s  = v.x + v.y + v.z + v.w;
    float sq = v.x*v.x + v.y*v.y + v.z*v.z + v.w*v.w;
    #pragma unroll
    for (int off = 32; off > 0; off >>= 1) {
        s  += __shfl_down(s, off);
        sq += __shfl_down(sq, off);
    }
    __shared__ float red[8];
    const int wid = tid >> 6, lane = tid & 63;
    if (lane == 0) { red[wid] = s; red[4 + wid] = sq; }
    __syncthreads();
    if (tid == 0) {
        float S0 = red[0] + red[1] + red[2] + red[3];
        float Q0 = red[4] + red[5] + red[6] + red[7];
        float mean = S0 / (float)D_;
        float var  = fmaxf((Q0 - (float)D_ * mean * mean) / (float)(D_ - 1), 0.0f);
        red[0] = mean;
        red[1] = 1.0f / (sqrtf(var) + EPS_);     // torch std(): unbiased; eps on std
    }
    __syncthreads();
    const float mean = red[0], inv = red[1];
    float4 a = ((const float4*)a_p)[tid];
    float4 b = ((const float4*)b_p)[tid];
    float o0 = a.x * (v.x - mean) * inv + b.x;
    float o1 = a.y * (v.y - mean) * inv + b.y;
    float o2 = a.z * (v.z - mean) * inv + b.z;
    float o3 = a.w * (v.w - mean) * inv + b.w;
    ushort4 hv, lv;
    hv.x = f2bf(o0); lv.x = f2bf(o0 - bf2f(hv.x));
    hv.y = f2bf(o1); lv.y = f2bf(o1 - bf2f(hv.y));
    hv.z = f2bf(o2); lv.z = f2bf(o2 - bf2f(hv.z));
    hv.w = f2bf(o3); lv.w = f2bf(o3 - bf2f(hv.w));
    *(ushort4*)&xh[(size_t)row * D_ + tid*4] = hv;
    *(ushort4*)&xl[(size_t)row * D_ + tid*4] = lv;
}

// ------------- Transpose + bf16-split weights: W[k][n] -> T[n][k] hi/lo ---------
__global__ __launch_bounds__(256) void tsplit(
    const float* __restrict__ W, unsigned short* __restrict__ Th,
    unsigned short* __restrict__ Tl, int K, int N)
{
    const int z = blockIdx.z;
    W  += (size_t)z * K * N;
    Th += (size_t)z * K * N;
    Tl += (size_t)z * K * N;
    const int k0 = blockIdx.x * 64, n0 = blockIdx.y * 64;
    __shared__ float tile[64][65];
    const int ix = threadIdx.x & 63, iy = threadIdx.x >> 6;
    #pragma unroll
    for (int u = 0; u < 16; u++) {
        const int kk = iy*16 + u;
        tile[kk][ix] = W[(size_t)(k0+kk)*N + n0 + ix];
    }
    __syncthreads();
    #pragma unroll
    for (int u = 0; u < 16; u++) {
        const int nn = iy*16 + u;
        const float v = tile[ix][nn];
        const unsigned short h = f2bf(v);
        Th[(size_t)(n0+nn)*K + k0 + ix] = h;
        Tl[(size_t)(n0+nn)*K + k0 + ix] = f2bf(v - bf2f(h));
    }
}

// ------------- Split-bf16 MFMA GEMM: C = A*B^T + bias ---------------------------
// OUTMODE 0: f32 row-major. 1: bf16 hi/lo row-major. 2: bf16 hi/lo transposed
// per batch of TB rows: out[b][n][t], b=m/TB, t=m%TB.
template<int OUTMODE>
__global__ __launch_bounds__(256) void mm_mfma(
    const unsigned short* __restrict__ Ah, const unsigned short* __restrict__ Al,
    const unsigned short* __restrict__ Bh, const unsigned short* __restrict__ Bl,
    const float* __restrict__ bias, void* __restrict__ Cout,
    int M, int N, int K, long sB, long sBias, long sC, long loff, int TB)
{
    const int z = blockIdx.z;
    Bh   += (size_t)z * sB;
    Bl   += (size_t)z * sB;
    bias += (size_t)z * sBias;
    const int n0 = blockIdx.x * 128, m0 = blockIdx.y * 128;
    __shared__ __align__(16) unsigned short Ash[128][40];
    __shared__ __align__(16) unsigned short Als[128][40];
    __shared__ __align__(16) unsigned short Bsh[128][40];
    __shared__ __align__(16) unsigned short Bls[128][40];
    const int tid = threadIdx.x;
    const int wave = tid >> 6, lane = tid & 63;
    const int wm = wave & 1, wn = wave >> 1;
    const int lrow = lane & 15, quad = lane >> 4;
    const int sr = tid >> 1, sko = (tid & 1) * 16;
    f32x4 acc[4][4];
    #pragma unroll
    for (int j = 0; j < 4; j++) {
        const float bv = bias[n0 + wn*64 + j*16 + lrow];
        #pragma unroll
        for (int i = 0; i < 4; i++) {
            acc[i][j][0] = bv; acc[i][j][1] = bv; acc[i][j][2] = bv; acc[i][j][3] = bv;
        }
    }
    for (int k0 = 0; k0 < K; k0 += 32) {
        const size_t ga = (size_t)(m0 + sr) * K + k0 + sko;
        const size_t gb = (size_t)(n0 + sr) * K + k0 + sko;
        uint4 ah0 = *(const uint4*)&Ah[ga];
        uint4 ah1 = *(const uint4*)&Ah[ga + 8];
        uint4 al0 = *(const uint4*)&Al[ga];
        uint4 al1 = *(const uint4*)&Al[ga + 8];
        uint4 bh0 = *(const uint4*)&Bh[gb];
        uint4 bh1 = *(const uint4*)&Bh[gb + 8];
        uint4 bl0 = *(const uint4*)&Bl[gb];
        uint4 bl1 = *(const uint4*)&Bl[gb + 8];
        __syncthreads();
        *(uint4*)&Ash[sr][sko]     = ah0;
        *(uint4*)&Ash[sr][sko + 8] = ah1;
        *(uint4*)&Als[sr][sko]     = al0;
        *(uint4*)&Als[sr][sko + 8] = al1;
        *(uint4*)&Bsh[sr][sko]     = bh0;
        *(uint4*)&Bsh[sr][sko + 8] = bh1;
        *(uint4*)&Bls[sr][sko]     = bl0;
        *(uint4*)&Bls[sr][sko + 8] = bl1;
        __syncthreads();
        short8v bhf[4], blf[4];
        #pragma unroll
        for (int j = 0; j < 4; j++) {
            bhf[j] = *(const short8v*)&Bsh[wn*64 + j*16 + lrow][quad*8];
            blf[j] = *(const short8v*)&Bls[wn*64 + j*16 + lrow][quad*8];
        }
        #pragma unroll
        for (int i = 0; i < 4; i++) {
            short8v ahf = *(const short8v*)&Ash[wm*64 + i*16 + lrow][quad*8];
            short8v alf = *(const short8v*)&Als[wm*64 + i*16 + lrow][quad*8];
            #pragma unroll
            for (int j = 0; j < 4; j++) {
                acc[i][j] = __builtin_amdgcn_mfma_f32_16x16x32_bf16(ahf, bhf[j], acc[i][j], 0, 0, 0);
                acc[i][j] = __builtin_amdgcn_mfma_f32_16x16x32_bf16(ahf, blf[j], acc[i][j], 0, 0, 0);
                acc[i][j] = __builtin_amdgcn_mfma_f32_16x16x32_bf16(alf, bhf[j], acc[i][j], 0, 0, 0);
            }
        }
    }
    // C/D layout: col = lane&15, row = quad*4 + reg  [m89/m91-verified]
    #pragma unroll
    for (int i = 0; i < 4; i++) {
        const int mrow = m0 + wm*64 + i*16 + quad*4;
        #pragma unroll
        for (int j = 0; j < 4; j++) {
            const int ncol = n0 + wn*64 + j*16 + lrow;
            if (OUTMODE == 0) {
                float* C = (float*)Cout + (size_t)z * sC;
                #pragma unroll
                for (int r = 0; r < 4; r++)
                    C[(size_t)(mrow + r) * N + ncol] = acc[i][j][r];
            } else if (OUTMODE == 1) {
                unsigned short* Ch = (unsigned short*)Cout + (size_t)z * sC;
                unsigned short* Cl = Ch + loff;
                #pragma unroll
                for (int r = 0; r < 4; r++) {
                    const float val = acc[i][j][r];
                    const unsigned short hh = f2bf(val);
                    Ch[(size_t)(mrow + r) * N + ncol] = hh;
                    Cl[(size_t)(mrow + r) * N + ncol] = f2bf(val - bf2f(hh));
                }
            } else {
                unsigned short* Ch = (unsigned short*)Cout;
                unsigned short* Cl = Ch + loff;
                const int bidx = mrow / TB, t0 = mrow % TB;
                const size_t ad = (size_t)bidx * N * TB + (size_t)ncol * TB + t0;
                ushort4 hv, lv;
                float v0 = acc[i][j][0], v1 = acc[i][j][1], v2 = acc[i][j][2], v3 = acc[i][j][3];
                hv.x = f2bf(v0); lv.x = f2bf(v0 - bf2f(hv.x));
                hv.y = f2bf(v1); lv.y = f2bf(v1 - bf2f(hv.y));
                hv.z = f2bf(v2); lv.z = f2bf(v2 - bf2f(hv.z));
                hv.w = f2bf(v3); lv.w = f2bf(v3 - bf2f(hv.w));
                *(ushort4*)&Ch[ad] = hv;
                *(ushort4*)&Cl[ad] = lv;
            }
        }
    }
}

// ------- K3: positional attention, MFMA flash, S^T=K*Q^T trick ------------------
// Mtile=64 (wave owns 16 q-rows), Ntile=64 keys, dk=64. P row-major b64, hi-only.
__global__ __launch_bounds__(256) void k3_mfma(
    const unsigned short* __restrict__ qh, const unsigned short* __restrict__ ql,
    const unsigned short* __restrict__ kh, const unsigned short* __restrict__ kl,
    const unsigned short* __restrict__ vth, const unsigned short* __restrict__ vtl,
    float* __restrict__ out)
{
    const int m0 = blockIdx.x * 64;
    const int h = blockIdx.y, b = blockIdx.z;
    const int hoff = h * DK_;
    const size_t rowb = (size_t)b * S_;
    __shared__ __align__(16) unsigned short Ksh[64][72], Ksl[64][72];
    __shared__ __align__(16) unsigned short VTh[64][72], VTl[64][72];
    __shared__ __align__(16) unsigned short Ps[64][72];
    const int tid = threadIdx.x;
    const int w = tid >> 6, lane = tid & 63;
    const int lrow = lane & 15, quad = lane >> 4;
    // Q as B-operand (cols of S^T): hi/lo, 2 k-steps
    short8v bqh[2], bql[2];
    #pragma unroll
    for (int ks = 0; ks < 2; ks++) {
        const size_t qb = (rowb + m0 + w*16 + lrow) * D_ + hoff + ks*32 + quad*8;
        bqh[ks] = *(const short8v*)&qh[qb];
        bql[ks] = *(const short8v*)&ql[qb];
    }
    const int srow = tid >> 2, scol = (tid & 3) * 16;
    f32x4 o[4] = {};
    float lacc = 0.f;
    for (int kt = 0; kt < 4; kt++) {
        const int n00 = kt * 64;
        const size_t kb = (rowb + n00 + srow) * D_ + hoff + scol;
        const size_t vb = ((size_t)b * D_ + hoff + srow) * S_ + n00 + scol;
        uint4 kH0 = *(const uint4*)&kh[kb];
        uint4 kH1 = *(const uint4*)&kh[kb + 8];
        uint4 kL0 = *(const uint4*)&kl[kb];
        uint4 kL1 = *(const uint4*)&kl[kb + 8];
        uint4 vH0 = *(const uint4*)&vth[vb];
        uint4 vH1 = *(const uint4*)&vth[vb + 8];
        uint4 vL0 = *(const uint4*)&vtl[vb];
        uint4 vL1 = *(const uint4*)&vtl[vb + 8];
        __syncthreads();   // prev iter LDS reads done
        *(uint4*)&Ksh[srow][scol]     = kH0;
        *(uint4*)&Ksh[srow][scol + 8] = kH1;
        *(uint4*)&Ksl[srow][scol]     = kL0;
        *(uint4*)&Ksl[srow][scol + 8] = kL1;
        *(uint4*)&VTh[srow][scol]     = vH0;
        *(uint4*)&VTh[srow][scol + 8] = vH1;
        *(uint4*)&VTl[srow][scol]     = vL0;
        *(uint4*)&VTl[srow][scol + 8] = vL1;
        __syncthreads();
        // S^T = K·Q^T: rows=keys (A=K), cols=queries (B=Q regs)
        f32x4 sa[4] = {};
        #pragma unroll
        for (int ks = 0; ks < 2; ks++) {
            #pragma unroll
            for (int jk = 0; jk < 4; jk++) {
                short8v akh = *(const short8v*)&Ksh[jk*16 + lrow][ks*32 + quad*8];
                short8v akl = *(const short8v*)&Ksl[jk*16 + lrow][ks*32 + quad*8];
                sa[jk] = __builtin_amdgcn_mfma_f32_16x16x32_bf16(akh, bqh[ks], sa[jk], 0, 0, 0);
                sa[jk] = __builtin_amdgcn_mfma_f32_16x16x32_bf16(akl, bqh[ks], sa[jk], 0, 0, 0);
                sa[jk] = __builtin_amdgcn_mfma_f32_16x16x32_bf16(akh, bql[ks], sa[jk], 0, 0, 0);
            }
        }
        // exp; P[m][key] row-major, b64 per frag (4 consecutive keys per lane)
        #pragma unroll
        for (int jk = 0; jk < 4; jk++) {
            ushort4 ph;
            float p0 = __expf(sa[jk][0] * 0.125f);
            float p1 = __expf(sa[jk][1] * 0.125f);
            float p2 = __expf(sa[jk][2] * 0.125f);
            float p3 = __expf(sa[jk][3] * 0.125f);
            lacc += (p0 + p1) + (p2 + p3);
            ph.x = f2bf(p0); ph.y = f2bf(p1); ph.z = f2bf(p2); ph.w = f2bf(p3);
            *(ushort4*)&Ps[w*16 + lrow][jk*16 + quad*4] = ph;   // wave-private rows
        }
        // PV: O = P·V^T' (A=P rows m, B=VT rows d) — no barrier (wave-private P)
        #pragma unroll
        for (int ks = 0; ks < 2; ks++) {
            short8v ap = *(const short8v*)&Ps[w*16 + lrow][ks*32 + quad*8];
            #pragma unroll
            for (int nf = 0; nf < 4; nf++) {
                short8v vH = *(const short8v*)&VTh[nf*16 + lrow][ks*32 + quad*8];
                short8v vL = *(const short8v*)&VTl[nf*16 + lrow][ks*32 + quad*8];
                o[nf] = __builtin_amdgcn_mfma_f32_16x16x32_bf16(ap, vH, o[nf], 0, 0, 0);
                o[nf] = __builtin_amdgcn_mfma_f32_16x16x32_bf16(ap, vL, o[nf], 0, 0, 0);
            }
        }
    }
    // l: lane holds partials for col m=lrow (its quad's keys) -> sum over quads
    lacc += __shfl_xor(lacc, 16);
    lacc += __shfl_xor(lacc, 32);
    #pragma unroll
    for (int r = 0; r < 4; r++) {
        const float linv = 1.0f / __shfl(lacc, quad*4 + r);
        #pragma unroll
        for (int nf = 0; nf < 4; nf++)
            out[(rowb + m0 + w*16 + quad*4 + r) * D_ + hoff + nf*16 + lrow] =
                o[nf][r] * linv;
    }
}

// ------- K6: channel attention, MFMA flash, S^T trick. Mtile=128, Ntile=64 ------
// dk=32. Wave owns 32 q-rows (2 m-frags). P hi-only b64. Out bf16 h/l.
__global__ __launch_bounds__(256) void k6_mfma(
    const unsigned short* __restrict__ qch, const unsigned short* __restrict__ qcl,
    const unsigned short* __restrict__ kch, const unsigned short* __restrict__ kcl,
    const unsigned short* __restrict__ vth, const unsigned short* __restrict__ vtl,
    unsigned short* __restrict__ oh, unsigned short* __restrict__ ol)
{
    const int m0 = blockIdx.x * 128;
    const int h = blockIdx.y, b = blockIdx.z;
    const int hoff = h * SK_;
    const size_t rowb = (size_t)b * D_;
    __shared__ __align__(16) unsigned short Ksh[64][40], Ksl[64][40];
    __shared__ __align__(16) unsigned short VTh[32][72], VTl[32][72];
    __shared__ __align__(16) unsigned short Ps[128][72];
    const int tid = threadIdx.x;
    const int w = tid >> 6, lane = tid & 63;
    const int lrow = lane & 15, quad = lane >> 4;
    short8v bqh[2], bql[2];
    #pragma unroll
    for (int i = 0; i < 2; i++) {
        const size_t qb = (rowb + m0 + w*32 + i*16 + lrow) * S_ + hoff + quad*8;
        bqh[i] = *(const short8v*)&qch[qb];
        bql[i] = *(const short8v*)&qcl[qb];
    }
    const int krow = tid >> 2, kcol = (tid & 3) * 8;
    const int vrow = tid >> 3, vcol = (tid & 7) * 8;
    f32x4 o[2][2] = {};
    float lacc[2] = {0.f, 0.f};
    for (int kt = 0; kt < 16; kt++) {
        const int n00 = kt * 64;
        const size_t kb = (rowb + n00 + krow) * S_ + hoff + kcol;
        const size_t vb = ((size_t)b * S_ + hoff + vrow) * D_ + n00 + vcol;
        uint4 kH = *(const uint4*)&kch[kb];
        uint4 kL = *(const uint4*)&kcl[kb];
        uint4 vH = *(const uint4*)&vth[vb];
        uint4 vL = *(const uint4*)&vtl[vb];
        __syncthreads();
        *(uint4*)&Ksh[krow][kcol] = kH;
        *(uint4*)&Ksl[krow][kcol] = kL;
        *(uint4*)&VTh[vrow][vcol] = vH;
        *(uint4*)&VTl[vrow][vcol] = vL;
        __syncthreads();
        // S^T = K·Q^T
        f32x4 sa[2][4] = {};
        #pragma unroll
        for (int jk = 0; jk < 4; jk++) {
            short8v akh = *(const short8v*)&Ksh[jk*16 + lrow][quad*8];
            short8v akl = *(const short8v*)&Ksl[jk*16 + lrow][quad*8];
            #pragma unroll
            for (int i = 0; i < 2; i++) {
                sa[i][jk] = __builtin_amdgcn_mfma_f32_16x16x32_bf16(akh, bqh[i], sa[i][jk], 0, 0, 0);
                sa[i][jk] = __builtin_amdgcn_mfma_f32_16x16x32_bf16(akl, bqh[i], sa[i][jk], 0, 0, 0);
                sa[i][jk] = __builtin_amdgcn_mfma_f32_16x16x32_bf16(akh, bql[i], sa[i][jk], 0, 0, 0);
            }
        }
        // exp; P row-major [m][key], b64 writes, wave-private rows
        #pragma unroll
        for (int i = 0; i < 2; i++)
            #pragma unroll
            for (int jk = 0; jk < 4; jk++) {
                float p0 = __expf(sa[i][jk][0] * 0.17677669529663687f);
                float p1 = __expf(sa[i][jk][1] * 0.17677669529663687f);
                float p2 = __expf(sa[i][jk][2] * 0.17677669529663687f);
                float p3 = __expf(sa[i][jk][3] * 0.17677669529663687f);
                lacc[i] += (p0 + p1) + (p2 + p3);
                ushort4 ph;
                ph.x = f2bf(p0); ph.y = f2bf(p1); ph.z = f2bf(p2); ph.w = f2bf(p3);
                *(ushort4*)&Ps[w*32 + i*16 + lrow][jk*16 + quad*4] = ph;
            }
        // PV (no barrier needed: P rows wave-private)
        #pragma unroll
        for (int ks = 0; ks < 2; ks++) {
            short8v ap[2];
            #pragma unroll
            for (int i = 0; i < 2; i++)
                ap[i] = *(const short8v*)&Ps[w*32 + i*16 + lrow][ks*32 + quad*8];
            #pragma unroll
            for (int nf = 0; nf < 2; nf++) {
                short8v vHf = *(const short8v*)&VTh[nf*16 + lrow][ks*32 + quad*8];
                short8v vLf = *(const short8v*)&VTl[nf*16 + lrow][ks*32 + quad*8];
                #pragma unroll
                for (int i = 0; i < 2; i++) {
                    o[i][nf] = __builtin_amdgcn_mfma_f32_16x16x32_bf16(ap[i], vHf, o[i][nf], 0, 0, 0);
                    o[i][nf] = __builtin_amdgcn_mfma_f32_16x16x32_bf16(ap[i], vLf, o[i][nf], 0, 0, 0);
                }
            }
        }
    }
    #pragma unroll
    for (int i = 0; i < 2; i++) {
        lacc[i] += __shfl_xor(lacc[i], 16);
        lacc[i] += __shfl_xor(lacc[i], 32);
    }
    #pragma unroll
    for (int i = 0; i < 2; i++)
        #pragma unroll
        for (int r = 0; r < 4; r++) {
            const float linv = 1.0f / __shfl(lacc[i], quad*4 + r);
            #pragma unroll
            for (int nf = 0; nf < 2; nf++) {
                const float val = o[i][nf][r] * linv;
                const unsigned short hh = f2bf(val);
                const size_t idx =
                    (rowb + m0 + w*32 + i*16 + quad*4 + r) * S_ + hoff + nf*16 + lrow;
                oh[idx] = hh;
                ol[idx] = f2bf(val - bf2f(hh));
            }
        }
}

// ---------------- K4a: per-(b,d) stats over sequence dim ----------------
__global__ __launch_bounds__(256) void k4a_stats(
    const float* __restrict__ x, float* __restrict__ meanc, float* __restrict__ invc)
{
    const int d = blockIdx.x * 256 + threadIdx.x;
    const int b = blockIdx.y;
    const float* p = x + (size_t)b * S_ * D_ + d;
    float s = 0.f, q = 0.f;
    for (int t = 0; t < S_; t++) { float vv = p[(size_t)t * D_]; s += vv; q += vv*vv; }
    const float mean = s / (float)S_;
    const float var  = fmaxf((q - (float)S_ * mean * mean) / (float)(S_ - 1), 0.0f);
    meanc[b*D_ + d] = mean;
    invc[b*D_ + d]  = 1.0f / (sqrtf(var) + EPS_);
}

// ------- K4b: LN over seq + transpose to [B,D,S], output bf16 hi/lo split --------
__global__ __launch_bounds__(256) void k4b_ntrans(
    const float* __restrict__ x, const float* __restrict__ meanc,
    const float* __restrict__ invc, const float* __restrict__ a_c,
    const float* __restrict__ b_c, unsigned short* __restrict__ xth,
    unsigned short* __restrict__ xtl)
{
    const int s0 = blockIdx.x * 64, d0 = blockIdx.y * 64, b = blockIdx.z;
    __shared__ float tile[64][65];
    const int ix = threadIdx.x & 63, iy = threadIdx.x >> 6;
    const int d = d0 + ix;
    const float mean = meanc[b*D_ + d], inv = invc[b*D_ + d];
    #pragma unroll
    for (int u = 0; u < 16; u++) {
        const int srow = iy*16 + u;
        const float vv = x[((size_t)(b*S_ + s0 + srow)) * D_ + d];
        tile[srow][ix] = a_c[s0+srow] * (vv - mean) * inv + b_c[s0+srow];
    }
    __syncthreads();
    #pragma unroll
    for (int u = 0; u < 16; u++) {
        const int drow = iy*16 + u;
        const float vv = tile[ix][drow];
        const unsigned short h = f2bf(vv);
        const size_t idx = ((size_t)(b*D_ + d0 + drow)) * S_ + s0 + ix;
        xth[idx] = h;
        xtl[idx] = f2bf(vv - bf2f(h));
    }
}

// ---------------- K8: final transpose [B,D,S] -> [B,S,D] ----------------
__global__ __launch_bounds__(256) void k8_trans(
    const float* __restrict__ y, float* __restrict__ out)
{
    const int e0 = blockIdx.x * 64, d0 = blockIdx.y * 64, b = blockIdx.z;
    __shared__ float tile[64][65];
    const int ix = threadIdx.x & 63, iy = threadIdx.x >> 6;
    #pragma unroll
    for (int u = 0; u < 16; u++) {
        const int drow = iy*16 + u;
        tile[drow][ix] = y[((size_t)(b*D_ + d0 + drow)) * S_ + e0 + ix];
    }
    __syncthreads();
    #pragma unroll
    for (int u = 0; u < 16; u++) {
        const int erow = iy*16 + u;
        out[((size_t)(b*S_ + e0 + erow)) * D_ + d0 + ix] = tile[ix][erow];
    }
}

extern "C" void kernel_launch(void* const* d_in, const int* in_sizes, int n_in,
                              void* d_out, int out_size, void* d_ws, size_t ws_size,
                              hipStream_t stream)
{
    const float* x   = (const float*)d_in[0];
    const float* Wp  = (const float*)d_in[1];
    const float* bp  = (const float*)d_in[2];
    const float* Wc  = (const float*)d_in[3];
    const float* bc  = (const float*)d_in[4];
    const float* a_p = (const float*)d_in[5];
    const float* b_p = (const float*)d_in[6];
    const float* a_c = (const float*)d_in[7];
    const float* b_c = (const float*)d_in[8];
    float* out = (float*)d_out;
    float* ws  = (float*)d_ws;
    const size_t NE = (size_t)B_ * S_ * D_;     // 4,194,304

    float* S0 = ws;             // xp h/l -> attn f32 -> vcT h/l
    float* S1 = ws + NE;        // q h/l -> xt h/l -> xcatt h/l
    float* S2 = ws + 2*NE;      // k h/l -> qc h/l -> y f32
    float* S3 = ws + 3*NE;      // vT h/l -> kc h/l
    float* meanc = ws + 4*NE;
    float* invc  = meanc + (size_t)B_*D_;
    unsigned short* SW = (unsigned short*)(invc + (size_t)B_*D_);

    const size_t baseBytes = (4*NE + 2*(size_t)B_*D_) * sizeof(float);
    const bool big = ws_size >= baseBytes + (size_t)2 * 3 * D_ * D_ * sizeof(unsigned short) * 2;

    unsigned short* xh = (unsigned short*)S0;
    unsigned short* xl = xh + NE;
    unsigned short* q_h  = (unsigned short*)S1;
    unsigned short* k_h  = (unsigned short*)S2;
    unsigned short* vt_h = (unsigned short*)S3;

    // 1) LayerNorm over channels -> bf16 hi/lo
    k1_ln_p<<<dim3(B_*S_), 256, 0, stream>>>(x, a_p, b_p, xh, xl);

    // 2) QKV projection: q,k row-major bf16 h/l; v transposed bf16 h/l
    if (big) {
        unsigned short* WTh = SW;
        unsigned short* WTl = WTh + (size_t)3 * D_ * D_;
        tsplit<<<dim3(D_/64, D_/64, 3), 256, 0, stream>>>(Wp, WTh, WTl, D_, D_);
        mm_mfma<1><<<dim3(D_/128, (B_*S_)/128, 2), 256, 0, stream>>>(
            xh, xl, WTh, WTl, bp, (void*)q_h,
            B_*S_, D_, D_, (long)D_*D_, (long)D_, (long)(2*NE), (long)NE, 1);
        mm_mfma<2><<<dim3(D_/128, (B_*S_)/128, 1), 256, 0, stream>>>(
            xh, xl, WTh + (size_t)2*D_*D_, WTl + (size_t)2*D_*D_, bp + 2*D_,
            (void*)vt_h, B_*S_, D_, D_, 0, 0, 0, (long)NE, S_);
    } else {
        unsigned short* WTh = SW;
        unsigned short* WTl = WTh + (size_t)D_ * D_;
        for (int z = 0; z < 3; z++) {
            tsplit<<<dim3(D_/64, D_/64, 1), 256, 0, stream>>>(
                Wp + (size_t)z*D_*D_, WTh, WTl, D_, D_);
            if (z < 2)
                mm_mfma<1><<<dim3(D_/128, (B_*S_)/128, 1), 256, 0, stream>>>(
                    xh, xl, WTh, WTl, bp + (size_t)z*D_,
                    (void*)(q_h + (size_t)z*2*NE),
                    B_*S_, D_, D_, 0, 0, 0, (long)NE, 1);
            else
                mm_mfma<2><<<dim3(D_/128, (B_*S_)/128, 1), 256, 0, stream>>>(
                    xh, xl, WTh, WTl, bp + (size_t)z*D_, (void*)vt_h,
                    B_*S_, D_, D_, 0, 0, 0, (long)NE, S_);
        }
    }

    // 3) positional attention (MFMA flash, S^T trick) -> attn f32 in S0 (xp dead)
    k3_mfma<<<dim3(S_/64, HP_, B_), 256, 0, stream>>>(
        q_h, q_h + NE, k_h, k_h + NE, vt_h, vt_h + NE, S0);

    // 4) LN over sequence -> xt bf16 h/l in S1 (q dead)
    k4a_stats<<<dim3(D_/256, B_), 256, 0, stream>>>(S0, meanc, invc);
    unsigned short* xth = (unsigned short*)S1;
    k4b_ntrans<<<dim3(S_/64, D_/64, B_), 256, 0, stream>>>(
        S0, meanc, invc, a_c, b_c, xth, xth + NE);

    // 5) channel weights + channel QKV: qc,kc row-major; vc transposed
    unsigned short* WcTh = SW;
    unsigned short* WcTl = WcTh + (size_t)4 * S_ * S_;
    tsplit<<<dim3(S_/64, S_/64, 4), 256, 0, stream>>>(Wc, WcTh, WcTl, S_, S_);
    unsigned short* qc_h  = (unsigned short*)S2;   // k dead
    unsigned short* vct_h = (unsigned short*)S0;   // attn f32 dead after k4b
    mm_mfma<1><<<dim3(S_/128, (B_*D_)/128, 2), 256, 0, stream>>>(
        xth, xth + NE, WcTh, WcTl, bc, (void*)qc_h,
        B_*D_, S_, S_, (long)S_*S_, (long)S_, (long)(2*NE), (long)NE, 1);
    mm_mfma<2><<<dim3(S_/128, (B_*D_)/128, 1), 256, 0, stream>>>(
        xth, xth + NE, WcTh + (size_t)2*S_*S_, WcTl + (size_t)2*S_*S_, bc + 2*S_,
        (void*)vct_h, B_*D_, S_, S_, 0, 0, 0, (long)NE, D_);

    // 6) channel attention (MFMA flash, S^T trick) -> xcatt bf16 h/l in S1 (xt dead)
    unsigned short* kc_h = (unsigned short*)S3;
    unsigned short* xch  = (unsigned short*)S1;
    k6_mfma<<<dim3(D_/128, HC_, B_), 256, 0, stream>>>(
        qc_h, qc_h + NE, kc_h, kc_h + NE, vct_h, vct_h + NE, xch, xch + NE);

    // 7) final projection -> y f32 in S2 (qc dead)
    mm_mfma<0><<<dim3(S_/128, (B_*D_)/128, 1), 256, 0, stream>>>(
        xch, xch + NE, WcTh + (size_t)3*S_*S_, WcTl + (size_t)3*S_*S_, bc + 3*S_,
        (void*)S2, B_*D_, S_, S_, 0, 0, 0, 0, 1);

    // 8) transpose y -> out [B,S,D]
    k8_trans<<<dim3(S_/64, D_/64, B_), 256, 0, stream>>>(S2, out);
}

// Round 7
// 364.220 us; speedup vs baseline: 6.4383x; 1.0354x over previous
//
#include <hip/hip_runtime.h>
#include <hip/hip_bf16.h>
#include <math.h>

#define B_ 16
#define S_ 256
#define D_ 1024
#define HP_ 16
#define DK_ 64
#define HC_ 8
#define SK_ 32
#define EPS_ 1e-6f

typedef __attribute__((ext_vector_type(8))) short short8v;
typedef __attribute__((ext_vector_type(4))) float f32x4;

__device__ __forceinline__ unsigned short f2bf(float f) {
    unsigned u = __float_as_uint(f);
    u += 0x7fffu + ((u >> 16) & 1u);          // round-to-nearest-even
    return (unsigned short)(u >> 16);
}
__device__ __forceinline__ float bf2f(unsigned short h) {
    return __uint_as_float((unsigned)h << 16);
}
// packed f32x2 -> bf16x2 RNE (v_cvt_pk_bf16_f32 on gfx950)
__device__ __forceinline__ ushort2 f2bf2(float a, float b) {
    __hip_bfloat162 h = __float22bfloat162_rn(make_float2(a, b));
    union { __hip_bfloat162 h2; ushort2 u2; } cv;
    cv.h2 = h;
    return cv.u2;
}

// ---------------- K1: LayerNorm over channels -> bf16 hi/lo split ---------------
__global__ __launch_bounds__(256) void k1_ln_p(
    const float* __restrict__ x, const float* __restrict__ a_p,
    const float* __restrict__ b_p, unsigned short* __restrict__ xh,
    unsigned short* __restrict__ xl)
{
    const int row = blockIdx.x;                  // b*S + s
    const float4* xr = (const float4*)(x + (size_t)row * D_);
    const int tid = threadIdx.x;
    float4 v = xr[tid];
    float s  = v.x + v.y + v.z + v.w;
    float sq = v.x*v.x + v.y*v.y + v.z*v.z + v.w*v.w;
    #pragma unroll
    for (int off = 32; off > 0; off >>= 1) {
        s  += __shfl_down(s, off);
        sq += __shfl_down(sq, off);
    }
    __shared__ float red[8];
    const int wid = tid >> 6, lane = tid & 63;
    if (lane == 0) { red[wid] = s; red[4 + wid] = sq; }
    __syncthreads();
    if (tid == 0) {
        float S0 = red[0] + red[1] + red[2] + red[3];
        float Q0 = red[4] + red[5] + red[6] + red[7];
        float mean = S0 / (float)D_;
        float var  = fmaxf((Q0 - (float)D_ * mean * mean) / (float)(D_ - 1), 0.0f);
        red[0] = mean;
        red[1] = 1.0f / (sqrtf(var) + EPS_);     // torch std(): unbiased; eps on std
    }
    __syncthreads();
    const float mean = red[0], inv = red[1];
    float4 a = ((const float4*)a_p)[tid];
    float4 b = ((const float4*)b_p)[tid];
    float o0 = a.x * (v.x - mean) * inv + b.x;
    float o1 = a.y * (v.y - mean) * inv + b.y;
    float o2 = a.z * (v.z - mean) * inv + b.z;
    float o3 = a.w * (v.w - mean) * inv + b.w;
    ushort2 h01 = f2bf2(o0, o1), h23 = f2bf2(o2, o3);
    ushort2 l01 = f2bf2(o0 - bf2f(h01.x), o1 - bf2f(h01.y));
    ushort2 l23 = f2bf2(o2 - bf2f(h23.x), o3 - bf2f(h23.y));
    ushort4 hv, lv;
    hv.x = h01.x; hv.y = h01.y; hv.z = h23.x; hv.w = h23.y;
    lv.x = l01.x; lv.y = l01.y; lv.z = l23.x; lv.w = l23.y;
    *(ushort4*)&xh[(size_t)row * D_ + tid*4] = hv;
    *(ushort4*)&xl[(size_t)row * D_ + tid*4] = lv;
}

// ------------- Transpose + bf16-split weights: W[k][n] -> T[n][k] hi/lo ---------
__global__ __launch_bounds__(256) void tsplit(
    const float* __restrict__ W, unsigned short* __restrict__ Th,
    unsigned short* __restrict__ Tl, int K, int N)
{
    const int z = blockIdx.z;
    W  += (size_t)z * K * N;
    Th += (size_t)z * K * N;
    Tl += (size_t)z * K * N;
    const int k0 = blockIdx.x * 64, n0 = blockIdx.y * 64;
    __shared__ float tile[64][65];
    const int ix = threadIdx.x & 63, iy = threadIdx.x >> 6;
    #pragma unroll
    for (int u = 0; u < 16; u++) {
        const int kk = iy*16 + u;
        tile[kk][ix] = W[(size_t)(k0+kk)*N + n0 + ix];
    }
    __syncthreads();
    #pragma unroll
    for (int u = 0; u < 16; u += 2) {
        const int nn0 = iy*16 + u, nn1 = nn0 + 1;
        const float v0 = tile[ix][nn0], v1 = tile[ix][nn1];
        ushort2 h2 = f2bf2(v0, v1);
        ushort2 l2 = f2bf2(v0 - bf2f(h2.x), v1 - bf2f(h2.y));
        Th[(size_t)(n0+nn0)*K + k0 + ix] = h2.x;
        Th[(size_t)(n0+nn1)*K + k0 + ix] = h2.y;
        Tl[(size_t)(n0+nn0)*K + k0 + ix] = l2.x;
        Tl[(size_t)(n0+nn1)*K + k0 + ix] = l2.y;
    }
}

// ------------- Split-bf16 MFMA GEMM: C = A*B^T + bias ---------------------------
// OUTMODE 0: f32 row-major. 1: bf16 hi/lo row-major. 2: bf16 hi/lo transposed
// per batch of TB rows. 3: f32 transposed per batch of TB rows (b128 stores).
template<int OUTMODE>
__global__ __launch_bounds__(256) void mm_mfma(
    const unsigned short* __restrict__ Ah, const unsigned short* __restrict__ Al,
    const unsigned short* __restrict__ Bh, const unsigned short* __restrict__ Bl,
    const float* __restrict__ bias, void* __restrict__ Cout,
    int M, int N, int K, long sB, long sBias, long sC, long loff, int TB)
{
    const int z = blockIdx.z;
    Bh   += (size_t)z * sB;
    Bl   += (size_t)z * sB;
    bias += (size_t)z * sBias;
    const int n0 = blockIdx.x * 128, m0 = blockIdx.y * 128;
    __shared__ __align__(16) unsigned short Ash[128][40];
    __shared__ __align__(16) unsigned short Als[128][40];
    __shared__ __align__(16) unsigned short Bsh[128][40];
    __shared__ __align__(16) unsigned short Bls[128][40];
    const int tid = threadIdx.x;
    const int wave = tid >> 6, lane = tid & 63;
    const int wm = wave & 1, wn = wave >> 1;
    const int lrow = lane & 15, quad = lane >> 4;
    const int sr = tid >> 1, sko = (tid & 1) * 16;
    f32x4 acc[4][4];
    #pragma unroll
    for (int j = 0; j < 4; j++) {
        const float bv = bias[n0 + wn*64 + j*16 + lrow];
        #pragma unroll
        for (int i = 0; i < 4; i++) {
            acc[i][j][0] = bv; acc[i][j][1] = bv; acc[i][j][2] = bv; acc[i][j][3] = bv;
        }
    }
    for (int k0 = 0; k0 < K; k0 += 32) {
        const size_t ga = (size_t)(m0 + sr) * K + k0 + sko;
        const size_t gb = (size_t)(n0 + sr) * K + k0 + sko;
        uint4 ah0 = *(const uint4*)&Ah[ga];
        uint4 ah1 = *(const uint4*)&Ah[ga + 8];
        uint4 al0 = *(const uint4*)&Al[ga];
        uint4 al1 = *(const uint4*)&Al[ga + 8];
        uint4 bh0 = *(const uint4*)&Bh[gb];
        uint4 bh1 = *(const uint4*)&Bh[gb + 8];
        uint4 bl0 = *(const uint4*)&Bl[gb];
        uint4 bl1 = *(const uint4*)&Bl[gb + 8];
        __syncthreads();
        *(uint4*)&Ash[sr][sko]     = ah0;
        *(uint4*)&Ash[sr][sko + 8] = ah1;
        *(uint4*)&Als[sr][sko]     = al0;
        *(uint4*)&Als[sr][sko + 8] = al1;
        *(uint4*)&Bsh[sr][sko]     = bh0;
        *(uint4*)&Bsh[sr][sko + 8] = bh1;
        *(uint4*)&Bls[sr][sko]     = bl0;
        *(uint4*)&Bls[sr][sko + 8] = bl1;
        __syncthreads();
        short8v bhf[4], blf[4];
        #pragma unroll
        for (int j = 0; j < 4; j++) {
            bhf[j] = *(const short8v*)&Bsh[wn*64 + j*16 + lrow][quad*8];
            blf[j] = *(const short8v*)&Bls[wn*64 + j*16 + lrow][quad*8];
        }
        #pragma unroll
        for (int i = 0; i < 4; i++) {
            short8v ahf = *(const short8v*)&Ash[wm*64 + i*16 + lrow][quad*8];
            short8v alf = *(const short8v*)&Als[wm*64 + i*16 + lrow][quad*8];
            #pragma unroll
            for (int j = 0; j < 4; j++) {
                acc[i][j] = __builtin_amdgcn_mfma_f32_16x16x32_bf16(ahf, bhf[j], acc[i][j], 0, 0, 0);
                acc[i][j] = __builtin_amdgcn_mfma_f32_16x16x32_bf16(ahf, blf[j], acc[i][j], 0, 0, 0);
                acc[i][j] = __builtin_amdgcn_mfma_f32_16x16x32_bf16(alf, bhf[j], acc[i][j], 0, 0, 0);
            }
        }
    }
    // C/D layout: col = lane&15, row = quad*4 + reg  [m89/m91-verified]
    #pragma unroll
    for (int i = 0; i < 4; i++) {
        const int mrow = m0 + wm*64 + i*16 + quad*4;
        #pragma unroll
        for (int j = 0; j < 4; j++) {
            const int ncol = n0 + wn*64 + j*16 + lrow;
            if (OUTMODE == 0) {
                float* C = (float*)Cout + (size_t)z * sC;
                #pragma unroll
                for (int r = 0; r < 4; r++)
                    C[(size_t)(mrow + r) * N + ncol] = acc[i][j][r];
            } else if (OUTMODE == 1) {
                unsigned short* Ch = (unsigned short*)Cout + (size_t)z * sC;
                unsigned short* Cl = Ch + loff;
                #pragma unroll
                for (int r = 0; r < 4; r += 2) {
                    const float v0 = acc[i][j][r], v1 = acc[i][j][r+1];
                    ushort2 h2 = f2bf2(v0, v1);
                    ushort2 l2 = f2bf2(v0 - bf2f(h2.x), v1 - bf2f(h2.y));
                    Ch[(size_t)(mrow + r    ) * N + ncol] = h2.x;
                    Ch[(size_t)(mrow + r + 1) * N + ncol] = h2.y;
                    Cl[(size_t)(mrow + r    ) * N + ncol] = l2.x;
                    Cl[(size_t)(mrow + r + 1) * N + ncol] = l2.y;
                }
            } else if (OUTMODE == 2) {
                unsigned short* Ch = (unsigned short*)Cout;
                unsigned short* Cl = Ch + loff;
                const int bidx = mrow / TB, t0 = mrow % TB;
                const size_t ad = (size_t)bidx * N * TB + (size_t)ncol * TB + t0;
                const float v0 = acc[i][j][0], v1 = acc[i][j][1];
                const float v2 = acc[i][j][2], v3 = acc[i][j][3];
                ushort2 h01 = f2bf2(v0, v1), h23 = f2bf2(v2, v3);
                ushort2 l01 = f2bf2(v0 - bf2f(h01.x), v1 - bf2f(h01.y));
                ushort2 l23 = f2bf2(v2 - bf2f(h23.x), v3 - bf2f(h23.y));
                ushort4 hv, lv;
                hv.x = h01.x; hv.y = h01.y; hv.z = h23.x; hv.w = h23.y;
                lv.x = l01.x; lv.y = l01.y; lv.z = l23.x; lv.w = l23.y;
                *(ushort4*)&Ch[ad] = hv;
                *(ushort4*)&Cl[ad] = lv;
            } else {
                // f32 transposed: out[bidx][ncol][t0..t0+3], one b128 store
                float* C = (float*)Cout;
                const int bidx = mrow / TB, t0 = mrow % TB;
                f32x4 a4 = acc[i][j];
                *(float4*)&C[((size_t)bidx * N + ncol) * TB + t0] = *(float4*)&a4;
            }
        }
    }
}

// ------- K3: positional attention, MFMA flash, S^T=K*Q^T trick ------------------
// Mtile=64 (wave owns 16 q-rows), Ntile=64 keys, dk=64. P row-major b64, hi-only.
__global__ __launch_bounds__(256) void k3_mfma(
    const unsigned short* __restrict__ qh, const unsigned short* __restrict__ ql,
    const unsigned short* __restrict__ kh, const unsigned short* __restrict__ kl,
    const unsigned short* __restrict__ vth, const unsigned short* __restrict__ vtl,
    float* __restrict__ out)
{
    const int m0 = blockIdx.x * 64;
    const int h = blockIdx.y, b = blockIdx.z;
    const int hoff = h * DK_;
    const size_t rowb = (size_t)b * S_;
    __shared__ __align__(16) unsigned short Ksh[64][72], Ksl[64][72];
    __shared__ __align__(16) unsigned short VTh[64][72], VTl[64][72];
    __shared__ __align__(16) unsigned short Ps[64][72];
    const int tid = threadIdx.x;
    const int w = tid >> 6, lane = tid & 63;
    const int lrow = lane & 15, quad = lane >> 4;
    // Q as B-operand (cols of S^T): hi/lo, 2 k-steps
    short8v bqh[2], bql[2];
    #pragma unroll
    for (int ks = 0; ks < 2; ks++) {
        const size_t qb = (rowb + m0 + w*16 + lrow) * D_ + hoff + ks*32 + quad*8;
        bqh[ks] = *(const short8v*)&qh[qb];
        bql[ks] = *(const short8v*)&ql[qb];
    }
    const int srow = tid >> 2, scol = (tid & 3) * 16;
    f32x4 o[4] = {};
    float lacc = 0.f;
    for (int kt = 0; kt < 4; kt++) {
        const int n00 = kt * 64;
        const size_t kb = (rowb + n00 + srow) * D_ + hoff + scol;
        const size_t vb = ((size_t)b * D_ + hoff + srow) * S_ + n00 + scol;
        uint4 kH0 = *(const uint4*)&kh[kb];
        uint4 kH1 = *(const uint4*)&kh[kb + 8];
        uint4 kL0 = *(const uint4*)&kl[kb];
        uint4 kL1 = *(const uint4*)&kl[kb + 8];
        uint4 vH0 = *(const uint4*)&vth[vb];
        uint4 vH1 = *(const uint4*)&vth[vb + 8];
        uint4 vL0 = *(const uint4*)&vtl[vb];
        uint4 vL1 = *(const uint4*)&vtl[vb + 8];
        __syncthreads();   // prev iter LDS reads done
        *(uint4*)&Ksh[srow][scol]     = kH0;
        *(uint4*)&Ksh[srow][scol + 8] = kH1;
        *(uint4*)&Ksl[srow][scol]     = kL0;
        *(uint4*)&Ksl[srow][scol + 8] = kL1;
        *(uint4*)&VTh[srow][scol]     = vH0;
        *(uint4*)&VTh[srow][scol + 8] = vH1;
        *(uint4*)&VTl[srow][scol]     = vL0;
        *(uint4*)&VTl[srow][scol + 8] = vL1;
        __syncthreads();
        // S^T = K·Q^T: rows=keys (A=K), cols=queries (B=Q regs)
        f32x4 sa[4] = {};
        #pragma unroll
        for (int ks = 0; ks < 2; ks++) {
            #pragma unroll
            for (int jk = 0; jk < 4; jk++) {
                short8v akh = *(const short8v*)&Ksh[jk*16 + lrow][ks*32 + quad*8];
                short8v akl = *(const short8v*)&Ksl[jk*16 + lrow][ks*32 + quad*8];
                sa[jk] = __builtin_amdgcn_mfma_f32_16x16x32_bf16(akh, bqh[ks], sa[jk], 0, 0, 0);
                sa[jk] = __builtin_amdgcn_mfma_f32_16x16x32_bf16(akl, bqh[ks], sa[jk], 0, 0, 0);
                sa[jk] = __builtin_amdgcn_mfma_f32_16x16x32_bf16(akh, bql[ks], sa[jk], 0, 0, 0);
            }
        }
        // exp; P[m][key] row-major, b64 per frag (4 consecutive keys per lane)
        #pragma unroll
        for (int jk = 0; jk < 4; jk++) {
            float p0 = __expf(sa[jk][0] * 0.125f);
            float p1 = __expf(sa[jk][1] * 0.125f);
            float p2 = __expf(sa[jk][2] * 0.125f);
            float p3 = __expf(sa[jk][3] * 0.125f);
            lacc += (p0 + p1) + (p2 + p3);
            ushort2 p01 = f2bf2(p0, p1), p23 = f2bf2(p2, p3);
            ushort4 ph;
            ph.x = p01.x; ph.y = p01.y; ph.z = p23.x; ph.w = p23.y;
            *(ushort4*)&Ps[w*16 + lrow][jk*16 + quad*4] = ph;   // wave-private rows
        }
        // PV: O = P·V^T' (A=P rows m, B=VT rows d) — no barrier (wave-private P)
        #pragma unroll
        for (int ks = 0; ks < 2; ks++) {
            short8v ap = *(const short8v*)&Ps[w*16 + lrow][ks*32 + quad*8];
            #pragma unroll
            for (int nf = 0; nf < 4; nf++) {
                short8v vH = *(const short8v*)&VTh[nf*16 + lrow][ks*32 + quad*8];
                short8v vL = *(const short8v*)&VTl[nf*16 + lrow][ks*32 + quad*8];
                o[nf] = __builtin_amdgcn_mfma_f32_16x16x32_bf16(ap, vH, o[nf], 0, 0, 0);
                o[nf] = __builtin_amdgcn_mfma_f32_16x16x32_bf16(ap, vL, o[nf], 0, 0, 0);
            }
        }
    }
    // l: lane holds partials for col m=lrow (its quad's keys) -> sum over quads
    lacc += __shfl_xor(lacc, 16);
    lacc += __shfl_xor(lacc, 32);
    #pragma unroll
    for (int r = 0; r < 4; r++) {
        const float linv = 1.0f / __shfl(lacc, quad*4 + r);
        #pragma unroll
        for (int nf = 0; nf < 4; nf++)
            out[(rowb + m0 + w*16 + quad*4 + r) * D_ + hoff + nf*16 + lrow] =
                o[nf][r] * linv;
    }
}

// ------- K6: channel attention, MFMA flash, S^T trick. Mtile=128, Ntile=64 ------
// dk=32. Wave owns 32 q-rows (2 m-frags). P hi-only b64. Out bf16 h/l.
__global__ __launch_bounds__(256) void k6_mfma(
    const unsigned short* __restrict__ qch, const unsigned short* __restrict__ qcl,
    const unsigned short* __restrict__ kch, const unsigned short* __restrict__ kcl,
    const unsigned short* __restrict__ vth, const unsigned short* __restrict__ vtl,
    unsigned short* __restrict__ oh, unsigned short* __restrict__ ol)
{
    const int m0 = blockIdx.x * 128;
    const int h = blockIdx.y, b = blockIdx.z;
    const int hoff = h * SK_;
    const size_t rowb = (size_t)b * D_;
    __shared__ __align__(16) unsigned short Ksh[64][40], Ksl[64][40];
    __shared__ __align__(16) unsigned short VTh[32][72], VTl[32][72];
    __shared__ __align__(16) unsigned short Ps[128][72];
    const int tid = threadIdx.x;
    const int w = tid >> 6, lane = tid & 63;
    const int lrow = lane & 15, quad = lane >> 4;
    short8v bqh[2], bql[2];
    #pragma unroll
    for (int i = 0; i < 2; i++) {
        const size_t qb = (rowb + m0 + w*32 + i*16 + lrow) * S_ + hoff + quad*8;
        bqh[i] = *(const short8v*)&qch[qb];
        bql[i] = *(const short8v*)&qcl[qb];
    }
    const int krow = tid >> 2, kcol = (tid & 3) * 8;
    const int vrow = tid >> 3, vcol = (tid & 7) * 8;
    f32x4 o[2][2] = {};
    float lacc[2] = {0.f, 0.f};
    for (int kt = 0; kt < 16; kt++) {
        const int n00 = kt * 64;
        const size_t kb = (rowb + n00 + krow) * S_ + hoff + kcol;
        const size_t vb = ((size_t)b * S_ + hoff + vrow) * D_ + n00 + vcol;
        uint4 kH = *(const uint4*)&kch[kb];
        uint4 kL = *(const uint4*)&kcl[kb];
        uint4 vH = *(const uint4*)&vth[vb];
        uint4 vL = *(const uint4*)&vtl[vb];
        __syncthreads();
        *(uint4*)&Ksh[krow][kcol] = kH;
        *(uint4*)&Ksl[krow][kcol] = kL;
        *(uint4*)&VTh[vrow][vcol] = vH;
        *(uint4*)&VTl[vrow][vcol] = vL;
        __syncthreads();
        // S^T = K·Q^T
        f32x4 sa[2][4] = {};
        #pragma unroll
        for (int jk = 0; jk < 4; jk++) {
            short8v akh = *(const short8v*)&Ksh[jk*16 + lrow][quad*8];
            short8v akl = *(const short8v*)&Ksl[jk*16 + lrow][quad*8];
            #pragma unroll
            for (int i = 0; i < 2; i++) {
                sa[i][jk] = __builtin_amdgcn_mfma_f32_16x16x32_bf16(akh, bqh[i], sa[i][jk], 0, 0, 0);
                sa[i][jk] = __builtin_amdgcn_mfma_f32_16x16x32_bf16(akl, bqh[i], sa[i][jk], 0, 0, 0);
                sa[i][jk] = __builtin_amdgcn_mfma_f32_16x16x32_bf16(akh, bql[i], sa[i][jk], 0, 0, 0);
            }
        }
        // exp; P row-major [m][key], b64 writes, wave-private rows
        #pragma unroll
        for (int i = 0; i < 2; i++)
            #pragma unroll
            for (int jk = 0; jk < 4; jk++) {
                float p0 = __expf(sa[i][jk][0] * 0.17677669529663687f);
                float p1 = __expf(sa[i][jk][1] * 0.17677669529663687f);
                float p2 = __expf(sa[i][jk][2] * 0.17677669529663687f);
                float p3 = __expf(sa[i][jk][3] * 0.17677669529663687f);
                lacc[i] += (p0 + p1) + (p2 + p3);
                ushort2 p01 = f2bf2(p0, p1), p23 = f2bf2(p2, p3);
                ushort4 ph;
                ph.x = p01.x; ph.y = p01.y; ph.z = p23.x; ph.w = p23.y;
                *(ushort4*)&Ps[w*32 + i*16 + lrow][jk*16 + quad*4] = ph;
            }
        // PV (no barrier needed: P rows wave-private)
        #pragma unroll
        for (int ks = 0; ks < 2; ks++) {
            short8v ap[2];
            #pragma unroll
            for (int i = 0; i < 2; i++)
                ap[i] = *(const short8v*)&Ps[w*32 + i*16 + lrow][ks*32 + quad*8];
            #pragma unroll
            for (int nf = 0; nf < 2; nf++) {
                short8v vHf = *(const short8v*)&VTh[nf*16 + lrow][ks*32 + quad*8];
                short8v vLf = *(const short8v*)&VTl[nf*16 + lrow][ks*32 + quad*8];
                #pragma unroll
                for (int i = 0; i < 2; i++) {
                    o[i][nf] = __builtin_amdgcn_mfma_f32_16x16x32_bf16(ap[i], vHf, o[i][nf], 0, 0, 0);
                    o[i][nf] = __builtin_amdgcn_mfma_f32_16x16x32_bf16(ap[i], vLf, o[i][nf], 0, 0, 0);
                }
            }
        }
    }
    #pragma unroll
    for (int i = 0; i < 2; i++) {
        lacc[i] += __shfl_xor(lacc[i], 16);
        lacc[i] += __shfl_xor(lacc[i], 32);
    }
    #pragma unroll
    for (int i = 0; i < 2; i++)
        #pragma unroll
        for (int r = 0; r < 4; r++) {
            const float linv = 1.0f / __shfl(lacc[i], quad*4 + r);
            const float v0 = o[i][0][r] * linv;
            const float v1 = o[i][1][r] * linv;
            ushort2 h2 = f2bf2(v0, v1);
            ushort2 l2 = f2bf2(v0 - bf2f(h2.x), v1 - bf2f(h2.y));
            const size_t idx =
                (rowb + m0 + w*32 + i*16 + quad*4 + r) * S_ + hoff + lrow;
            oh[idx]      = h2.x;
            oh[idx + 16] = h2.y;
            ol[idx]      = l2.x;
            ol[idx + 16] = l2.y;
        }
}

// ---------------- K4a: per-(b,d) stats over sequence dim ----------------
__global__ __launch_bounds__(256) void k4a_stats(
    const float* __restrict__ x, float* __restrict__ meanc, float* __restrict__ invc)
{
    const int d = blockIdx.x * 256 + threadIdx.x;
    const int b = blockIdx.y;
    const float* p = x + (size_t)b * S_ * D_ + d;
    float s = 0.f, q = 0.f;
    for (int t = 0; t < S_; t++) { float vv = p[(size_t)t * D_]; s += vv; q += vv*vv; }
    const float mean = s / (float)S_;
    const float var  = fmaxf((q - (float)S_ * mean * mean) / (float)(S_ - 1), 0.0f);
    meanc[b*D_ + d] = mean;
    invc[b*D_ + d]  = 1.0f / (sqrtf(var) + EPS_);
}

// ------- K4b: LN over seq + transpose to [B,D,S], output bf16 hi/lo split --------
__global__ __launch_bounds__(256) void k4b_ntrans(
    const float* __restrict__ x, const float* __restrict__ meanc,
    const float* __restrict__ invc, const float* __restrict__ a_c,
    const float* __restrict__ b_c, unsigned short* __restrict__ xth,
    unsigned short* __restrict__ xtl)
{
    const int s0 = blockIdx.x * 64, d0 = blockIdx.y * 64, b = blockIdx.z;
    __shared__ float tile[64][65];
    const int ix = threadIdx.x & 63, iy = threadIdx.x >> 6;
    const int d = d0 + ix;
    const float mean = meanc[b*D_ + d], inv = invc[b*D_ + d];
    #pragma unroll
    for (int u = 0; u < 16; u++) {
        const int srow = iy*16 + u;
        const float vv = x[((size_t)(b*S_ + s0 + srow)) * D_ + d];
        tile[srow][ix] = a_c[s0+srow] * (vv - mean) * inv + b_c[s0+srow];
    }
    __syncthreads();
    const int sx = (threadIdx.x & 31) * 2, dbase = threadIdx.x >> 5;
    #pragma unroll
    for (int u = 0; u < 8; u++) {
        const int drow = dbase + u*8;
        const float v0 = tile[sx][drow], v1 = tile[sx+1][drow];
        ushort2 h2 = f2bf2(v0, v1);
        ushort2 l2 = f2bf2(v0 - bf2f(h2.x), v1 - bf2f(h2.y));
        const size_t idx = ((size_t)(b*D_ + d0 + drow)) * S_ + s0 + sx;
        *(ushort2*)&xth[idx] = h2;
        *(ushort2*)&xtl[idx] = l2;
    }
}

extern "C" void kernel_launch(void* const* d_in, const int* in_sizes, int n_in,
                              void* d_out, int out_size, void* d_ws, size_t ws_size,
                              hipStream_t stream)
{
    const float* x   = (const float*)d_in[0];
    const float* Wp  = (const float*)d_in[1];
    const float* bp  = (const float*)d_in[2];
    const float* Wc  = (const float*)d_in[3];
    const float* bc  = (const float*)d_in[4];
    const float* a_p = (const float*)d_in[5];
    const float* b_p = (const float*)d_in[6];
    const float* a_c = (const float*)d_in[7];
    const float* b_c = (const float*)d_in[8];
    float* out = (float*)d_out;
    float* ws  = (float*)d_ws;
    const size_t NE = (size_t)B_ * S_ * D_;     // 4,194,304

    float* S0 = ws;             // xp h/l -> attn f32 -> vcT h/l
    float* S1 = ws + NE;        // q h/l -> xt h/l -> xcatt h/l
    float* S2 = ws + 2*NE;      // k h/l -> qc h/l
    float* S3 = ws + 3*NE;      // vT h/l -> kc h/l
    float* meanc = ws + 4*NE;
    float* invc  = meanc + (size_t)B_*D_;
    unsigned short* SW = (unsigned short*)(invc + (size_t)B_*D_);

    const size_t baseBytes = (4*NE + 2*(size_t)B_*D_) * sizeof(float);
    const bool big = ws_size >= baseBytes + (size_t)2 * 3 * D_ * D_ * sizeof(unsigned short) * 2;

    unsigned short* xh = (unsigned short*)S0;
    unsigned short* xl = xh + NE;
    unsigned short* q_h  = (unsigned short*)S1;
    unsigned short* k_h  = (unsigned short*)S2;
    unsigned short* vt_h = (unsigned short*)S3;

    // 1) LayerNorm over channels -> bf16 hi/lo
    k1_ln_p<<<dim3(B_*S_), 256, 0, stream>>>(x, a_p, b_p, xh, xl);

    // 2) QKV projection: q,k row-major bf16 h/l; v transposed bf16 h/l
    if (big) {
        unsigned short* WTh = SW;
        unsigned short* WTl = WTh + (size_t)3 * D_ * D_;
        tsplit<<<dim3(D_/64, D_/64, 3), 256, 0, stream>>>(Wp, WTh, WTl, D_, D_);
        mm_mfma<1><<<dim3(D_/128, (B_*S_)/128, 2), 256, 0, stream>>>(
            xh, xl, WTh, WTl, bp, (void*)q_h,
            B_*S_, D_, D_, (long)D_*D_, (long)D_, (long)(2*NE), (long)NE, 1);
        mm_mfma<2><<<dim3(D_/128, (B_*S_)/128, 1), 256, 0, stream>>>(
            xh, xl, WTh + (size_t)2*D_*D_, WTl + (size_t)2*D_*D_, bp + 2*D_,
            (void*)vt_h, B_*S_, D_, D_, 0, 0, 0, (long)NE, S_);
    } else {
        unsigned short* WTh = SW;
        unsigned short* WTl = WTh + (size_t)D_ * D_;
        for (int z = 0; z < 3; z++) {
            tsplit<<<dim3(D_/64, D_/64, 1), 256, 0, stream>>>(
                Wp + (size_t)z*D_*D_, WTh, WTl, D_, D_);
            if (z < 2)
                mm_mfma<1><<<dim3(D_/128, (B_*S_)/128, 1), 256, 0, stream>>>(
                    xh, xl, WTh, WTl, bp + (size_t)z*D_,
                    (void*)(q_h + (size_t)z*2*NE),
                    B_*S_, D_, D_, 0, 0, 0, (long)NE, 1);
            else
                mm_mfma<2><<<dim3(D_/128, (B_*S_)/128, 1), 256, 0, stream>>>(
                    xh, xl, WTh, WTl, bp + (size_t)z*D_, (void*)vt_h,
                    B_*S_, D_, D_, 0, 0, 0, (long)NE, S_);
        }
    }

    // 3) positional attention (MFMA flash, S^T trick) -> attn f32 in S0 (xp dead)
    k3_mfma<<<dim3(S_/64, HP_, B_), 256, 0, stream>>>(
        q_h, q_h + NE, k_h, k_h + NE, vt_h, vt_h + NE, S0);

    // 4) LN over sequence -> xt bf16 h/l in S1 (q dead)
    k4a_stats<<<dim3(D_/256, B_), 256, 0, stream>>>(S0, meanc, invc);
    unsigned short* xth = (unsigned short*)S1;
    k4b_ntrans<<<dim3(S_/64, D_/64, B_), 256, 0, stream>>>(
        S0, meanc, invc, a_c, b_c, xth, xth + NE);

    // 5) channel weights + channel QKV: qc,kc row-major; vc transposed
    unsigned short* WcTh = SW;
    unsigned short* WcTl = WcTh + (size_t)4 * S_ * S_;
    tsplit<<<dim3(S_/64, S_/64, 4), 256, 0, stream>>>(Wc, WcTh, WcTl, S_, S_);
    unsigned short* qc_h  = (unsigned short*)S2;   // k dead
    unsigned short* vct_h = (unsigned short*)S0;   // attn f32 dead after k4b
    mm_mfma<1><<<dim3(S_/128, (B_*D_)/128, 2), 256, 0, stream>>>(
        xth, xth + NE, WcTh, WcTl, bc, (void*)qc_h,
        B_*D_, S_, S_, (long)S_*S_, (long)S_, (long)(2*NE), (long)NE, 1);
    mm_mfma<2><<<dim3(S_/128, (B_*D_)/128, 1), 256, 0, stream>>>(
        xth, xth + NE, WcTh + (size_t)2*S_*S_, WcTl + (size_t)2*S_*S_, bc + 2*S_,
        (void*)vct_h, B_*D_, S_, S_, 0, 0, 0, (long)NE, D_);

    // 6) channel attention (MFMA flash, S^T trick) -> xcatt bf16 h/l in S1 (xt dead)
    unsigned short* kc_h = (unsigned short*)S3;
    unsigned short* xch  = (unsigned short*)S1;
    k6_mfma<<<dim3(D_/128, HC_, B_), 256, 0, stream>>>(
        qc_h, qc_h + NE, kc_h, kc_h + NE, vct_h, vct_h + NE, xch, xch + NE);

    // 7) final projection -> out directly (f32 transposed epilogue; k8 eliminated)
    mm_mfma<3><<<dim3(S_/128, (B_*D_)/128, 1), 256, 0, stream>>>(
        xch, xch + NE, WcTh + (size_t)3*S_*S_, WcTl + (size_t)3*S_*S_, bc + 3*S_,
        (void*)out, B_*D_, S_, S_, 0, 0, 0, 0, D_);
}

// Round 8
// 356.667 us; speedup vs baseline: 6.5746x; 1.0212x over previous
//
#include <hip/hip_runtime.h>
#include <hip/hip_bf16.h>
#include <math.h>

#define B_ 16
#define S_ 256
#define D_ 1024
#define HP_ 16
#define DK_ 64
#define HC_ 8
#define SK_ 32
#define EPS_ 1e-6f

typedef __attribute__((ext_vector_type(8))) short short8v;
typedef __attribute__((ext_vector_type(4))) float f32x4;

__device__ __forceinline__ unsigned short f2bf(float f) {
    unsigned u = __float_as_uint(f);
    u += 0x7fffu + ((u >> 16) & 1u);          // round-to-nearest-even
    return (unsigned short)(u >> 16);
}
__device__ __forceinline__ float bf2f(unsigned short h) {
    return __uint_as_float((unsigned)h << 16);
}
// packed f32x2 -> bf16x2 RNE (v_cvt_pk_bf16_f32 on gfx950)
__device__ __forceinline__ ushort2 f2bf2(float a, float b) {
    __hip_bfloat162 h = __float22bfloat162_rn(make_float2(a, b));
    union { __hip_bfloat162 h2; ushort2 u2; } cv;
    cv.h2 = h;
    return cv.u2;
}
// async global->LDS, 16B per lane; LDS dest = wave-uniform base + lane*16
__device__ __forceinline__ void ldlds16(const unsigned short* g, unsigned short* l) {
    const unsigned int* gp = reinterpret_cast<const unsigned int*>(g);
    auto* lp = reinterpret_cast<__attribute__((address_space(3))) unsigned int*>(
        reinterpret_cast<uintptr_t>(l));
    __builtin_amdgcn_global_load_lds(gp, lp, 16, 0, 0);
}

// ---------------- K1: LayerNorm over channels -> bf16 hi/lo split ---------------
__global__ __launch_bounds__(256) void k1_ln_p(
    const float* __restrict__ x, const float* __restrict__ a_p,
    const float* __restrict__ b_p, unsigned short* __restrict__ xh,
    unsigned short* __restrict__ xl)
{
    const int row = blockIdx.x;                  // b*S + s
    const float4* xr = (const float4*)(x + (size_t)row * D_);
    const int tid = threadIdx.x;
    float4 v = xr[tid];
    float s  = v.x + v.y + v.z + v.w;
    float sq = v.x*v.x + v.y*v.y + v.z*v.z + v.w*v.w;
    #pragma unroll
    for (int off = 32; off > 0; off >>= 1) {
        s  += __shfl_down(s, off);
        sq += __shfl_down(sq, off);
    }
    __shared__ float red[8];
    const int wid = tid >> 6, lane = tid & 63;
    if (lane == 0) { red[wid] = s; red[4 + wid] = sq; }
    __syncthreads();
    if (tid == 0) {
        float S0 = red[0] + red[1] + red[2] + red[3];
        float Q0 = red[4] + red[5] + red[6] + red[7];
        float mean = S0 / (float)D_;
        float var  = fmaxf((Q0 - (float)D_ * mean * mean) / (float)(D_ - 1), 0.0f);
        red[0] = mean;
        red[1] = 1.0f / (sqrtf(var) + EPS_);     // torch std(): unbiased; eps on std
    }
    __syncthreads();
    const float mean = red[0], inv = red[1];
    float4 a = ((const float4*)a_p)[tid];
    float4 b = ((const float4*)b_p)[tid];
    float o0 = a.x * (v.x - mean) * inv + b.x;
    float o1 = a.y * (v.y - mean) * inv + b.y;
    float o2 = a.z * (v.z - mean) * inv + b.z;
    float o3 = a.w * (v.w - mean) * inv + b.w;
    ushort2 h01 = f2bf2(o0, o1), h23 = f2bf2(o2, o3);
    ushort2 l01 = f2bf2(o0 - bf2f(h01.x), o1 - bf2f(h01.y));
    ushort2 l23 = f2bf2(o2 - bf2f(h23.x), o3 - bf2f(h23.y));
    ushort4 hv, lv;
    hv.x = h01.x; hv.y = h01.y; hv.z = h23.x; hv.w = h23.y;
    lv.x = l01.x; lv.y = l01.y; lv.z = l23.x; lv.w = l23.y;
    *(ushort4*)&xh[(size_t)row * D_ + tid*4] = hv;
    *(ushort4*)&xl[(size_t)row * D_ + tid*4] = lv;
}

// ------------- Transpose + bf16-split weights: W[k][n] -> T[n][k] hi/lo ---------
__global__ __launch_bounds__(256) void tsplit(
    const float* __restrict__ W, unsigned short* __restrict__ Th,
    unsigned short* __restrict__ Tl, int K, int N)
{
    const int z = blockIdx.z;
    W  += (size_t)z * K * N;
    Th += (size_t)z * K * N;
    Tl += (size_t)z * K * N;
    const int k0 = blockIdx.x * 64, n0 = blockIdx.y * 64;
    __shared__ float tile[64][65];
    const int ix = threadIdx.x & 63, iy = threadIdx.x >> 6;
    #pragma unroll
    for (int u = 0; u < 16; u++) {
        const int kk = iy*16 + u;
        tile[kk][ix] = W[(size_t)(k0+kk)*N + n0 + ix];
    }
    __syncthreads();
    #pragma unroll
    for (int u = 0; u < 16; u += 2) {
        const int nn0 = iy*16 + u, nn1 = nn0 + 1;
        const float v0 = tile[ix][nn0], v1 = tile[ix][nn1];
        ushort2 h2 = f2bf2(v0, v1);
        ushort2 l2 = f2bf2(v0 - bf2f(h2.x), v1 - bf2f(h2.y));
        Th[(size_t)(n0+nn0)*K + k0 + ix] = h2.x;
        Th[(size_t)(n0+nn1)*K + k0 + ix] = h2.y;
        Tl[(size_t)(n0+nn0)*K + k0 + ix] = l2.x;
        Tl[(size_t)(n0+nn1)*K + k0 + ix] = l2.y;
    }
}

// ------------- Split-bf16 MFMA GEMM: C = A*B^T + bias ---------------------------
// Staging via global_load_lds (async DMA) into XOR-swizzled LDS (pitch 32, no pad):
//   chunk(row, cc) stored at p = row*4 + (cc ^ ((row>>1)&3)), 16B chunks.
// OUTMODE 0: f32 row-major. 1: bf16 hi/lo row-major. 2: bf16 hi/lo transposed
// per batch of TB rows. 3: f32 transposed per batch of TB rows (b128 stores).
template<int OUTMODE>
__global__ __launch_bounds__(256) void mm_mfma(
    const unsigned short* __restrict__ Ah, const unsigned short* __restrict__ Al,
    const unsigned short* __restrict__ Bh, const unsigned short* __restrict__ Bl,
    const float* __restrict__ bias, void* __restrict__ Cout,
    int M, int N, int K, long sB, long sBias, long sC, long loff, int TB)
{
    const int z = blockIdx.z;
    Bh   += (size_t)z * sB;
    Bl   += (size_t)z * sB;
    bias += (size_t)z * sBias;
    const int n0 = blockIdx.x * 128, m0 = blockIdx.y * 128;
    __shared__ __align__(16) unsigned short Ash[128*32], Als[128*32];
    __shared__ __align__(16) unsigned short Bsh[128*32], Bls[128*32];
    const int tid = threadIdx.x;
    const int wave = tid >> 6, lane = tid & 63;
    const int wm = wave & 1, wn = wave >> 1;
    const int lrow = lane & 15, quad = lane >> 4;
    // DMA source offsets: chunk p = wave*128 + j*64 + lane
    size_t gaOff[2], gbOff[2];
    int cb[2];
    #pragma unroll
    for (int j = 0; j < 2; j++) {
        const int p = wave*128 + j*64 + lane;
        const int row = p >> 2;
        const int cc = (p & 3) ^ ((row >> 1) & 3);
        gaOff[j] = (size_t)(m0 + row) * K + cc*8;
        gbOff[j] = (size_t)(n0 + row) * K + cc*8;
        cb[j] = (wave*128 + j*64) * 8;
    }
    // fragment read offsets (swizzled)
    int aFr[4], bFr[4];
    #pragma unroll
    for (int i = 0; i < 4; i++) {
        const int ra = wm*64 + i*16 + lrow;
        aFr[i] = ((ra << 2) | (quad ^ ((ra >> 1) & 3))) * 8;
        const int rb = wn*64 + i*16 + lrow;
        bFr[i] = ((rb << 2) | (quad ^ ((rb >> 1) & 3))) * 8;
    }
    f32x4 acc[4][4];
    #pragma unroll
    for (int j = 0; j < 4; j++) {
        const float bv = bias[n0 + wn*64 + j*16 + lrow];
        #pragma unroll
        for (int i = 0; i < 4; i++) {
            acc[i][j][0] = bv; acc[i][j][1] = bv; acc[i][j][2] = bv; acc[i][j][3] = bv;
        }
    }
    for (int k0 = 0; k0 < K; k0 += 32) {
        __syncthreads();             // prev iter fragment reads done
        #pragma unroll
        for (int j = 0; j < 2; j++) {
            ldlds16(Ah + gaOff[j] + k0, &Ash[cb[j]]);
            ldlds16(Al + gaOff[j] + k0, &Als[cb[j]]);
            ldlds16(Bh + gbOff[j] + k0, &Bsh[cb[j]]);
            ldlds16(Bl + gbOff[j] + k0, &Bls[cb[j]]);
        }
        __syncthreads();             // vmcnt drain + barrier
        short8v bhf[4], blf[4];
        #pragma unroll
        for (int j = 0; j < 4; j++) {
            bhf[j] = *(const short8v*)&Bsh[bFr[j]];
            blf[j] = *(const short8v*)&Bls[bFr[j]];
        }
        #pragma unroll
        for (int i = 0; i < 4; i++) {
            short8v ahf = *(const short8v*)&Ash[aFr[i]];
            short8v alf = *(const short8v*)&Als[aFr[i]];
            #pragma unroll
            for (int j = 0; j < 4; j++) {
                acc[i][j] = __builtin_amdgcn_mfma_f32_16x16x32_bf16(ahf, bhf[j], acc[i][j], 0, 0, 0);
                acc[i][j] = __builtin_amdgcn_mfma_f32_16x16x32_bf16(ahf, blf[j], acc[i][j], 0, 0, 0);
                acc[i][j] = __builtin_amdgcn_mfma_f32_16x16x32_bf16(alf, bhf[j], acc[i][j], 0, 0, 0);
            }
        }
    }
    // C/D layout: col = lane&15, row = quad*4 + reg  [m89/m91-verified]
    #pragma unroll
    for (int i = 0; i < 4; i++) {
        const int mrow = m0 + wm*64 + i*16 + quad*4;
        #pragma unroll
        for (int j = 0; j < 4; j++) {
            const int ncol = n0 + wn*64 + j*16 + lrow;
            if (OUTMODE == 0) {
                float* C = (float*)Cout + (size_t)z * sC;
                #pragma unroll
                for (int r = 0; r < 4; r++)
                    C[(size_t)(mrow + r) * N + ncol] = acc[i][j][r];
            } else if (OUTMODE == 1) {
                unsigned short* Ch = (unsigned short*)Cout + (size_t)z * sC;
                unsigned short* Cl = Ch + loff;
                #pragma unroll
                for (int r = 0; r < 4; r += 2) {
                    const float v0 = acc[i][j][r], v1 = acc[i][j][r+1];
                    ushort2 h2 = f2bf2(v0, v1);
                    ushort2 l2 = f2bf2(v0 - bf2f(h2.x), v1 - bf2f(h2.y));
                    Ch[(size_t)(mrow + r    ) * N + ncol] = h2.x;
                    Ch[(size_t)(mrow + r + 1) * N + ncol] = h2.y;
                    Cl[(size_t)(mrow + r    ) * N + ncol] = l2.x;
                    Cl[(size_t)(mrow + r + 1) * N + ncol] = l2.y;
                }
            } else if (OUTMODE == 2) {
                unsigned short* Ch = (unsigned short*)Cout;
                unsigned short* Cl = Ch + loff;
                const int bidx = mrow / TB, t0 = mrow % TB;
                const size_t ad = (size_t)bidx * N * TB + (size_t)ncol * TB + t0;
                const float v0 = acc[i][j][0], v1 = acc[i][j][1];
                const float v2 = acc[i][j][2], v3 = acc[i][j][3];
                ushort2 h01 = f2bf2(v0, v1), h23 = f2bf2(v2, v3);
                ushort2 l01 = f2bf2(v0 - bf2f(h01.x), v1 - bf2f(h01.y));
                ushort2 l23 = f2bf2(v2 - bf2f(h23.x), v3 - bf2f(h23.y));
                ushort4 hv, lv;
                hv.x = h01.x; hv.y = h01.y; hv.z = h23.x; hv.w = h23.y;
                lv.x = l01.x; lv.y = l01.y; lv.z = l23.x; lv.w = l23.y;
                *(ushort4*)&Ch[ad] = hv;
                *(ushort4*)&Cl[ad] = lv;
            } else {
                // f32 transposed: out[bidx][ncol][t0..t0+3], one b128 store
                float* C = (float*)Cout;
                const int bidx = mrow / TB, t0 = mrow % TB;
                f32x4 a4 = acc[i][j];
                *(float4*)&C[((size_t)bidx * N + ncol) * TB + t0] = *(float4*)&a4;
            }
        }
    }
}

// ------- K3: positional attention, MFMA flash, S^T=K*Q^T trick, DMA staging -----
// Mtile=64 (wave owns 16 q-rows), Ntile=64 keys, dk=64. P row-major b64, hi-only.
// K/V LDS: pitch 64 shorts, swizzle p = row*8 + (cc ^ (row&7)).
__global__ __launch_bounds__(256) void k3_mfma(
    const unsigned short* __restrict__ qh, const unsigned short* __restrict__ ql,
    const unsigned short* __restrict__ kh, const unsigned short* __restrict__ kl,
    const unsigned short* __restrict__ vth, const unsigned short* __restrict__ vtl,
    float* __restrict__ out)
{
    const int m0 = blockIdx.x * 64;
    const int h = blockIdx.y, b = blockIdx.z;
    const int hoff = h * DK_;
    const size_t rowb = (size_t)b * S_;
    __shared__ __align__(16) unsigned short Ksh[64*64], Ksl[64*64];
    __shared__ __align__(16) unsigned short VTh[64*64], VTl[64*64];
    __shared__ __align__(16) unsigned short Ps[64][72];
    const int tid = threadIdx.x;
    const int w = tid >> 6, lane = tid & 63;
    const int lrow = lane & 15, quad = lane >> 4;
    // Q as B-operand (cols of S^T): hi/lo, 2 k-steps
    short8v bqh[2], bql[2];
    #pragma unroll
    for (int ks = 0; ks < 2; ks++) {
        const size_t qb = (rowb + m0 + w*16 + lrow) * D_ + hoff + ks*32 + quad*8;
        bqh[ks] = *(const short8v*)&qh[qb];
        bql[ks] = *(const short8v*)&ql[qb];
    }
    size_t kOff[2], vOff[2];
    int cb[2];
    #pragma unroll
    for (int j = 0; j < 2; j++) {
        const int p = w*128 + j*64 + lane;
        const int row = p >> 3;
        const int cc = (p & 7) ^ (row & 7);
        kOff[j] = (rowb + row) * D_ + hoff + cc*8;
        vOff[j] = ((size_t)b * D_ + hoff + row) * S_ + cc*8;
        cb[j] = (w*128 + j*64) * 8;
    }
    f32x4 o[4] = {};
    float lacc = 0.f;
    for (int kt = 0; kt < 4; kt++) {
        const int n00 = kt * 64;
        __syncthreads();   // prev iter LDS reads done
        #pragma unroll
        for (int j = 0; j < 2; j++) {
            ldlds16(kh  + kOff[j] + (size_t)n00 * D_, &Ksh[cb[j]]);
            ldlds16(kl  + kOff[j] + (size_t)n00 * D_, &Ksl[cb[j]]);
            ldlds16(vth + vOff[j] + n00,              &VTh[cb[j]]);
            ldlds16(vtl + vOff[j] + n00,              &VTl[cb[j]]);
        }
        __syncthreads();
        // S^T = K·Q^T: rows=keys (A=K), cols=queries (B=Q regs)
        f32x4 sa[4] = {};
        #pragma unroll
        for (int ks = 0; ks < 2; ks++) {
            #pragma unroll
            for (int jk = 0; jk < 4; jk++) {
                const int r = jk*16 + lrow, c = ks*4 + quad;
                const int off = ((r << 3) | (c ^ (r & 7))) * 8;
                short8v akh = *(const short8v*)&Ksh[off];
                short8v akl = *(const short8v*)&Ksl[off];
                sa[jk] = __builtin_amdgcn_mfma_f32_16x16x32_bf16(akh, bqh[ks], sa[jk], 0, 0, 0);
                sa[jk] = __builtin_amdgcn_mfma_f32_16x16x32_bf16(akl, bqh[ks], sa[jk], 0, 0, 0);
                sa[jk] = __builtin_amdgcn_mfma_f32_16x16x32_bf16(akh, bql[ks], sa[jk], 0, 0, 0);
            }
        }
        // exp; P[m][key] row-major, b64 per frag (4 consecutive keys per lane)
        #pragma unroll
        for (int jk = 0; jk < 4; jk++) {
            float p0 = __expf(sa[jk][0] * 0.125f);
            float p1 = __expf(sa[jk][1] * 0.125f);
            float p2 = __expf(sa[jk][2] * 0.125f);
            float p3 = __expf(sa[jk][3] * 0.125f);
            lacc += (p0 + p1) + (p2 + p3);
            ushort2 p01 = f2bf2(p0, p1), p23 = f2bf2(p2, p3);
            ushort4 ph;
            ph.x = p01.x; ph.y = p01.y; ph.z = p23.x; ph.w = p23.y;
            *(ushort4*)&Ps[w*16 + lrow][jk*16 + quad*4] = ph;   // wave-private rows
        }
        // PV: O = P·V^T' — no barrier (wave-private P)
        #pragma unroll
        for (int ks = 0; ks < 2; ks++) {
            short8v ap = *(const short8v*)&Ps[w*16 + lrow][ks*32 + quad*8];
            #pragma unroll
            for (int nf = 0; nf < 4; nf++) {
                const int r = nf*16 + lrow, c = ks*4 + quad;
                const int off = ((r << 3) | (c ^ (r & 7))) * 8;
                short8v vH = *(const short8v*)&VTh[off];
                short8v vL = *(const short8v*)&VTl[off];
                o[nf] = __builtin_amdgcn_mfma_f32_16x16x32_bf16(ap, vH, o[nf], 0, 0, 0);
                o[nf] = __builtin_amdgcn_mfma_f32_16x16x32_bf16(ap, vL, o[nf], 0, 0, 0);
            }
        }
    }
    // l: lane holds partials for col m=lrow (its quad's keys) -> sum over quads
    lacc += __shfl_xor(lacc, 16);
    lacc += __shfl_xor(lacc, 32);
    #pragma unroll
    for (int r = 0; r < 4; r++) {
        const float linv = 1.0f / __shfl(lacc, quad*4 + r);
        #pragma unroll
        for (int nf = 0; nf < 4; nf++)
            out[(rowb + m0 + w*16 + quad*4 + r) * D_ + hoff + nf*16 + lrow] =
                o[nf][r] * linv;
    }
}

// ------- K6: channel attention, MFMA flash, S^T trick, DMA staging --------------
// dk=32. Wave owns 32 q-rows (2 m-frags). P hi-only b64. Out bf16 h/l.
// K LDS: pitch 32 (swz (row>>1)&3); V LDS: pitch 64 (swz row&7).
__global__ __launch_bounds__(256) void k6_mfma(
    const unsigned short* __restrict__ qch, const unsigned short* __restrict__ qcl,
    const unsigned short* __restrict__ kch, const unsigned short* __restrict__ kcl,
    const unsigned short* __restrict__ vth, const unsigned short* __restrict__ vtl,
    unsigned short* __restrict__ oh, unsigned short* __restrict__ ol)
{
    const int m0 = blockIdx.x * 128;
    const int h = blockIdx.y, b = blockIdx.z;
    const int hoff = h * SK_;
    const size_t rowb = (size_t)b * D_;
    __shared__ __align__(16) unsigned short Ksh[64*32], Ksl[64*32];
    __shared__ __align__(16) unsigned short VTh[32*64], VTl[32*64];
    __shared__ __align__(16) unsigned short Ps[128][72];
    const int tid = threadIdx.x;
    const int w = tid >> 6, lane = tid & 63;
    const int lrow = lane & 15, quad = lane >> 4;
    short8v bqh[2], bql[2];
    #pragma unroll
    for (int i = 0; i < 2; i++) {
        const size_t qb = (rowb + m0 + w*32 + i*16 + lrow) * S_ + hoff + quad*8;
        bqh[i] = *(const short8v*)&qch[qb];
        bql[i] = *(const short8v*)&qcl[qb];
    }
    size_t kOff, vOff;
    {
        const int pK = w*64 + lane;
        const int rowK = pK >> 2;
        const int ccK = (pK & 3) ^ ((rowK >> 1) & 3);
        kOff = (rowb + rowK) * S_ + hoff + ccK*8;
        const int pV = w*64 + lane;
        const int rowV = pV >> 3;
        const int ccV = (pV & 7) ^ (rowV & 7);
        vOff = ((size_t)b * S_ + hoff + rowV) * D_ + ccV*8;
    }
    const int cb = w*64*8;
    f32x4 o[2][2] = {};
    float lacc[2] = {0.f, 0.f};
    for (int kt = 0; kt < 16; kt++) {
        const int n00 = kt * 64;
        __syncthreads();
        ldlds16(kch + kOff + (size_t)n00 * S_, &Ksh[cb]);
        ldlds16(kcl + kOff + (size_t)n00 * S_, &Ksl[cb]);
        ldlds16(vth + vOff + n00,              &VTh[cb]);
        ldlds16(vtl + vOff + n00,              &VTl[cb]);
        __syncthreads();
        // S^T = K·Q^T
        f32x4 sa[2][4] = {};
        #pragma unroll
        for (int jk = 0; jk < 4; jk++) {
            const int r = jk*16 + lrow;
            const int off = ((r << 2) | (quad ^ ((r >> 1) & 3))) * 8;
            short8v akh = *(const short8v*)&Ksh[off];
            short8v akl = *(const short8v*)&Ksl[off];
            #pragma unroll
            for (int i = 0; i < 2; i++) {
                sa[i][jk] = __builtin_amdgcn_mfma_f32_16x16x32_bf16(akh, bqh[i], sa[i][jk], 0, 0, 0);
                sa[i][jk] = __builtin_amdgcn_mfma_f32_16x16x32_bf16(akl, bqh[i], sa[i][jk], 0, 0, 0);
                sa[i][jk] = __builtin_amdgcn_mfma_f32_16x16x32_bf16(akh, bql[i], sa[i][jk], 0, 0, 0);
            }
        }
        // exp; P row-major [m][key], b64 writes, wave-private rows
        #pragma unroll
        for (int i = 0; i < 2; i++)
            #pragma unroll
            for (int jk = 0; jk < 4; jk++) {
                float p0 = __expf(sa[i][jk][0] * 0.17677669529663687f);
                float p1 = __expf(sa[i][jk][1] * 0.17677669529663687f);
                float p2 = __expf(sa[i][jk][2] * 0.17677669529663687f);
                float p3 = __expf(sa[i][jk][3] * 0.17677669529663687f);
                lacc[i] += (p0 + p1) + (p2 + p3);
                ushort2 p01 = f2bf2(p0, p1), p23 = f2bf2(p2, p3);
                ushort4 ph;
                ph.x = p01.x; ph.y = p01.y; ph.z = p23.x; ph.w = p23.y;
                *(ushort4*)&Ps[w*32 + i*16 + lrow][jk*16 + quad*4] = ph;
            }
        // PV (no barrier: P rows wave-private)
        #pragma unroll
        for (int ks = 0; ks < 2; ks++) {
            short8v ap[2];
            #pragma unroll
            for (int i = 0; i < 2; i++)
                ap[i] = *(const short8v*)&Ps[w*32 + i*16 + lrow][ks*32 + quad*8];
            #pragma unroll
            for (int nf = 0; nf < 2; nf++) {
                const int r = nf*16 + lrow, c = ks*4 + quad;
                const int off = ((r << 3) | (c ^ (r & 7))) * 8;
                short8v vHf = *(const short8v*)&VTh[off];
                short8v vLf = *(const short8v*)&VTl[off];
                #pragma unroll
                for (int i = 0; i < 2; i++) {
                    o[i][nf] = __builtin_amdgcn_mfma_f32_16x16x32_bf16(ap[i], vHf, o[i][nf], 0, 0, 0);
                    o[i][nf] = __builtin_amdgcn_mfma_f32_16x16x32_bf16(ap[i], vLf, o[i][nf], 0, 0, 0);
                }
            }
        }
    }
    #pragma unroll
    for (int i = 0; i < 2; i++) {
        lacc[i] += __shfl_xor(lacc[i], 16);
        lacc[i] += __shfl_xor(lacc[i], 32);
    }
    #pragma unroll
    for (int i = 0; i < 2; i++)
        #pragma unroll
        for (int r = 0; r < 4; r++) {
            const float linv = 1.0f / __shfl(lacc[i], quad*4 + r);
            const float v0 = o[i][0][r] * linv;
            const float v1 = o[i][1][r] * linv;
            ushort2 h2 = f2bf2(v0, v1);
            ushort2 l2 = f2bf2(v0 - bf2f(h2.x), v1 - bf2f(h2.y));
            const size_t idx =
                (rowb + m0 + w*32 + i*16 + quad*4 + r) * S_ + hoff + lrow;
            oh[idx]      = h2.x;
            oh[idx + 16] = h2.y;
            ol[idx]      = l2.x;
            ol[idx + 16] = l2.y;
        }
}

// ------- K4 fused: LN over seq (stats+normalize) + transpose, bf16 h/l out ------
// Block = (64 d-cols, one b). tile[256][65] f32 + partials. One pass over x.
__global__ __launch_bounds__(256) void k4_fused(
    const float* __restrict__ x, const float* __restrict__ a_c,
    const float* __restrict__ b_c, unsigned short* __restrict__ xth,
    unsigned short* __restrict__ xtl)
{
    const int d0 = blockIdx.x * 64, b = blockIdx.y;
    __shared__ float tile[256][65];
    __shared__ float part[8][64];
    __shared__ float stats[2][64];
    __shared__ float acs[256], bcs[256];
    const int tid = threadIdx.x;
    acs[tid] = a_c[tid];
    bcs[tid] = b_c[tid];
    const int dl = tid & 63, sq = tid >> 6;
    float s1 = 0.f, s2 = 0.f;
    #pragma unroll 8
    for (int u = 0; u < 64; u++) {
        const int srow = sq*64 + u;
        const float v = x[((size_t)(b*S_ + srow))*D_ + d0 + dl];
        tile[srow][dl] = v;
        s1 += v; s2 += v*v;
    }
    part[sq][dl] = s1; part[4+sq][dl] = s2;
    __syncthreads();
    if (tid < 64) {
        const float S = part[0][tid]+part[1][tid]+part[2][tid]+part[3][tid];
        const float Q = part[4][tid]+part[5][tid]+part[6][tid]+part[7][tid];
        const float mean = S / (float)S_;
        const float var  = fmaxf((Q - (float)S_*mean*mean)/(float)(S_-1), 0.f);
        stats[0][tid] = mean;
        stats[1][tid] = 1.f/(sqrtf(var)+EPS_);
    }
    __syncthreads();
    const int dd = tid >> 2, s00 = (tid & 3) * 64;
    const float mean = stats[0][dd], inv = stats[1][dd];
    const size_t obase = ((size_t)(b*D_ + d0 + dd))*S_ + s00;
    #pragma unroll
    for (int c = 0; c < 8; c++) {
        union { ushort u[8]; uint4 v4; } hb, lb;
        #pragma unroll
        for (int t = 0; t < 8; t += 2) {
            const int s = s00 + c*8 + t;
            const float v0 = acs[s]  *(tile[s][dd]  -mean)*inv + bcs[s];
            const float v1 = acs[s+1]*(tile[s+1][dd]-mean)*inv + bcs[s+1];
            ushort2 h2 = f2bf2(v0, v1);
            ushort2 l2 = f2bf2(v0 - bf2f(h2.x), v1 - bf2f(h2.y));
            hb.u[t] = h2.x; hb.u[t+1] = h2.y;
            lb.u[t] = l2.x; lb.u[t+1] = l2.y;
        }
        *(uint4*)&xth[obase + c*8] = hb.v4;
        *(uint4*)&xtl[obase + c*8] = lb.v4;
    }
}

extern "C" void kernel_launch(void* const* d_in, const int* in_sizes, int n_in,
                              void* d_out, int out_size, void* d_ws, size_t ws_size,
                              hipStream_t stream)
{
    const float* x   = (const float*)d_in[0];
    const float* Wp  = (const float*)d_in[1];
    const float* bp  = (const float*)d_in[2];
    const float* Wc  = (const float*)d_in[3];
    const float* bc  = (const float*)d_in[4];
    const float* a_p = (const float*)d_in[5];
    const float* b_p = (const float*)d_in[6];
    const float* a_c = (const float*)d_in[7];
    const float* b_c = (const float*)d_in[8];
    float* out = (float*)d_out;
    float* ws  = (float*)d_ws;
    const size_t NE = (size_t)B_ * S_ * D_;     // 4,194,304

    float* S0 = ws;             // xp h/l -> attn f32 -> vcT h/l
    float* S1 = ws + NE;        // q h/l -> xt h/l -> xcatt h/l
    float* S2 = ws + 2*NE;      // k h/l -> qc h/l
    float* S3 = ws + 3*NE;      // vT h/l -> kc h/l
    unsigned short* SW = (unsigned short*)(ws + 4*NE);

    const size_t baseBytes = 4*NE*sizeof(float);
    const bool big = ws_size >= baseBytes + (size_t)2 * 3 * D_ * D_ * sizeof(unsigned short) * 2;

    unsigned short* xh = (unsigned short*)S0;
    unsigned short* xl = xh + NE;
    unsigned short* q_h  = (unsigned short*)S1;
    unsigned short* k_h  = (unsigned short*)S2;
    unsigned short* vt_h = (unsigned short*)S3;

    // 1) LayerNorm over channels -> bf16 hi/lo
    k1_ln_p<<<dim3(B_*S_), 256, 0, stream>>>(x, a_p, b_p, xh, xl);

    // 2) QKV projection: q,k row-major bf16 h/l; v transposed bf16 h/l
    if (big) {
        unsigned short* WTh = SW;
        unsigned short* WTl = WTh + (size_t)3 * D_ * D_;
        tsplit<<<dim3(D_/64, D_/64, 3), 256, 0, stream>>>(Wp, WTh, WTl, D_, D_);
        mm_mfma<1><<<dim3(D_/128, (B_*S_)/128, 2), 256, 0, stream>>>(
            xh, xl, WTh, WTl, bp, (void*)q_h,
            B_*S_, D_, D_, (long)D_*D_, (long)D_, (long)(2*NE), (long)NE, 1);
        mm_mfma<2><<<dim3(D_/128, (B_*S_)/128, 1), 256, 0, stream>>>(
            xh, xl, WTh + (size_t)2*D_*D_, WTl + (size_t)2*D_*D_, bp + 2*D_,
            (void*)vt_h, B_*S_, D_, D_, 0, 0, 0, (long)NE, S_);
    } else {
        unsigned short* WTh = SW;
        unsigned short* WTl = WTh + (size_t)D_ * D_;
        for (int z = 0; z < 3; z++) {
            tsplit<<<dim3(D_/64, D_/64, 1), 256, 0, stream>>>(
                Wp + (size_t)z*D_*D_, WTh, WTl, D_, D_);
            if (z < 2)
                mm_mfma<1><<<dim3(D_/128, (B_*S_)/128, 1), 256, 0, stream>>>(
                    xh, xl, WTh, WTl, bp + (size_t)z*D_,
                    (void*)(q_h + (size_t)z*2*NE),
                    B_*S_, D_, D_, 0, 0, 0, (long)NE, 1);
            else
                mm_mfma<2><<<dim3(D_/128, (B_*S_)/128, 1), 256, 0, stream>>>(
                    xh, xl, WTh, WTl, bp + (size_t)z*D_, (void*)vt_h,
                    B_*S_, D_, D_, 0, 0, 0, (long)NE, S_);
        }
    }

    // 3) positional attention (MFMA flash, S^T trick) -> attn f32 in S0 (xp dead)
    k3_mfma<<<dim3(S_/64, HP_, B_), 256, 0, stream>>>(
        q_h, q_h + NE, k_h, k_h + NE, vt_h, vt_h + NE, S0);

    // 4) fused LN over sequence + transpose -> xt bf16 h/l in S1 (q dead)
    unsigned short* xth = (unsigned short*)S1;
    k4_fused<<<dim3(D_/64, B_), 256, 0, stream>>>(S0, a_c, b_c, xth, xth + NE);

    // 5) channel weights + channel QKV: qc,kc row-major; vc transposed
    unsigned short* WcTh = SW;
    unsigned short* WcTl = WcTh + (size_t)4 * S_ * S_;
    tsplit<<<dim3(S_/64, S_/64, 4), 256, 0, stream>>>(Wc, WcTh, WcTl, S_, S_);
    unsigned short* qc_h  = (unsigned short*)S2;   // k dead
    unsigned short* vct_h = (unsigned short*)S0;   // attn f32 dead after k4
    mm_mfma<1><<<dim3(S_/128, (B_*D_)/128, 2), 256, 0, stream>>>(
        xth, xth + NE, WcTh, WcTl, bc, (void*)qc_h,
        B_*D_, S_, S_, (long)S_*S_, (long)S_, (long)(2*NE), (long)NE, 1);
    mm_mfma<2><<<dim3(S_/128, (B_*D_)/128, 1), 256, 0, stream>>>(
        xth, xth + NE, WcTh + (size_t)2*S_*S_, WcTl + (size_t)2*S_*S_, bc + 2*S_,
        (void*)vct_h, B_*D_, S_, S_, 0, 0, 0, (long)NE, D_);

    // 6) channel attention (MFMA flash, S^T trick) -> xcatt bf16 h/l in S1 (xt dead)
    unsigned short* kc_h = (unsigned short*)S3;
    unsigned short* xch  = (unsigned short*)S1;
    k6_mfma<<<dim3(D_/128, HC_, B_), 256, 0, stream>>>(
        qc_h, qc_h + NE, kc_h, kc_h + NE, vct_h, vct_h + NE, xch, xch + NE);

    // 7) final projection -> out directly (f32 transposed epilogue)
    mm_mfma<3><<<dim3(S_/128, (B_*D_)/128, 1), 256, 0, stream>>>(
        xch, xch + NE, WcTh + (size_t)3*S_*S_, WcTl + (size_t)3*S_*S_, bc + 3*S_,
        (void*)out, B_*D_, S_, S_, 0, 0, 0, 0, D_);
}